// Round 1
// baseline (1146.654 us; speedup 1.0000x reference)
//
#include <hip/hip_runtime.h>
#include <hip/hip_bf16.h>
#include <math.h>

// Problem constants (B,S,D,E = 2,2048,1024,8)
#define Bq 2
#define Sq 2048
#define Dq 1024
#define Eq 8
#define Hq 2048            // 2*D
#define Aq 128             // H/16
#define Nq (Bq*Sq)         // 4096 tokens

__device__ __forceinline__ float silu_f(float x) {
    return x / (1.0f + expf(-x));
}

// ---------------------------------------------------------------------------
// Generic tiled fp32 GEMM:  C[M,N] = A[M,K] * op(B)
//   BT=true : B is [N,K] row-major (i.e. C = A * B^T)  -- "NT"
//   BT=false: B is [K,N] row-major (i.e. C = A * B)    -- "NN"
// EPI: 0 = store
//      1 = store silu(clip(acc,-5,5))
//      2 = C = silu(C_old) * acc        (SwiGLU: C_old holds gate)
//      3 = C += alpha * acc
// ksplit > 0: blockIdx.z selects K-chunk [z*ksplit, (z+1)*ksplit); else z = batch.
// Requirements (all met by our shapes): M%BM==0, N%BN==0, K%16==0, BN==64.
// ---------------------------------------------------------------------------
template<int BM, int BN, int TM, int TN, bool BT, int EPI>
__global__ __launch_bounds__(256)
void sgemm(const float* __restrict__ Ag, const float* __restrict__ Bg,
           float* __restrict__ Cg,
           int M, int N, int K, int ksplit,
           long sA, long sB, long sC, float alpha)
{
    constexpr int TX = BN / TN;  // threads in N dir
    constexpr int TY = BM / TM;  // threads in M dir
    static_assert(TX * TY == 256, "256 threads");
    static_assert(BN == 64, "B-tile loader assumes BN==64");
    static_assert(TM % 4 == 0 && TN % 4 == 0, "float4 frags");

    const int tid = threadIdx.x;
    const int tx  = tid % TX;
    const int ty  = tid / TX;
    const int bn0 = blockIdx.x * BN;
    const int bm0 = blockIdx.y * BM;
    const int bz  = blockIdx.z;

    const float* Ab = Ag + (long)bz * sA;
    const float* Bb = Bg + (long)bz * sB;
    float*       Cb = Cg + (long)bz * sC;

    int kbeg = 0, kend = K;
    if (ksplit > 0) { kbeg = bz * ksplit; kend = kbeg + ksplit; }

    __shared__ __align__(16) float As[16][BM + 4];
    __shared__ __align__(16) float Bs[16][BN + 4];

    float acc[TM][TN];
#pragma unroll
    for (int i = 0; i < TM; i++)
#pragma unroll
        for (int j = 0; j < TN; j++) acc[i][j] = 0.0f;

    const int lr = tid >> 2;        // 0..63  (row within tile for K-major loads)
    const int lk = (tid & 3) * 4;   // 0,4,8,12 (k offset)
    const int nr = tid >> 4;        // 0..15  (k row for NN B load)
    const int nc = (tid & 15) * 4;  // col offset for NN B load

    for (int kt = kbeg; kt < kend; kt += 16) {
        // ---- stage A tile [BM x 16] (K-major, transposed into LDS) ----
#pragma unroll
        for (int it = 0; it < BM / 64; ++it) {
            float4 v = *(const float4*)&Ab[(long)(bm0 + lr + it * 64) * K + kt + lk];
            As[lk + 0][lr + it * 64] = v.x;
            As[lk + 1][lr + it * 64] = v.y;
            As[lk + 2][lr + it * 64] = v.z;
            As[lk + 3][lr + it * 64] = v.w;
        }
        // ---- stage B tile ----
        if (BT) {
            float4 v = *(const float4*)&Bb[(long)(bn0 + lr) * K + kt + lk];
            Bs[lk + 0][lr] = v.x;
            Bs[lk + 1][lr] = v.y;
            Bs[lk + 2][lr] = v.z;
            Bs[lk + 3][lr] = v.w;
        } else {
            float4 v = *(const float4*)&Bb[(long)(kt + nr) * N + bn0 + nc];
            *(float4*)&Bs[nr][nc] = v;
        }
        __syncthreads();

#pragma unroll
        for (int k = 0; k < 16; k++) {
            float a[TM], b[TN];
#pragma unroll
            for (int i = 0; i < TM; i += 4) {
                float4 v = *(const float4*)&As[k][ty * TM + i];
                a[i] = v.x; a[i + 1] = v.y; a[i + 2] = v.z; a[i + 3] = v.w;
            }
#pragma unroll
            for (int j = 0; j < TN; j += 4) {
                float4 v = *(const float4*)&Bs[k][tx * TN + j];
                b[j] = v.x; b[j + 1] = v.y; b[j + 2] = v.z; b[j + 3] = v.w;
            }
#pragma unroll
            for (int i = 0; i < TM; i++)
#pragma unroll
                for (int j = 0; j < TN; j++)
                    acc[i][j] = fmaf(a[i], b[j], acc[i][j]);
        }
        __syncthreads();
    }

    // ---- epilogue ----
#pragma unroll
    for (int i = 0; i < TM; i++) {
        long row = bm0 + ty * TM + i;
        float* cp = &Cb[row * (long)N + bn0 + tx * TN];
#pragma unroll
        for (int j = 0; j < TN; j += 4) {
            if (EPI == 0) {
                float4 v;
                v.x = acc[i][j + 0]; v.y = acc[i][j + 1];
                v.z = acc[i][j + 2]; v.w = acc[i][j + 3];
                *(float4*)&cp[j] = v;
            } else if (EPI == 1) {
                float4 v;
                v.x = silu_f(fminf(fmaxf(acc[i][j + 0], -5.f), 5.f));
                v.y = silu_f(fminf(fmaxf(acc[i][j + 1], -5.f), 5.f));
                v.z = silu_f(fminf(fmaxf(acc[i][j + 2], -5.f), 5.f));
                v.w = silu_f(fminf(fmaxf(acc[i][j + 3], -5.f), 5.f));
                *(float4*)&cp[j] = v;
            } else if (EPI == 2) {
                float4 o = *(const float4*)&cp[j];
                o.x = silu_f(o.x) * acc[i][j + 0];
                o.y = silu_f(o.y) * acc[i][j + 1];
                o.z = silu_f(o.z) * acc[i][j + 2];
                o.w = silu_f(o.w) * acc[i][j + 3];
                *(float4*)&cp[j] = o;
            } else if (EPI == 3) {
                float4 o = *(const float4*)&cp[j];
                o.x += alpha * acc[i][j + 0];
                o.y += alpha * acc[i][j + 1];
                o.z += alpha * acc[i][j + 2];
                o.w += alpha * acc[i][j + 3];
                *(float4*)&cp[j] = o;
            }
        }
    }
}

// Row LayerNorm over A=128 columns; one wave per row, 4 rows per block.
__global__ __launch_bounds__(256)
void ln_rows(const float* __restrict__ in, float* __restrict__ out,
             const float* __restrict__ g, const float* __restrict__ b)
{
    int row  = blockIdx.x * 4 + (threadIdx.x >> 6);
    int lane = threadIdx.x & 63;
    const float* r = in + (long)row * Aq;
    float x0 = r[lane], x1 = r[lane + 64];
    float s  = x0 + x1;
    float ss = x0 * x0 + x1 * x1;
#pragma unroll
    for (int off = 32; off > 0; off >>= 1) {
        s  += __shfl_xor(s, off);
        ss += __shfl_xor(ss, off);
    }
    float m  = s * (1.0f / Aq);
    float v  = ss * (1.0f / Aq) - m * m;
    float rs = rsqrtf(v + 1e-5f);
    float* o = out + (long)row * Aq;
    o[lane]      = (x0 - m) * rs * g[lane]      + b[lane];
    o[lane + 64] = (x1 - m) * rs * g[lane + 64] + b[lane + 64];
}

// mixed[n,:] = sum_e ew[n,e] * LN_e(h[e,n,:])   (LN over A with per-(e,a) g,b)
__global__ __launch_bounds__(256)
void mix_ln(const float* __restrict__ h,   // [E][N][A]
            const float* __restrict__ ew,  // [N][E]
            const float* __restrict__ g,   // [E][A]
            const float* __restrict__ bb,  // [E][A]
            float* __restrict__ mixed)     // [N][A]
{
    int n    = blockIdx.x * 4 + (threadIdx.x >> 6);
    int lane = threadIdx.x & 63;
    float a0 = 0.0f, a1 = 0.0f;
#pragma unroll
    for (int e = 0; e < Eq; e++) {
        const float* r = h + ((long)e * Nq + n) * Aq;
        float x0 = r[lane], x1 = r[lane + 64];
        float s  = x0 + x1;
        float ss = x0 * x0 + x1 * x1;
#pragma unroll
        for (int off = 32; off > 0; off >>= 1) {
            s  += __shfl_xor(s, off);
            ss += __shfl_xor(ss, off);
        }
        float m  = s * (1.0f / Aq);
        float v  = ss * (1.0f / Aq) - m * m;
        float rs = rsqrtf(v + 1e-5f);
        float w  = ew[(long)n * Eq + e];
        a0 += w * ((x0 - m) * rs * g[e * Aq + lane]      + bb[e * Aq + lane]);
        a1 += w * ((x1 - m) * rs * g[e * Aq + lane + 64] + bb[e * Aq + lane + 64]);
    }
    mixed[(long)n * Aq + lane]      = a0;
    mixed[(long)n * Aq + lane + 64] = a1;
}

// Sum 8 split-K partial results.
__global__ __launch_bounds__(256)
void reduce8(const float* __restrict__ in, float* __restrict__ out, int n)
{
    int i = blockIdx.x * blockDim.x + threadIdx.x;
    if (i < n) {
        float s = 0.0f;
#pragma unroll
        for (int z = 0; z < 8; z++) s += in[(long)z * n + i];
        out[i] = s;
    }
}

extern "C" void kernel_launch(void* const* d_in, const int* in_sizes, int n_in,
                              void* d_out, int out_size, void* d_ws, size_t ws_size,
                              hipStream_t stream)
{
    const float* x             = (const float*)d_in[0];   // [B,S,D]
    const float* ew            = (const float*)d_in[1];   // [N,E]
    const float* up_w          = (const float*)d_in[2];   // [H,D]
    const float* gate_w        = (const float*)d_in[3];   // [H,D]
    const float* down_w        = (const float*)d_in[4];   // [D,H]
    const float* pre_w         = (const float*)d_in[5];   // [A,D]
    const float* post_w        = (const float*)d_in[6];   // [A,H]
    const float* an_g          = (const float*)d_in[7];   // [A]
    const float* an_b          = (const float*)d_in[8];   // [A]
    const float* adapt_proj_w  = (const float*)d_in[9];   // [H,A]
    const float* adapter_w     = (const float*)d_in[10];  // [E,A,A]
    const float* adapter_g     = (const float*)d_in[11];  // [E,A]
    const float* adapter_b     = (const float*)d_in[12];  // [E,A]
    const float* expert_proj_w = (const float*)d_in[13];  // [H,A]
    const float* output_proj_w = (const float*)d_in[14];  // [D,H]
    float* out = (float*)d_out;

    // Workspace layout (floats). Total ~82.3 MB.
    float* ws     = (float*)d_ws;
    float* hidden = ws;                              // N*H      (32 MB)
    float* wmat   = hidden + (size_t)Nq * Hq;        // B*S*S    (32 MB)
    float* h_e    = wmat;                            // E*N*A    (16 MB, reuses wmat)
    float* tmp    = wmat + (size_t)Bq * Sq * Sq;     // N*A
    float* ain    = tmp    + (size_t)Nq * Aq;        // N*A  (adapt_in == expert 'a')
    float* aout   = ain    + (size_t)Nq * Aq;        // N*A
    float* adapt  = aout   + (size_t)Nq * Aq;        // N*A
    float* mixed  = adapt  + (size_t)Nq * Aq;        // N*A
    float* wfp    = mixed  + (size_t)Nq * Aq;        // 8*D*A (split-K parts)
    float* wf     = wfp    + (size_t)8 * Dq * Aq;    // D*A   (fused output proj)

    dim3 blk(256);

    // 1. tmp = x @ pre_w^T                       [N,A]  (M=4096,N=128,K=1024)
    sgemm<64, 64, 4, 4, true, 0><<<dim3(Aq / 64, Nq / 64, 1), blk, 0, stream>>>(
        x, pre_w, tmp, Nq, Aq, Dq, 0, 0, 0, 0, 1.0f);
    // 2. ain = LN(tmp)   (== adapt_in == expert-path 'a')
    ln_rows<<<dim3(Nq / 4), blk, 0, stream>>>(tmp, ain, an_g, an_b);

    // 3a. hidden = x @ gate_w^T (raw gate)       [N,H]
    sgemm<128, 64, 8, 4, true, 0><<<dim3(Hq / 64, Nq / 128, 1), blk, 0, stream>>>(
        x, gate_w, hidden, Nq, Hq, Dq, 0, 0, 0, 0, 1.0f);
    // 3b. hidden = silu(hidden) * (x @ up_w^T)   (SwiGLU fused in epilogue)
    sgemm<128, 64, 8, 4, true, 2><<<dim3(Hq / 64, Nq / 128, 1), blk, 0, stream>>>(
        x, up_w, hidden, Nq, Hq, Dq, 0, 0, 0, 0, 1.0f);

    // 4. tmp = hidden @ post_w^T                 [N,A]  (K=2048)
    sgemm<64, 64, 4, 4, true, 0><<<dim3(Aq / 64, Nq / 64, 1), blk, 0, stream>>>(
        hidden, post_w, tmp, Nq, Aq, Hq, 0, 0, 0, 0, 1.0f);
    // 5. aout = LN(tmp)
    ln_rows<<<dim3(Nq / 4), blk, 0, stream>>>(tmp, aout, an_g, an_b);

    // 6. wmat[b] = silu(clip(ain_b @ aout_b^T))  [S,S] per batch (K=128)
    sgemm<128, 64, 8, 4, true, 1><<<dim3(Sq / 64, Sq / 128, Bq), blk, 0, stream>>>(
        ain, aout, wmat, Sq, Sq, Aq, 0,
        (long)Sq * Aq, (long)Sq * Aq, (long)Sq * Sq, 1.0f);

    // 7. adapt[b] = wmat[b] @ ain_b  (NN)        [S,A] per batch (K=2048)
    sgemm<64, 64, 4, 4, false, 0><<<dim3(Aq / 64, Sq / 64, Bq), blk, 0, stream>>>(
        wmat, ain, adapt, Sq, Aq, Sq, 0,
        (long)Sq * Sq, (long)Sq * Aq, (long)Sq * Aq, 1.0f);

    // 8. hidden += 0.1 * (adapt @ adapt_proj_w^T)   [N,H] (K=128)
    sgemm<128, 64, 8, 4, true, 3><<<dim3(Hq / 64, Nq / 128, 1), blk, 0, stream>>>(
        adapt, adapt_proj_w, hidden, Nq, Hq, Aq, 0, 0, 0, 0, 0.1f);

    // 9. out = hidden @ down_w^T                 [N,D] (K=2048)
    sgemm<128, 64, 8, 4, true, 0><<<dim3(Dq / 64, Nq / 128, 1), blk, 0, stream>>>(
        hidden, down_w, out, Nq, Dq, Hq, 0, 0, 0, 0, 1.0f);

    // 10. h_e[e] = ain @ adapter_w[e]^T          [N,A] per expert (K=128)
    sgemm<64, 64, 4, 4, true, 0><<<dim3(Aq / 64, Nq / 64, Eq), blk, 0, stream>>>(
        ain, adapter_w, h_e, Nq, Aq, Aq, 0,
        0, (long)Aq * Aq, (long)Nq * Aq, 1.0f);

    // 11. mixed = sum_e ew[:,e] * LN_e(h_e)
    mix_ln<<<dim3(Nq / 4), blk, 0, stream>>>(h_e, ew, adapter_g, adapter_b, mixed);

    // 12. wfp[z] = (output_proj_w @ expert_proj_w) split-K partials  [D,A] (K=2048/8)
    sgemm<64, 64, 4, 4, false, 0><<<dim3(Aq / 64, Dq / 64, 8), blk, 0, stream>>>(
        output_proj_w, expert_proj_w, wfp, Dq, Aq, Hq, Hq / 8,
        0, 0, (long)Dq * Aq, 1.0f);
    // 13. wf = sum_z wfp[z]
    reduce8<<<dim3((Dq * Aq + 255) / 256), blk, 0, stream>>>(wfp, wf, Dq * Aq);

    // 14. out += mixed @ wf^T                    [N,D] (K=128)
    sgemm<128, 64, 8, 4, true, 3><<<dim3(Dq / 64, Nq / 128, 1), blk, 0, stream>>>(
        mixed, wf, out, Nq, Dq, Aq, 0, 0, 0, 0, 1.0f);
}

// Round 2
// 664.759 us; speedup vs baseline: 1.7249x; 1.7249x over previous
//
#include <hip/hip_runtime.h>
#include <hip/hip_bf16.h>
#include <math.h>

// Problem constants (B,S,D,E = 2,2048,1024,8)
#define Bq 2
#define Sq 2048
#define Dq 1024
#define Eq 8
#define Hq 2048            // 2*D
#define Aq 128             // H/16
#define Nq (Bq*Sq)         // 4096 tokens

typedef __attribute__((ext_vector_type(4))) float f32x4;
typedef __attribute__((ext_vector_type(8))) short bfrag;   // 8 bf16 in 4 VGPRs

__device__ __forceinline__ float silu_f(float x) {
    return x / (1.0f + expf(-x));
}
__device__ __forceinline__ unsigned short f2bf(float x) {  // RNE fp32->bf16
    unsigned u = __float_as_uint(x);
    u += 0x7fffu + ((u >> 16) & 1u);
    return (unsigned short)(u >> 16);
}
__device__ __forceinline__ float bf2f(unsigned short h) {
    return __uint_as_float(((unsigned)h) << 16);
}
__device__ __forceinline__ void gl16(const unsigned short* g, unsigned short* l) {
    __builtin_amdgcn_global_load_lds(
        (const __attribute__((address_space(1))) void*)g,
        (__attribute__((address_space(3))) void*)(void*)l, 16, 0, 0);
}

// ---------------------------------------------------------------------------
// split fp32 -> (hi, lo) bf16 pair.  n4 = element count / 4.
// ---------------------------------------------------------------------------
__global__ __launch_bounds__(256)
void split2(const float* __restrict__ in, unsigned short* __restrict__ hi,
            unsigned short* __restrict__ lo, int n4)
{
    int i = blockIdx.x * 256 + threadIdx.x;
    int stride = gridDim.x * 256;
    for (; i < n4; i += stride) {
        float4 v = ((const float4*)in)[i];
        float f[4] = {v.x, v.y, v.z, v.w};
        unsigned short hh[4], ll[4];
#pragma unroll
        for (int j = 0; j < 4; j++) {
            hh[j] = f2bf(f[j]);
            ll[j] = f2bf(f[j] - bf2f(hh[j]));   // Sterbenz-exact residual
        }
        ((ushort4*)hi)[i] = make_ushort4(hh[0], hh[1], hh[2], hh[3]);
        ((ushort4*)lo)[i] = make_ushort4(ll[0], ll[1], ll[2], ll[3]);
    }
}

// ---------------------------------------------------------------------------
// Split-bf16 MFMA GEMM: C[M,N] = (Ahi+Alo)[M,K] @ (Bhi+Blo)[N,K]^T  (fp32 out)
// 3-term: hi*hi + hi*lo + lo*hi  ->  ~fp32 accuracy at bf16 MFMA rate.
// 128x128 tile, BK=32, 4 waves (2x2 of 64x64), global_load_lds staging,
// XOR swizzle (k-seg ^= row&3) applied on the global source (linear LDS dest)
// and on the ds_read side.
// EPI: 0 = store acc;  2 = store silu(Gate[idx]) * acc  (SwiGLU)
// ---------------------------------------------------------------------------
template<int EPI>
__global__ __launch_bounds__(256)
void mgemm(const unsigned short* __restrict__ Ahi, const unsigned short* __restrict__ Alo,
           const unsigned short* __restrict__ Bhi, const unsigned short* __restrict__ Blo,
           const float* __restrict__ Gate, float* __restrict__ C,
           int M, int N, int K)
{
    __shared__ __align__(16) unsigned short lds[16384];  // 4 tiles x [128][32] bf16 = 32 KB
    // tile bases (ushort units): AHI=0, ALO=4096, BHI=8192, BLO=12288
    const int tid = threadIdx.x;
    const int l   = tid & 63;
    const int w   = tid >> 6;
    const int wr  = w >> 1, wc = w & 1;
    const int bm0 = blockIdx.y * 128, bn0 = blockIdx.x * 128;

    // ---- staging source (per-lane; pre-swizzled k-segment) ----
    const int srow = tid >> 2;                              // 0..63 (round adds 64)
    const int scol = (((tid & 3) ^ (srow & 3)) << 3);       // swizzled k offset (elements)
    const size_t aoff0 = (size_t)(bm0 + srow) * K + scol;
    const size_t boff0 = (size_t)(bn0 + srow) * K + scol;
    const size_t rstep = (size_t)64 * K;                    // +64 rows for round 1
    unsigned short* ldsw = &lds[w << 9];                    // wave-uniform dest base (w*512)

    // ---- fragment read offsets (ushort units), same swizzle ----
    const int cu = (((l >> 4) ^ (l & 3)) << 3);
    const int ra = (wr * 64 + (l & 15)) * 32 + cu;          // + fm*512
    const int rb = (wc * 64 + (l & 15)) * 32 + cu;          // + fn*512

    f32x4 acc[4][4];
#pragma unroll
    for (int i = 0; i < 4; i++)
#pragma unroll
        for (int j = 0; j < 4; j++) acc[i][j] = (f32x4){0.f, 0.f, 0.f, 0.f};

    for (int kt = 0; kt < K; kt += 32) {
        // 8 x global_load_lds (16B/lane): {Ahi,Alo,Bhi,Blo} x {round0, round1}
        gl16(Ahi + aoff0 + kt,         ldsw + 0);
        gl16(Ahi + aoff0 + kt + rstep, ldsw + 2048);
        gl16(Alo + aoff0 + kt,         ldsw + 4096);
        gl16(Alo + aoff0 + kt + rstep, ldsw + 4096 + 2048);
        gl16(Bhi + boff0 + kt,         ldsw + 8192);
        gl16(Bhi + boff0 + kt + rstep, ldsw + 8192 + 2048);
        gl16(Blo + boff0 + kt,         ldsw + 12288);
        gl16(Blo + boff0 + kt + rstep, ldsw + 12288 + 2048);
        __syncthreads();   // drains vmcnt before any wave reads LDS

        bfrag ah[4], al2[4], bh[4], bl2[4];
#pragma unroll
        for (int f = 0; f < 4; f++) {
            ah[f]  = *(const bfrag*)&lds[        ra + f * 512];
            al2[f] = *(const bfrag*)&lds[ 4096 + ra + f * 512];
            bh[f]  = *(const bfrag*)&lds[ 8192 + rb + f * 512];
            bl2[f] = *(const bfrag*)&lds[12288 + rb + f * 512];
        }
#pragma unroll
        for (int i = 0; i < 4; i++)
#pragma unroll
            for (int j = 0; j < 4; j++) {
                acc[i][j] = __builtin_amdgcn_mfma_f32_16x16x32_bf16(ah[i],  bh[j],  acc[i][j], 0, 0, 0);
                acc[i][j] = __builtin_amdgcn_mfma_f32_16x16x32_bf16(ah[i],  bl2[j], acc[i][j], 0, 0, 0);
                acc[i][j] = __builtin_amdgcn_mfma_f32_16x16x32_bf16(al2[i], bh[j],  acc[i][j], 0, 0, 0);
            }
        __syncthreads();
    }

    // ---- epilogue: C/D layout col = lane&15, row = (lane>>4)*4 + reg ----
    const int crow0 = bm0 + wr * 64 + (l >> 4) * 4;
    const int ccol0 = bn0 + wc * 64 + (l & 15);
#pragma unroll
    for (int i = 0; i < 4; i++)
#pragma unroll
        for (int j = 0; j < 4; j++)
#pragma unroll
            for (int r = 0; r < 4; r++) {
                size_t idx = (size_t)(crow0 + i * 16 + r) * N + (ccol0 + j * 16);
                float v = acc[i][j][r];
                if (EPI == 2) v = silu_f(Gate[idx]) * v;
                C[idx] = v;
            }
}

// ---------------------------------------------------------------------------
// fp32 tiled GEMM (unchanged from round 1) for the small / attenuated paths.
// ---------------------------------------------------------------------------
template<int BM, int BN, int TM, int TN, bool BT, int EPI>
__global__ __launch_bounds__(256)
void sgemm(const float* __restrict__ Ag, const float* __restrict__ Bg,
           float* __restrict__ Cg,
           int M, int N, int K, int ksplit,
           long sA, long sB, long sC, float alpha)
{
    constexpr int TX = BN / TN;
    constexpr int TY = BM / TM;
    static_assert(TX * TY == 256, "256 threads");
    static_assert(BN == 64, "B-tile loader assumes BN==64");

    const int tid = threadIdx.x;
    const int tx  = tid % TX;
    const int ty  = tid / TX;
    const int bn0 = blockIdx.x * BN;
    const int bm0 = blockIdx.y * BM;
    const int bz  = blockIdx.z;

    const float* Ab = Ag + (long)bz * sA;
    const float* Bb = Bg + (long)bz * sB;
    float*       Cb = Cg + (long)bz * sC;

    int kbeg = 0, kend = K;
    if (ksplit > 0) { kbeg = bz * ksplit; kend = kbeg + ksplit; }

    __shared__ __align__(16) float As[16][BM + 4];
    __shared__ __align__(16) float Bs[16][BN + 4];

    float acc[TM][TN];
#pragma unroll
    for (int i = 0; i < TM; i++)
#pragma unroll
        for (int j = 0; j < TN; j++) acc[i][j] = 0.0f;

    const int lr = tid >> 2;
    const int lk = (tid & 3) * 4;
    const int nr = tid >> 4;
    const int nc = (tid & 15) * 4;

    for (int kt = kbeg; kt < kend; kt += 16) {
#pragma unroll
        for (int it = 0; it < BM / 64; ++it) {
            float4 v = *(const float4*)&Ab[(long)(bm0 + lr + it * 64) * K + kt + lk];
            As[lk + 0][lr + it * 64] = v.x;
            As[lk + 1][lr + it * 64] = v.y;
            As[lk + 2][lr + it * 64] = v.z;
            As[lk + 3][lr + it * 64] = v.w;
        }
        if (BT) {
            float4 v = *(const float4*)&Bb[(long)(bn0 + lr) * K + kt + lk];
            Bs[lk + 0][lr] = v.x;
            Bs[lk + 1][lr] = v.y;
            Bs[lk + 2][lr] = v.z;
            Bs[lk + 3][lr] = v.w;
        } else {
            float4 v = *(const float4*)&Bb[(long)(kt + nr) * N + bn0 + nc];
            *(float4*)&Bs[nr][nc] = v;
        }
        __syncthreads();

#pragma unroll
        for (int k = 0; k < 16; k++) {
            float a[TM], b[TN];
#pragma unroll
            for (int i = 0; i < TM; i += 4) {
                float4 v = *(const float4*)&As[k][ty * TM + i];
                a[i] = v.x; a[i + 1] = v.y; a[i + 2] = v.z; a[i + 3] = v.w;
            }
#pragma unroll
            for (int j = 0; j < TN; j += 4) {
                float4 v = *(const float4*)&Bs[k][tx * TN + j];
                b[j] = v.x; b[j + 1] = v.y; b[j + 2] = v.z; b[j + 3] = v.w;
            }
#pragma unroll
            for (int i = 0; i < TM; i++)
#pragma unroll
                for (int j = 0; j < TN; j++)
                    acc[i][j] = fmaf(a[i], b[j], acc[i][j]);
        }
        __syncthreads();
    }

#pragma unroll
    for (int i = 0; i < TM; i++) {
        long row = bm0 + ty * TM + i;
        float* cp = &Cb[row * (long)N + bn0 + tx * TN];
#pragma unroll
        for (int j = 0; j < TN; j += 4) {
            if (EPI == 0) {
                float4 v;
                v.x = acc[i][j + 0]; v.y = acc[i][j + 1];
                v.z = acc[i][j + 2]; v.w = acc[i][j + 3];
                *(float4*)&cp[j] = v;
            } else if (EPI == 1) {
                float4 v;
                v.x = silu_f(fminf(fmaxf(acc[i][j + 0], -5.f), 5.f));
                v.y = silu_f(fminf(fmaxf(acc[i][j + 1], -5.f), 5.f));
                v.z = silu_f(fminf(fmaxf(acc[i][j + 2], -5.f), 5.f));
                v.w = silu_f(fminf(fmaxf(acc[i][j + 3], -5.f), 5.f));
                *(float4*)&cp[j] = v;
            } else if (EPI == 3) {
                float4 o = *(const float4*)&cp[j];
                o.x += alpha * acc[i][j + 0];
                o.y += alpha * acc[i][j + 1];
                o.z += alpha * acc[i][j + 2];
                o.w += alpha * acc[i][j + 3];
                *(float4*)&cp[j] = o;
            }
        }
    }
}

// Row LayerNorm over A=128 columns; one wave per row, 4 rows per block.
__global__ __launch_bounds__(256)
void ln_rows(const float* __restrict__ in, float* __restrict__ out,
             const float* __restrict__ g, const float* __restrict__ b)
{
    int row  = blockIdx.x * 4 + (threadIdx.x >> 6);
    int lane = threadIdx.x & 63;
    const float* r = in + (long)row * Aq;
    float x0 = r[lane], x1 = r[lane + 64];
    float s  = x0 + x1;
    float ss = x0 * x0 + x1 * x1;
#pragma unroll
    for (int off = 32; off > 0; off >>= 1) {
        s  += __shfl_xor(s, off);
        ss += __shfl_xor(ss, off);
    }
    float m  = s * (1.0f / Aq);
    float v  = ss * (1.0f / Aq) - m * m;
    float rs = rsqrtf(v + 1e-5f);
    float* o = out + (long)row * Aq;
    o[lane]      = (x0 - m) * rs * g[lane]      + b[lane];
    o[lane + 64] = (x1 - m) * rs * g[lane + 64] + b[lane + 64];
}

// mixed[n,:] = sum_e ew[n,e] * LN_e(h[e,n,:])
__global__ __launch_bounds__(256)
void mix_ln(const float* __restrict__ h,   // [E][N][A]
            const float* __restrict__ ew,  // [N][E]
            const float* __restrict__ g,   // [E][A]
            const float* __restrict__ bb,  // [E][A]
            float* __restrict__ mixed)     // [N][A]
{
    int n    = blockIdx.x * 4 + (threadIdx.x >> 6);
    int lane = threadIdx.x & 63;
    float a0 = 0.0f, a1 = 0.0f;
#pragma unroll
    for (int e = 0; e < Eq; e++) {
        const float* r = h + ((long)e * Nq + n) * Aq;
        float x0 = r[lane], x1 = r[lane + 64];
        float s  = x0 + x1;
        float ss = x0 * x0 + x1 * x1;
#pragma unroll
        for (int off = 32; off > 0; off >>= 1) {
            s  += __shfl_xor(s, off);
            ss += __shfl_xor(ss, off);
        }
        float m  = s * (1.0f / Aq);
        float v  = ss * (1.0f / Aq) - m * m;
        float rs = rsqrtf(v + 1e-5f);
        float wv = ew[(long)n * Eq + e];
        a0 += wv * ((x0 - m) * rs * g[e * Aq + lane]      + bb[e * Aq + lane]);
        a1 += wv * ((x1 - m) * rs * g[e * Aq + lane + 64] + bb[e * Aq + lane + 64]);
    }
    mixed[(long)n * Aq + lane]      = a0;
    mixed[(long)n * Aq + lane + 64] = a1;
}

__global__ __launch_bounds__(256)
void reduce8(const float* __restrict__ in, float* __restrict__ out, int n)
{
    int i = blockIdx.x * blockDim.x + threadIdx.x;
    if (i < n) {
        float s = 0.0f;
#pragma unroll
        for (int z = 0; z < 8; z++) s += in[(long)z * n + i];
        out[i] = s;
    }
}

extern "C" void kernel_launch(void* const* d_in, const int* in_sizes, int n_in,
                              void* d_out, int out_size, void* d_ws, size_t ws_size,
                              hipStream_t stream)
{
    const float* x             = (const float*)d_in[0];   // [B,S,D]
    const float* ew            = (const float*)d_in[1];   // [N,E]
    const float* up_w          = (const float*)d_in[2];   // [H,D]
    const float* gate_w        = (const float*)d_in[3];   // [H,D]
    const float* down_w        = (const float*)d_in[4];   // [D,H]
    const float* pre_w         = (const float*)d_in[5];   // [A,D]
    const float* post_w        = (const float*)d_in[6];   // [A,H]
    const float* an_g          = (const float*)d_in[7];   // [A]
    const float* an_b          = (const float*)d_in[8];   // [A]
    const float* adapt_proj_w  = (const float*)d_in[9];   // [H,A]
    const float* adapter_w     = (const float*)d_in[10];  // [E,A,A]
    const float* adapter_g     = (const float*)d_in[11];  // [E,A]
    const float* adapter_b     = (const float*)d_in[12];  // [E,A]
    const float* expert_proj_w = (const float*)d_in[13];  // [H,A]
    const float* output_proj_w = (const float*)d_in[14];  // [D,H]
    float* out = (float*)d_out;

    // ---- workspace layout (byte offsets), total 120 MB ----
    char* base = (char*)d_ws;
    float* hidden = (float*)(base);                        // [N,H] 32 MB
    float* gate   = (float*)(base + ((size_t)32 << 20));   // 32 MB, reused as wmat then h_e
    float* wmat   = gate;
    float* h_e    = gate;
    float* tmp    = (float*)(base + ((size_t)64 << 20));   // [N,A] 2 MB
    float* ain    = (float*)(base + ((size_t)66 << 20));
    float* aout   = (float*)(base + ((size_t)68 << 20));
    float* adapt  = (float*)(base + ((size_t)70 << 20));
    float* mixed  = (float*)(base + ((size_t)72 << 20));
    float* wfp    = (float*)(base + ((size_t)74 << 20));   // 8*[D,A] 4 MB
    float* wf     = (float*)(base + ((size_t)78 << 20));   // [D,A] 0.5 MB
    unsigned short* xhi  = (unsigned short*)(base + ((size_t)80  << 20));  // [N,D] 8 MB
    unsigned short* xlo  = (unsigned short*)(base + ((size_t)88  << 20));
    unsigned short* gwhi = (unsigned short*)(base + ((size_t)96  << 20));  // [H,D] 4 MB
    unsigned short* gwlo = (unsigned short*)(base + ((size_t)100 << 20));
    unsigned short* uwhi = (unsigned short*)(base + ((size_t)104 << 20));
    unsigned short* uwlo = (unsigned short*)(base + ((size_t)108 << 20));
    unsigned short* hhi  = (unsigned short*)(base + ((size_t)80  << 20));  // [N,H] 16 MB (reuses x/gw/uw)
    unsigned short* hlo  = (unsigned short*)(base + ((size_t)96  << 20));
    unsigned short* dwhi = (unsigned short*)(base + ((size_t)112 << 20));  // [D,H] 4 MB
    unsigned short* dwlo = (unsigned short*)(base + ((size_t)116 << 20));

    dim3 blk(256);

    // 0. fp32 -> split-bf16 conversions
    split2<<<dim3(1024), blk, 0, stream>>>(x,      xhi,  xlo,  Nq * Dq / 4);
    split2<<<dim3(512),  blk, 0, stream>>>(gate_w, gwhi, gwlo, Hq * Dq / 4);
    split2<<<dim3(512),  blk, 0, stream>>>(up_w,   uwhi, uwlo, Hq * Dq / 4);
    split2<<<dim3(512),  blk, 0, stream>>>(down_w, dwhi, dwlo, Dq * Hq / 4);

    // 1-2. adapt_in = LN(x @ pre_w^T)     (also the expert-path 'a')
    sgemm<64, 64, 4, 4, true, 0><<<dim3(Aq / 64, Nq / 64, 1), blk, 0, stream>>>(
        x, pre_w, tmp, Nq, Aq, Dq, 0, 0, 0, 0, 1.0f);
    ln_rows<<<dim3(Nq / 4), blk, 0, stream>>>(tmp, ain, an_g, an_b);

    // 3a. gate = x @ gate_w^T   (split-bf16 MFMA)
    mgemm<0><<<dim3(Hq / 128, Nq / 128), blk, 0, stream>>>(
        xhi, xlo, gwhi, gwlo, nullptr, gate, Nq, Hq, Dq);
    // 3b. hidden = silu(gate) * (x @ up_w^T)
    mgemm<2><<<dim3(Hq / 128, Nq / 128), blk, 0, stream>>>(
        xhi, xlo, uwhi, uwlo, gate, hidden, Nq, Hq, Dq);

    // 4-5. adapt_out = LN(hidden @ post_w^T)
    sgemm<64, 64, 4, 4, true, 0><<<dim3(Aq / 64, Nq / 64, 1), blk, 0, stream>>>(
        hidden, post_w, tmp, Nq, Aq, Hq, 0, 0, 0, 0, 1.0f);
    ln_rows<<<dim3(Nq / 4), blk, 0, stream>>>(tmp, aout, an_g, an_b);

    // 6. wmat[b] = silu(clip(ain_b @ aout_b^T))   [S,S] per batch
    sgemm<128, 64, 8, 4, true, 1><<<dim3(Sq / 64, Sq / 128, Bq), blk, 0, stream>>>(
        ain, aout, wmat, Sq, Sq, Aq, 0,
        (long)Sq * Aq, (long)Sq * Aq, (long)Sq * Sq, 1.0f);

    // 7. adapt[b] = wmat[b] @ ain_b  (NN)
    sgemm<64, 64, 4, 4, false, 0><<<dim3(Aq / 64, Sq / 64, Bq), blk, 0, stream>>>(
        wmat, ain, adapt, Sq, Aq, Sq, 0,
        (long)Sq * Sq, (long)Sq * Aq, (long)Sq * Aq, 1.0f);

    // 8. hidden += 0.1 * (adapt @ adapt_proj_w^T)
    sgemm<128, 64, 8, 4, true, 3><<<dim3(Hq / 64, Nq / 128, 1), blk, 0, stream>>>(
        adapt, adapt_proj_w, hidden, Nq, Hq, Aq, 0, 0, 0, 0, 0.1f);

    // 9. out = hidden @ down_w^T   (split-bf16 MFMA)
    split2<<<dim3(2048), blk, 0, stream>>>(hidden, hhi, hlo, Nq * Hq / 4);
    mgemm<0><<<dim3(Dq / 128, Nq / 128), blk, 0, stream>>>(
        hhi, hlo, dwhi, dwlo, nullptr, out, Nq, Dq, Hq);

    // 10. h_e[e] = ain @ adapter_w[e]^T
    sgemm<64, 64, 4, 4, true, 0><<<dim3(Aq / 64, Nq / 64, Eq), blk, 0, stream>>>(
        ain, adapter_w, h_e, Nq, Aq, Aq, 0,
        0, (long)Aq * Aq, (long)Nq * Aq, 1.0f);

    // 11. mixed = sum_e ew[:,e] * LN_e(h_e)
    mix_ln<<<dim3(Nq / 4), blk, 0, stream>>>(h_e, ew, adapter_g, adapter_b, mixed);

    // 12-13. wf = output_proj_w @ expert_proj_w  (split-K + reduce)
    sgemm<64, 64, 4, 4, false, 0><<<dim3(Aq / 64, Dq / 64, 8), blk, 0, stream>>>(
        output_proj_w, expert_proj_w, wfp, Dq, Aq, Hq, Hq / 8,
        0, 0, (long)Dq * Aq, 1.0f);
    reduce8<<<dim3((Dq * Aq + 255) / 256), blk, 0, stream>>>(wfp, wf, Dq * Aq);

    // 14. out += mixed @ wf^T
    sgemm<128, 64, 8, 4, true, 3><<<dim3(Dq / 64, Nq / 128, 1), blk, 0, stream>>>(
        mixed, wf, out, Nq, Dq, Aq, 0, 0, 0, 0, 1.0f);
}

// Round 4
// 400.699 us; speedup vs baseline: 2.8616x; 1.6590x over previous
//
#include <hip/hip_runtime.h>
#include <hip/hip_bf16.h>
#include <math.h>

// Problem constants (B,S,D,E = 2,2048,1024,8)
#define Bq 2
#define Sq 2048
#define Dq 1024
#define Eq 8
#define Hq 2048            // 2*D
#define Aq 128             // H/16
#define Nq (Bq*Sq)         // 4096 tokens

typedef __attribute__((ext_vector_type(4))) float f32x4;
typedef __attribute__((ext_vector_type(8))) short bfrag;   // 8 bf16 in 4 VGPRs

__device__ __forceinline__ float silu_f(float x) {
    return x / (1.0f + expf(-x));
}
__device__ __forceinline__ unsigned short f2bf(float x) {  // RNE fp32->bf16
    unsigned u = __float_as_uint(x);
    u += 0x7fffu + ((u >> 16) & 1u);
    return (unsigned short)(u >> 16);
}
__device__ __forceinline__ float bf2f(unsigned short h) {
    return __uint_as_float(((unsigned)h) << 16);
}
__device__ __forceinline__ void gl16(const unsigned short* g, unsigned short* l) {
    __builtin_amdgcn_global_load_lds(
        (const __attribute__((address_space(1))) void*)g,
        (__attribute__((address_space(3))) void*)(void*)l, 16, 0, 0);
}

// ---------------------------------------------------------------------------
// split fp32 -> (hi, lo) bf16 pair.
// ---------------------------------------------------------------------------
__global__ __launch_bounds__(256)
void split2(const float* __restrict__ in, unsigned short* __restrict__ hi,
            unsigned short* __restrict__ lo, int n4)
{
    int i = blockIdx.x * 256 + threadIdx.x;
    int stride = gridDim.x * 256;
    for (; i < n4; i += stride) {
        float4 v = ((const float4*)in)[i];
        float f[4] = {v.x, v.y, v.z, v.w};
        unsigned short hh[4], ll[4];
#pragma unroll
        for (int j = 0; j < 4; j++) {
            hh[j] = f2bf(f[j]);
            ll[j] = f2bf(f[j] - bf2f(hh[j]));
        }
        ((ushort4*)hi)[i] = make_ushort4(hh[0], hh[1], hh[2], hh[3]);
        ((ushort4*)lo)[i] = make_ushort4(ll[0], ll[1], ll[2], ll[3]);
    }
}

// fp32 -> bf16 (hi only)
__global__ __launch_bounds__(256)
void splitb(const float* __restrict__ in, unsigned short* __restrict__ out, int n4)
{
    int i = blockIdx.x * 256 + threadIdx.x;
    int stride = gridDim.x * 256;
    for (; i < n4; i += stride) {
        float4 v = ((const float4*)in)[i];
        ((ushort4*)out)[i] = make_ushort4(f2bf(v.x), f2bf(v.y), f2bf(v.z), f2bf(v.w));
    }
}

// Transpose [R][C] -> bf16 [C][R], batched by blockIdx.z.
template<typename TIN>
__global__ __launch_bounds__(256)
void transb(const TIN* __restrict__ in, unsigned short* __restrict__ out, int R, int C)
{
    __shared__ float t[32][33];
    in  += (size_t)blockIdx.z * R * C;
    out += (size_t)blockIdx.z * R * C;
    int tx = threadIdx.x & 31, ty = threadIdx.x >> 5;
    int r0 = blockIdx.y * 32, c0 = blockIdx.x * 32;
#pragma unroll
    for (int j = 0; j < 4; j++) {
        TIN v = in[(size_t)(r0 + ty + j * 8) * C + c0 + tx];
        float f;
        if (sizeof(TIN) == 2) f = bf2f(*(const unsigned short*)&v);
        else                  f = *(const float*)&v;
        t[ty + j * 8][tx] = f;
    }
    __syncthreads();
#pragma unroll
    for (int j = 0; j < 4; j++)
        out[(size_t)(c0 + ty + j * 8) * R + r0 + tx] = f2bf(t[tx][ty + j * 8]);
}

// ---------------------------------------------------------------------------
// MFMA GEMM: C[m][n] = sum_k (A)(m,k) * (B)(n,k), A/B bf16 row-major K-contig.
// NT=3: A=(Ah+Al), B=(Bh+Bl), 3-term hi*hi+hi*lo+lo*hi (~fp32 accuracy).
// NT=1: straight bf16.
// 128x128 tile, BK=32, 4 waves (2x2 of 64x64), global_load_lds staging with
// XOR-swizzled k-segment (pre-swizzled global source, linear LDS dest).
// z decode: bz = z / kchunks (batch), kz = z % kchunks (K-chunk).
// Bases: A += bz*zA, B += bz*zB, C += bz*zC + kz*pz.
// EPI: 0 = store fp32
//      1 = store bf16( silu(clip(acc,-5,5)) )
//      2 = store fp32( silu(Gate[idx]) * acc )
// ---------------------------------------------------------------------------
template<int NT, int EPI>
__global__ __launch_bounds__(256)
void mg(const unsigned short* __restrict__ Ah, const unsigned short* __restrict__ Al,
        const unsigned short* __restrict__ Bh, const unsigned short* __restrict__ Bl,
        const float* __restrict__ Gate, void* __restrict__ Cv,
        int N, int K, int kchunks, long zA, long zB, long zC, long pz)
{
    constexpr int LSZ  = (NT == 3) ? 16384 : 8192;
    constexpr int BOFF = (NT == 3) ? 8192 : 4096;
    __shared__ __align__(16) unsigned short lds[LSZ];

    const int tid = threadIdx.x;
    const int l   = tid & 63;
    const int w   = tid >> 6;
    const int wr  = w >> 1, wc = w & 1;
    const int bm0 = blockIdx.y * 128, bn0 = blockIdx.x * 128;
    const int bz  = blockIdx.z / kchunks;
    const int kz  = blockIdx.z - bz * kchunks;
    const int kcnt = K / kchunks;
    const int kbeg = kz * kcnt;

    const unsigned short* A0 = Ah + (size_t)bz * zA;
    const unsigned short* B0 = Bh + (size_t)bz * zB;
    const unsigned short* A1 = Al ? Al + (size_t)bz * zA : nullptr;
    const unsigned short* B1 = Bl ? Bl + (size_t)bz * zB : nullptr;

    const int srow = tid >> 2;
    const int scol = (((tid & 3) ^ (srow & 3)) << 3);
    const size_t aoff0 = (size_t)(bm0 + srow) * K + scol;
    const size_t boff0 = (size_t)(bn0 + srow) * K + scol;
    const size_t rstep = (size_t)64 * K;
    unsigned short* ldsw = &lds[w << 9];

    const int cu = (((l >> 4) ^ (l & 3)) << 3);
    const int ra = (wr * 64 + (l & 15)) * 32 + cu;
    const int rb = (wc * 64 + (l & 15)) * 32 + cu;

    f32x4 acc[4][4];
#pragma unroll
    for (int i = 0; i < 4; i++)
#pragma unroll
        for (int j = 0; j < 4; j++) acc[i][j] = (f32x4){0.f, 0.f, 0.f, 0.f};

    for (int kt = kbeg; kt < kbeg + kcnt; kt += 32) {
        gl16(A0 + aoff0 + kt,         ldsw + 0);
        gl16(A0 + aoff0 + kt + rstep, ldsw + 2048);
        if (NT == 3) {
            gl16(A1 + aoff0 + kt,         ldsw + 4096);
            gl16(A1 + aoff0 + kt + rstep, ldsw + 4096 + 2048);
        }
        gl16(B0 + boff0 + kt,         ldsw + BOFF);
        gl16(B0 + boff0 + kt + rstep, ldsw + BOFF + 2048);
        if (NT == 3) {
            gl16(B1 + boff0 + kt,         ldsw + 12288);
            gl16(B1 + boff0 + kt + rstep, ldsw + 12288 + 2048);
        }
        __syncthreads();

        bfrag ah[4], bh[4];
#pragma unroll
        for (int f = 0; f < 4; f++) {
            ah[f] = *(const bfrag*)&lds[ra + f * 512];
            bh[f] = *(const bfrag*)&lds[BOFF + rb + f * 512];
        }
        if (NT == 3) {
            bfrag al2[4], bl2[4];
#pragma unroll
            for (int f = 0; f < 4; f++) {
                al2[f] = *(const bfrag*)&lds[4096 + ra + f * 512];
                bl2[f] = *(const bfrag*)&lds[12288 + rb + f * 512];
            }
#pragma unroll
            for (int i = 0; i < 4; i++)
#pragma unroll
                for (int j = 0; j < 4; j++) {
                    acc[i][j] = __builtin_amdgcn_mfma_f32_16x16x32_bf16(ah[i],  bh[j],  acc[i][j], 0, 0, 0);
                    acc[i][j] = __builtin_amdgcn_mfma_f32_16x16x32_bf16(ah[i],  bl2[j], acc[i][j], 0, 0, 0);
                    acc[i][j] = __builtin_amdgcn_mfma_f32_16x16x32_bf16(al2[i], bh[j],  acc[i][j], 0, 0, 0);
                }
        } else {
#pragma unroll
            for (int i = 0; i < 4; i++)
#pragma unroll
                for (int j = 0; j < 4; j++)
                    acc[i][j] = __builtin_amdgcn_mfma_f32_16x16x32_bf16(ah[i], bh[j], acc[i][j], 0, 0, 0);
        }
        __syncthreads();
    }

    // C/D layout: col = lane&15, row = (lane>>4)*4 + reg
    const int crow0 = bm0 + wr * 64 + (l >> 4) * 4;
    const int ccol0 = bn0 + wc * 64 + (l & 15);
    float*          Cf = (float*)Cv          + (size_t)bz * zC + (size_t)kz * pz;
    unsigned short* Cb = (unsigned short*)Cv + (size_t)bz * zC;
#pragma unroll
    for (int i = 0; i < 4; i++)
#pragma unroll
        for (int j = 0; j < 4; j++)
#pragma unroll
            for (int r = 0; r < 4; r++) {
                size_t idx = (size_t)(crow0 + i * 16 + r) * N + (ccol0 + j * 16);
                float v = acc[i][j][r];
                if (EPI == 0) Cf[idx] = v;
                else if (EPI == 1)
                    Cb[idx] = f2bf(silu_f(fminf(fmaxf(v, -5.f), 5.f)));
                else if (EPI == 2) Cf[idx] = silu_f(Gate[idx]) * v;
            }
}

// ---------------------------------------------------------------------------
// Final fused GEMM over the same C tile [4096][1024]:
//   out = (hh+hl)@(dwh+dwl)^T  (3-term, K=2048)
//       + adapt01@kd^T         (1-term, K=128; adapt01 pre-scaled by 0.1)
//       + mixed@wf^T           (1-term, K=128)
// ---------------------------------------------------------------------------
__global__ __launch_bounds__(256)
void gfinal(const unsigned short* __restrict__ hh, const unsigned short* __restrict__ hl,
            const unsigned short* __restrict__ dwh, const unsigned short* __restrict__ dwl,
            const unsigned short* __restrict__ ad, const unsigned short* __restrict__ kd,
            const unsigned short* __restrict__ mx, const unsigned short* __restrict__ wfb,
            float* __restrict__ out)
{
    __shared__ __align__(16) unsigned short lds[16384];
    const int tid = threadIdx.x;
    const int l   = tid & 63;
    const int w   = tid >> 6;
    const int wr  = w >> 1, wc = w & 1;
    const int bm0 = blockIdx.y * 128, bn0 = blockIdx.x * 128;

    const int srow = tid >> 2;
    const int scol = (((tid & 3) ^ (srow & 3)) << 3);
    unsigned short* ldsw = &lds[w << 9];
    const int cu = (((l >> 4) ^ (l & 3)) << 3);
    const int ra = (wr * 64 + (l & 15)) * 32 + cu;
    const int rb = (wc * 64 + (l & 15)) * 32 + cu;

    f32x4 acc[4][4];
#pragma unroll
    for (int i = 0; i < 4; i++)
#pragma unroll
        for (int j = 0; j < 4; j++) acc[i][j] = (f32x4){0.f, 0.f, 0.f, 0.f};

    // ---- main: 3-term over K=2048 ----
    {
        const size_t aoff0 = (size_t)(bm0 + srow) * Hq + scol;
        const size_t boff0 = (size_t)(bn0 + srow) * Hq + scol;
        const size_t rstep = (size_t)64 * Hq;
        for (int kt = 0; kt < Hq; kt += 32) {
            gl16(hh  + aoff0 + kt,         ldsw + 0);
            gl16(hh  + aoff0 + kt + rstep, ldsw + 2048);
            gl16(hl  + aoff0 + kt,         ldsw + 4096);
            gl16(hl  + aoff0 + kt + rstep, ldsw + 4096 + 2048);
            gl16(dwh + boff0 + kt,         ldsw + 8192);
            gl16(dwh + boff0 + kt + rstep, ldsw + 8192 + 2048);
            gl16(dwl + boff0 + kt,         ldsw + 12288);
            gl16(dwl + boff0 + kt + rstep, ldsw + 12288 + 2048);
            __syncthreads();
            bfrag ah[4], al2[4], bh[4], bl2[4];
#pragma unroll
            for (int f = 0; f < 4; f++) {
                ah[f]  = *(const bfrag*)&lds[        ra + f * 512];
                al2[f] = *(const bfrag*)&lds[ 4096 + ra + f * 512];
                bh[f]  = *(const bfrag*)&lds[ 8192 + rb + f * 512];
                bl2[f] = *(const bfrag*)&lds[12288 + rb + f * 512];
            }
#pragma unroll
            for (int i = 0; i < 4; i++)
#pragma unroll
                for (int j = 0; j < 4; j++) {
                    acc[i][j] = __builtin_amdgcn_mfma_f32_16x16x32_bf16(ah[i],  bh[j],  acc[i][j], 0, 0, 0);
                    acc[i][j] = __builtin_amdgcn_mfma_f32_16x16x32_bf16(ah[i],  bl2[j], acc[i][j], 0, 0, 0);
                    acc[i][j] = __builtin_amdgcn_mfma_f32_16x16x32_bf16(al2[i], bh[j],  acc[i][j], 0, 0, 0);
                }
            __syncthreads();
        }
    }
    // ---- tails: 1-term over K=128 ----
#pragma unroll 1
    for (int t = 0; t < 2; t++) {
        const unsigned short* Ap = t == 0 ? ad : mx;
        const unsigned short* Bp = t == 0 ? kd : wfb;
        const size_t aoff0 = (size_t)(bm0 + srow) * Aq + scol;
        const size_t boff0 = (size_t)(bn0 + srow) * Aq + scol;
        const size_t rstep = (size_t)64 * Aq;
        for (int kt = 0; kt < Aq; kt += 32) {
            gl16(Ap + aoff0 + kt,         ldsw + 0);
            gl16(Ap + aoff0 + kt + rstep, ldsw + 2048);
            gl16(Bp + boff0 + kt,         ldsw + 8192);
            gl16(Bp + boff0 + kt + rstep, ldsw + 8192 + 2048);
            __syncthreads();
            bfrag ah[4], bh[4];
#pragma unroll
            for (int f = 0; f < 4; f++) {
                ah[f] = *(const bfrag*)&lds[       ra + f * 512];
                bh[f] = *(const bfrag*)&lds[8192 + rb + f * 512];
            }
#pragma unroll
            for (int i = 0; i < 4; i++)
#pragma unroll
                for (int j = 0; j < 4; j++)
                    acc[i][j] = __builtin_amdgcn_mfma_f32_16x16x32_bf16(ah[i], bh[j], acc[i][j], 0, 0, 0);
            __syncthreads();
        }
    }

    const int crow0 = bm0 + wr * 64 + (l >> 4) * 4;
    const int ccol0 = bn0 + wc * 64 + (l & 15);
#pragma unroll
    for (int i = 0; i < 4; i++)
#pragma unroll
        for (int j = 0; j < 4; j++)
#pragma unroll
            for (int r = 0; r < 4; r++)
                out[(size_t)(crow0 + i * 16 + r) * Dq + ccol0 + j * 16] = acc[i][j][r];
}

// Reduce NZ split-K partials + LayerNorm over A=128 -> (hi,lo) bf16.
template<int NZ>
__global__ __launch_bounds__(256)
void rln(const float* __restrict__ p, unsigned short* __restrict__ oh,
         unsigned short* __restrict__ ol, const float* __restrict__ g,
         const float* __restrict__ b, long pstride)
{
    int row  = blockIdx.x * 4 + (threadIdx.x >> 6);
    int lane = threadIdx.x & 63;
    long base = (long)row * Aq;
    float x0 = 0.f, x1 = 0.f;
#pragma unroll
    for (int z = 0; z < NZ; z++) {
        x0 += p[base + z * pstride + lane];
        x1 += p[base + z * pstride + lane + 64];
    }
    float s  = x0 + x1;
    float ss = x0 * x0 + x1 * x1;
#pragma unroll
    for (int off = 32; off > 0; off >>= 1) {
        s  += __shfl_xor(s, off);
        ss += __shfl_xor(ss, off);
    }
    float m  = s * (1.0f / Aq);
    float v  = ss * (1.0f / Aq) - m * m;
    float rs = rsqrtf(v + 1e-5f);
    float y0 = (x0 - m) * rs * g[lane]      + b[lane];
    float y1 = (x1 - m) * rs * g[lane + 64] + b[lane + 64];
    unsigned short h0 = f2bf(y0), h1 = f2bf(y1);
    oh[base + lane]      = h0;
    oh[base + lane + 64] = h1;
    ol[base + lane]      = f2bf(y0 - bf2f(h0));
    ol[base + lane + 64] = f2bf(y1 - bf2f(h1));
}

// Reduce NZ split-K partials (with per-batch layout [bz][kz][rowsPerB][A]) -> scaled bf16.
template<int NZ>
__global__ __launch_bounds__(256)
void rbf(const float* __restrict__ p, unsigned short* __restrict__ o,
         int rowsPerB, float scale, int total)
{
    int i = blockIdx.x * 256 + threadIdx.x;
    if (i >= total) return;
    int n = i >> 7, a = i & 127;
    int bz = n / rowsPerB, s = n - bz * rowsPerB;
    long base = ((long)bz * NZ) * rowsPerB * Aq + (long)s * Aq + a;
    float acc = 0.f;
#pragma unroll
    for (int z = 0; z < NZ; z++) acc += p[base + (long)z * rowsPerB * Aq];
    o[i] = f2bf(acc * scale);
}

// mixed[n,:] = sum_e ew[n,e] * LN_e(h[e,n,:])  -> bf16
__global__ __launch_bounds__(256)
void mix_ln(const float* __restrict__ h, const float* __restrict__ ew,
            const float* __restrict__ g, const float* __restrict__ bb,
            unsigned short* __restrict__ mixed)
{
    int n    = blockIdx.x * 4 + (threadIdx.x >> 6);
    int lane = threadIdx.x & 63;
    float a0 = 0.0f, a1 = 0.0f;
#pragma unroll
    for (int e = 0; e < Eq; e++) {
        const float* r = h + ((long)e * Nq + n) * Aq;
        float x0 = r[lane], x1 = r[lane + 64];
        float s  = x0 + x1;
        float ss = x0 * x0 + x1 * x1;
#pragma unroll
        for (int off = 32; off > 0; off >>= 1) {
            s  += __shfl_xor(s, off);
            ss += __shfl_xor(ss, off);
        }
        float m  = s * (1.0f / Aq);
        float v  = ss * (1.0f / Aq) - m * m;
        float rs = rsqrtf(v + 1e-5f);
        float wv = ew[(long)n * Eq + e];
        a0 += wv * ((x0 - m) * rs * g[e * Aq + lane]      + bb[e * Aq + lane]);
        a1 += wv * ((x1 - m) * rs * g[e * Aq + lane + 64] + bb[e * Aq + lane + 64]);
    }
    mixed[(long)n * Aq + lane]      = f2bf(a0);
    mixed[(long)n * Aq + lane + 64] = f2bf(a1);
}

extern "C" void kernel_launch(void* const* d_in, const int* in_sizes, int n_in,
                              void* d_out, int out_size, void* d_ws, size_t ws_size,
                              hipStream_t stream)
{
    const float* x             = (const float*)d_in[0];
    const float* ew            = (const float*)d_in[1];
    const float* up_w          = (const float*)d_in[2];
    const float* gate_w        = (const float*)d_in[3];
    const float* down_w        = (const float*)d_in[4];
    const float* pre_w         = (const float*)d_in[5];
    const float* post_w        = (const float*)d_in[6];
    const float* an_g          = (const float*)d_in[7];
    const float* an_b          = (const float*)d_in[8];
    const float* adapt_proj_w  = (const float*)d_in[9];
    const float* adapter_w     = (const float*)d_in[10];
    const float* adapter_g     = (const float*)d_in[11];
    const float* adapter_b     = (const float*)d_in[12];
    const float* expert_proj_w = (const float*)d_in[13];
    const float* output_proj_w = (const float*)d_in[14];
    float* out = (float*)d_out;

    // ---- workspace layout (KB offsets, lifetimes aliased; peak ~111.3 MB) ----
#define OFF(kb) ((char*)d_ws + (size_t)(kb) * 1024)
    float* wfp    = (float*)OFF(0);           // [4][1024][128] 2MB   (early)
    float* kdp    = (float*)OFF(2048);        // 2MB                  (early)
    float* gate   = (float*)OFF(0);           // [N,H] 32MB           (3a-3b)
    float* h_e    = (float*)OFF(0);           // [E][N][A] 16MB       (post-3b)
    float* p3     = (float*)OFF(16384);       // [2][4][S][A] 8MB     (post-3b)
    unsigned short* adapt01 = (unsigned short*)OFF(24576);  // [N][A] 1MB
    unsigned short* mixedb  = (unsigned short*)OFF(25600);  // [N][A] 1MB
    float* p1     = (float*)OFF(32768);       // [4][N][A] 8MB        (early)
    unsigned short* oph = (unsigned short*)OFF(40960);      // [D][H] 4MB (early)
    unsigned short* apT = (unsigned short*)OFF(45056);      // [A][H] .5MB (early)
    unsigned short* epT = (unsigned short*)OFF(45568);      // [A][H] .5MB (early)
    float* hidden = (float*)OFF(32768);       // [N,H] 32MB           (3b-split)
    unsigned short* wmat = (unsigned short*)OFF(32768);     // [B][S][S] bf16 16MB (post-split)
    float* p2     = (float*)OFF(49152);       // [4][N][A] 8MB        (post-split)
    unsigned short* xh  = (unsigned short*)OFF(65536);      // 8MB
    unsigned short* xl  = (unsigned short*)OFF(73728);      // 8MB
    unsigned short* hh  = (unsigned short*)OFF(65536);      // [N,H] 16MB (post-3b)
    unsigned short* gwh = (unsigned short*)OFF(81920);
    unsigned short* gwl = (unsigned short*)OFF(86016);
    unsigned short* uwh = (unsigned short*)OFF(90112);
    unsigned short* uwl = (unsigned short*)OFF(94208);
    unsigned short* hl  = (unsigned short*)OFF(81920);      // [N,H] 16MB (post-3b)
    unsigned short* dwh = (unsigned short*)OFF(98304);
    unsigned short* dwl = (unsigned short*)OFF(102400);
    unsigned short* pwh = (unsigned short*)OFF(106496);     // .25MB
    unsigned short* pwl = (unsigned short*)OFF(106752);
    unsigned short* powh= (unsigned short*)OFF(107008);     // .5MB
    unsigned short* powl= (unsigned short*)OFF(107520);
    unsigned short* ainh= (unsigned short*)OFF(108032);     // 1MB
    unsigned short* ainl= (unsigned short*)OFF(109056);
    unsigned short* aouth=(unsigned short*)OFF(110080);
    unsigned short* aoutl=(unsigned short*)OFF(111104);
    unsigned short* ainT= (unsigned short*)OFF(112128);     // [B][A][S] 1MB
    unsigned short* adw = (unsigned short*)OFF(113152);     // [E][A][A] .25MB
    unsigned short* wfb = (unsigned short*)OFF(113408);     // [D][A] .25MB
    unsigned short* kdb = (unsigned short*)OFF(113664);     // [D][A] .25MB
#undef OFF

    dim3 blk(256);
    const long NA = (long)Nq * Aq;       // 524288
    const long SA = (long)Sq * Aq;       // 262144
    const long SS = (long)Sq * Sq;       // 4194304

    // ---- conversions (early) ----
    split2<<<dim3(4096), blk, 0, stream>>>(x,      xh,  xl,  Nq * Dq / 4);
    split2<<<dim3(2048), blk, 0, stream>>>(gate_w, gwh, gwl, Hq * Dq / 4);
    split2<<<dim3(2048), blk, 0, stream>>>(up_w,   uwh, uwl, Hq * Dq / 4);
    split2<<<dim3(2048), blk, 0, stream>>>(down_w, dwh, dwl, Dq * Hq / 4);
    split2<<<dim3(128),  blk, 0, stream>>>(pre_w,  pwh, pwl, Aq * Dq / 4);
    split2<<<dim3(256),  blk, 0, stream>>>(post_w, powh, powl, Aq * Hq / 4);
    splitb<<<dim3(2048), blk, 0, stream>>>(output_proj_w, oph, Dq * Hq / 4);
    splitb<<<dim3(128),  blk, 0, stream>>>(adapter_w, adw, Eq * Aq * Aq / 4);
    transb<float><<<dim3(4, 64, 1), blk, 0, stream>>>(adapt_proj_w,  apT, Hq, Aq);
    transb<float><<<dim3(4, 64, 1), blk, 0, stream>>>(expert_proj_w, epT, Hq, Aq);

    // ---- weight fusions: wf = op@ep, Kd = down@adapt_proj (1-term, split-K 4) ----
    mg<1, 0><<<dim3(1, 8, 4), blk, 0, stream>>>(oph, nullptr, epT, nullptr, nullptr,
        wfp, Aq, Hq, 4, 0, 0, 0, (long)Dq * Aq);
    mg<1, 0><<<dim3(1, 8, 4), blk, 0, stream>>>(dwh, nullptr, apT, nullptr, nullptr,
        kdp, Aq, Hq, 4, 0, 0, 0, (long)Dq * Aq);
    rbf<4><<<dim3(512), blk, 0, stream>>>(wfp, wfb, Dq, 1.0f, Dq * Aq);
    // FIX(round3): scale 1.0 here — the 0.1 is applied once, on adapt01 below.
    rbf<4><<<dim3(512), blk, 0, stream>>>(kdp, kdb, Dq, 1.0f, Dq * Aq);

    // ---- steps 1-2: ain = LN(x @ pre_w^T)  (3-term, split-K 4) ----
    mg<3, 0><<<dim3(1, 32, 4), blk, 0, stream>>>(xh, xl, pwh, pwl, nullptr,
        p1, Aq, Dq, 4, 0, 0, 0, NA);
    rln<4><<<dim3(1024), blk, 0, stream>>>(p1, ainh, ainl, an_g, an_b, NA);
    transb<unsigned short><<<dim3(4, 64, 2), blk, 0, stream>>>(ainh, ainT, Sq, Aq);

    // ---- step 3: SwiGLU ----
    mg<3, 0><<<dim3(16, 32, 1), blk, 0, stream>>>(xh, xl, gwh, gwl, nullptr,
        gate, Hq, Dq, 1, 0, 0, 0, 0);
    mg<3, 2><<<dim3(16, 32, 1), blk, 0, stream>>>(xh, xl, uwh, uwl, gate,
        hidden, Hq, Dq, 1, 0, 0, 0, 0);
    split2<<<dim3(4096), blk, 0, stream>>>(hidden, hh, hl, Nq * Hq / 4);

    // ---- steps 4-5: aout = LN(hidden @ post_w^T)  (3-term, split-K 4) ----
    mg<3, 0><<<dim3(1, 32, 4), blk, 0, stream>>>(hh, hl, powh, powl, nullptr,
        p2, Aq, Hq, 4, 0, 0, 0, NA);
    rln<4><<<dim3(1024), blk, 0, stream>>>(p2, aouth, aoutl, an_g, an_b, NA);

    // ---- step 6: wmat = bf16(silu(clip(ain @ aout^T)))  per batch ----
    mg<3, 1><<<dim3(16, 16, 2), blk, 0, stream>>>(ainh, ainl, aouth, aoutl, nullptr,
        wmat, Sq, Aq, 1, SA, SA, SS, 0);

    // ---- step 7: adapt01 = 0.1 * (wmat @ ain)  (1-term, split-K 4, batched) ----
    mg<1, 0><<<dim3(1, 16, 8), blk, 0, stream>>>(wmat, nullptr, ainT, nullptr, nullptr,
        p3, Aq, Sq, 4, SS, SA, 4 * SA, SA);
    rbf<4><<<dim3(2048), blk, 0, stream>>>(p3, adapt01, Sq, 0.1f, Nq * Aq);

    // ---- expert path: h_e, mixed ----
    mg<1, 0><<<dim3(1, 32, 8), blk, 0, stream>>>(ainh, nullptr, adw, nullptr, nullptr,
        h_e, Aq, Aq, 1, 0, (long)Aq * Aq, NA, 0);
    mix_ln<<<dim3(1024), blk, 0, stream>>>(h_e, ew, adapter_g, adapter_b, mixedb);

    // ---- final fused: out = hid@down^T + adapt01@Kd^T + mixed@wf^T ----
    gfinal<<<dim3(8, 32), blk, 0, stream>>>(hh, hl, dwh, dwl,
        adapt01, kdb, mixedb, wfb, out);
}

// Round 6
// 302.212 us; speedup vs baseline: 3.7942x; 1.3259x over previous
//
#include <hip/hip_runtime.h>
#include <hip/hip_bf16.h>
#include <math.h>

// Problem constants (B,S,D,E = 2,2048,1024,8)
#define Bq 2
#define Sq 2048
#define Dq 1024
#define Eq 8
#define Hq 2048            // 2*D
#define Aq 128             // H/16
#define Nq (Bq*Sq)         // 4096 tokens

typedef __attribute__((ext_vector_type(4))) float f32x4;
typedef __attribute__((ext_vector_type(8))) short bfrag;   // 8 bf16 in 4 VGPRs

__device__ __forceinline__ float silu_f(float x) {
    return x / (1.0f + expf(-x));
}
__device__ __forceinline__ unsigned short f2bf(float x) {  // RNE fp32->bf16
    unsigned u = __float_as_uint(x);
    u += 0x7fffu + ((u >> 16) & 1u);
    return (unsigned short)(u >> 16);
}
__device__ __forceinline__ float bf2f(unsigned short h) {
    return __uint_as_float(((unsigned)h) << 16);
}
__device__ __forceinline__ void gl16(const unsigned short* g, unsigned short* l) {
    __builtin_amdgcn_global_load_lds(
        (const __attribute__((address_space(1))) void*)g,
        (__attribute__((address_space(3))) void*)(void*)l, 16, 0, 0);
}

// ---------------------------------------------------------------------------
// One-shot conversion of all inputs: fp32 -> (hi,lo) bf16 (or hi only).
// Segments (float4 units): x 1048576 | gw 524288 | uw 524288 | dw 524288
//                        | pw 32768 | pow 65536 | opw(hi) 524288 | aw(hi) 32768
// Total = 3276800.   (round-5 bug: x was 262144 -> 3/4 of x unconverted)
// ---------------------------------------------------------------------------
__global__ __launch_bounds__(256)
void convert_all(const float* __restrict__ x,  const float* __restrict__ gw,
                 const float* __restrict__ uw, const float* __restrict__ dw,
                 const float* __restrict__ pw, const float* __restrict__ ow,
                 const float* __restrict__ opw, const float* __restrict__ aw,
                 unsigned short* xh,  unsigned short* xl,
                 unsigned short* gwh, unsigned short* gwl,
                 unsigned short* uwh, unsigned short* uwl,
                 unsigned short* dwh, unsigned short* dwl,
                 unsigned short* pwh, unsigned short* pwl,
                 unsigned short* owh, unsigned short* owl,
                 unsigned short* oph, unsigned short* adw)
{
    const int T = 3276800;
    for (int i = blockIdx.x * 256 + threadIdx.x; i < T; i += gridDim.x * 256) {
        const float* in; unsigned short *hi, *lo; int j = i;
        if (j < 1048576)                 { in = x;   hi = xh;  lo = xl;  }
        else if ((j -= 1048576) < 524288){ in = gw;  hi = gwh; lo = gwl; }
        else if ((j -= 524288) < 524288) { in = uw;  hi = uwh; lo = uwl; }
        else if ((j -= 524288) < 524288) { in = dw;  hi = dwh; lo = dwl; }
        else if ((j -= 524288) < 32768)  { in = pw;  hi = pwh; lo = pwl; }
        else if ((j -= 32768) < 65536)   { in = ow;  hi = owh; lo = owl; }
        else if ((j -= 65536) < 524288)  { in = opw; hi = oph; lo = nullptr; }
        else { j -= 524288;                in = aw;  hi = adw; lo = nullptr; }
        float4 v = ((const float4*)in)[j];
        float f[4] = {v.x, v.y, v.z, v.w};
        unsigned short hh4[4];
#pragma unroll
        for (int k = 0; k < 4; k++) hh4[k] = f2bf(f[k]);
        ((ushort4*)hi)[j] = make_ushort4(hh4[0], hh4[1], hh4[2], hh4[3]);
        if (lo) {
            unsigned short ll4[4];
#pragma unroll
            for (int k = 0; k < 4; k++) ll4[k] = f2bf(f[k] - bf2f(hh4[k]));
            ((ushort4*)lo)[j] = make_ushort4(ll4[0], ll4[1], ll4[2], ll4[3]);
        }
    }
}

// Transpose [R][C] -> bf16 [C][R], batched by blockIdx.z.
template<typename TIN>
__global__ __launch_bounds__(256)
void transb(const TIN* __restrict__ in, unsigned short* __restrict__ out, int R, int C)
{
    __shared__ float t[32][33];
    in  += (size_t)blockIdx.z * R * C;
    out += (size_t)blockIdx.z * R * C;
    int tx = threadIdx.x & 31, ty = threadIdx.x >> 5;
    int r0 = blockIdx.y * 32, c0 = blockIdx.x * 32;
#pragma unroll
    for (int j = 0; j < 4; j++) {
        TIN v = in[(size_t)(r0 + ty + j * 8) * C + c0 + tx];
        float f;
        if (sizeof(TIN) == 2) f = bf2f(*(const unsigned short*)&v);
        else                  f = *(const float*)&v;
        t[ty + j * 8][tx] = f;
    }
    __syncthreads();
#pragma unroll
    for (int j = 0; j < 4; j++)
        out[(size_t)(c0 + ty + j * 8) * R + r0 + tx] = f2bf(t[tx][ty + j * 8]);
}

// ---------------------------------------------------------------------------
// MFMA GEMM with double-buffered 2-phase pipeline (stage(t+1) || compute(t)):
//   C[m][n] = sum_k A(m,k)*B(n,k), bf16 row-major K-contig operands.
// NT=3: 3-term split (hi*hi + hi*lo + lo*hi) ~fp32 accuracy. NT=1: plain bf16.
// 128x128 tile, BK=32, 4 waves; global_load_lds w=16, XOR-swizzled k-segment.
// SWZ: XCD-aware bijective blockIdx swizzle (requires gridDim.x*y % 8 == 0).
// z decode: bz = z / kchunks (batch), kz = z % kchunks (split-K chunk).
// EPI: 0 = fp32 store to C0 + bz*zC + kz*pz
//      1 = bf16 store silu(clip(acc,-5,5)) to C0 + bz*zC
//      2 = o = silu(Gate[idx])*acc; C0=bf16 hi(o), C1=bf16 lo(o)   (SwiGLU+split)
// ---------------------------------------------------------------------------
template<int NT, int EPI, bool SWZ>
__global__ __launch_bounds__(256)
void mg(const unsigned short* __restrict__ Ah, const unsigned short* __restrict__ Al,
        const unsigned short* __restrict__ Bh, const unsigned short* __restrict__ Bl,
        const float* __restrict__ Gate, void* __restrict__ C0, void* __restrict__ C1,
        int N, int K, int kchunks, long zA, long zB, long zC, long pz)
{
    constexpr int BUFU = (NT == 3) ? 16384 : 8192;   // ushorts per buffer
    constexpr int BOFF = (NT == 3) ? 8192 : 4096;    // B tile offset in buffer
    __shared__ __align__(16) unsigned short lds[2 * BUFU];

    const int tid = threadIdx.x;
    const int l   = tid & 63;
    const int w   = tid >> 6;
    const int wr  = w >> 1, wc = w & 1;

    int bx = blockIdx.x, by = blockIdx.y;
    if (SWZ) {
        int nb  = gridDim.x * gridDim.y;
        int id  = by * gridDim.x + bx;
        int id2 = (id & 7) * (nb >> 3) + (id >> 3);   // bijective, nb%8==0
        bx = id2 % gridDim.x;
        by = id2 / gridDim.x;
    }
    const int bm0 = by * 128, bn0 = bx * 128;
    const int bz  = blockIdx.z / kchunks;
    const int kz  = blockIdx.z - bz * kchunks;
    const int kcnt = K / kchunks;
    const int kbeg = kz * kcnt;
    const int kend = kbeg + kcnt;

    const unsigned short* A0 = Ah + (size_t)bz * zA;
    const unsigned short* B0 = Bh + (size_t)bz * zB;
    const unsigned short* A1 = (NT == 3) ? Al + (size_t)bz * zA : nullptr;
    const unsigned short* B1 = (NT == 3) ? Bl + (size_t)bz * zB : nullptr;

    const int srow = tid >> 2;
    const int scol = (((tid & 3) ^ (srow & 3)) << 3);
    const size_t aoff0 = (size_t)(bm0 + srow) * K + scol;
    const size_t boff0 = (size_t)(bn0 + srow) * K + scol;
    const size_t rstep = (size_t)64 * K;

    const int cu = (((l >> 4) ^ (l & 3)) << 3);
    const int ra = (wr * 64 + (l & 15)) * 32 + cu;
    const int rb = (wc * 64 + (l & 15)) * 32 + cu;

    auto stage = [&](int b, int kt) {
        unsigned short* d = &lds[b * BUFU + (w << 9)];
        gl16(A0 + aoff0 + kt,         d + 0);
        gl16(A0 + aoff0 + kt + rstep, d + 2048);
        if (NT == 3) {
            gl16(A1 + aoff0 + kt,         d + 4096);
            gl16(A1 + aoff0 + kt + rstep, d + 6144);
        }
        gl16(B0 + boff0 + kt,         d + BOFF);
        gl16(B0 + boff0 + kt + rstep, d + BOFF + 2048);
        if (NT == 3) {
            gl16(B1 + boff0 + kt,         d + 12288);
            gl16(B1 + boff0 + kt + rstep, d + 14336);
        }
    };

    f32x4 acc[4][4];
#pragma unroll
    for (int i = 0; i < 4; i++)
#pragma unroll
        for (int j = 0; j < 4; j++) acc[i][j] = (f32x4){0.f, 0.f, 0.f, 0.f};

    stage(0, kbeg);
    __syncthreads();                 // buf0 ready
    int cur = 0;
    for (int kt = kbeg; kt < kend; kt += 32) {
        if (kt + 32 < kend) stage(cur ^ 1, kt + 32);   // loads fly during compute
        const int cb = cur * BUFU;
        bfrag ah[4], bh[4];
#pragma unroll
        for (int f = 0; f < 4; f++) {
            ah[f] = *(const bfrag*)&lds[cb + ra + f * 512];
            bh[f] = *(const bfrag*)&lds[cb + BOFF + rb + f * 512];
        }
        if (NT == 3) {
            bfrag al2[4], bl2[4];
#pragma unroll
            for (int f = 0; f < 4; f++) {
                al2[f] = *(const bfrag*)&lds[cb + 4096 + ra + f * 512];
                bl2[f] = *(const bfrag*)&lds[cb + 12288 + rb + f * 512];
            }
#pragma unroll
            for (int i = 0; i < 4; i++)
#pragma unroll
                for (int j = 0; j < 4; j++) {
                    acc[i][j] = __builtin_amdgcn_mfma_f32_16x16x32_bf16(ah[i],  bh[j],  acc[i][j], 0, 0, 0);
                    acc[i][j] = __builtin_amdgcn_mfma_f32_16x16x32_bf16(ah[i],  bl2[j], acc[i][j], 0, 0, 0);
                    acc[i][j] = __builtin_amdgcn_mfma_f32_16x16x32_bf16(al2[i], bh[j],  acc[i][j], 0, 0, 0);
                }
        } else {
#pragma unroll
            for (int i = 0; i < 4; i++)
#pragma unroll
                for (int j = 0; j < 4; j++)
                    acc[i][j] = __builtin_amdgcn_mfma_f32_16x16x32_bf16(ah[i], bh[j], acc[i][j], 0, 0, 0);
        }
        __syncthreads();             // drains next-tile vmcnt; all reads of cur done
        cur ^= 1;
    }

    // C/D layout: col = lane&15, row = (lane>>4)*4 + reg
    const int crow0 = bm0 + wr * 64 + (l >> 4) * 4;
    const int ccol0 = bn0 + wc * 64 + (l & 15);
#pragma unroll
    for (int i = 0; i < 4; i++)
#pragma unroll
        for (int j = 0; j < 4; j++)
#pragma unroll
            for (int r = 0; r < 4; r++) {
                size_t idx = (size_t)(crow0 + i * 16 + r) * N + (ccol0 + j * 16);
                float v = acc[i][j][r];
                if (EPI == 0) {
                    ((float*)C0 + (size_t)bz * zC + (size_t)kz * pz)[idx] = v;
                } else if (EPI == 1) {
                    ((unsigned short*)C0 + (size_t)bz * zC)[idx] =
                        f2bf(silu_f(fminf(fmaxf(v, -5.f), 5.f)));
                } else {
                    float o = silu_f(Gate[idx]) * v;
                    unsigned short h = f2bf(o);
                    ((unsigned short*)C0)[idx] = h;
                    ((unsigned short*)C1)[idx] = f2bf(o - bf2f(h));
                }
            }
}

// ---------------------------------------------------------------------------
// Final fused GEMM, double-buffered:  out[4096][1024] =
//   (hh+hl)@(dwh+dwl)^T  (3-term, K=2048)  +  acat@kcat^T  (1-term, K=256)
// where acat=[0.1*adapt | mixed], kcat=[down@adapt_proj | op@ep].
// ---------------------------------------------------------------------------
__global__ __launch_bounds__(256)
void gfinal(const unsigned short* __restrict__ hh, const unsigned short* __restrict__ hl,
            const unsigned short* __restrict__ dwh, const unsigned short* __restrict__ dwl,
            const unsigned short* __restrict__ acat, const unsigned short* __restrict__ kcat,
            float* __restrict__ out)
{
    __shared__ __align__(16) unsigned short lds[32768];   // 2 bufs x 16384
    const int tid = threadIdx.x;
    const int l   = tid & 63;
    const int w   = tid >> 6;
    const int wr  = w >> 1, wc = w & 1;

    int nb  = gridDim.x * gridDim.y;                      // 256
    int id  = blockIdx.y * gridDim.x + blockIdx.x;
    int id2 = (id & 7) * (nb >> 3) + (id >> 3);
    int bx  = id2 % gridDim.x, by = id2 / gridDim.x;
    const int bm0 = by * 128, bn0 = bx * 128;

    const int srow = tid >> 2;
    const int scol = (((tid & 3) ^ (srow & 3)) << 3);
    const int cu = (((l >> 4) ^ (l & 3)) << 3);
    const int ra = (wr * 64 + (l & 15)) * 32 + cu;
    const int rb = (wc * 64 + (l & 15)) * 32 + cu;

    f32x4 acc[4][4];
#pragma unroll
    for (int i = 0; i < 4; i++)
#pragma unroll
        for (int j = 0; j < 4; j++) acc[i][j] = (f32x4){0.f, 0.f, 0.f, 0.f};

    // ---- main: 3-term, K=2048 ----
    {
        const size_t aoff0 = (size_t)(bm0 + srow) * Hq + scol;
        const size_t boff0 = (size_t)(bn0 + srow) * Hq + scol;
        const size_t rstep = (size_t)64 * Hq;
        auto stage = [&](int b, int kt) {
            unsigned short* d = &lds[b * 16384 + (w << 9)];
            gl16(hh  + aoff0 + kt,         d + 0);
            gl16(hh  + aoff0 + kt + rstep, d + 2048);
            gl16(hl  + aoff0 + kt,         d + 4096);
            gl16(hl  + aoff0 + kt + rstep, d + 6144);
            gl16(dwh + boff0 + kt,         d + 8192);
            gl16(dwh + boff0 + kt + rstep, d + 10240);
            gl16(dwl + boff0 + kt,         d + 12288);
            gl16(dwl + boff0 + kt + rstep, d + 14336);
        };
        stage(0, 0);
        __syncthreads();
        int cur = 0;
        for (int kt = 0; kt < Hq; kt += 32) {
            if (kt + 32 < Hq) stage(cur ^ 1, kt + 32);
            const int cb = cur * 16384;
            bfrag ah[4], al2[4], bh[4], bl2[4];
#pragma unroll
            for (int f = 0; f < 4; f++) {
                ah[f]  = *(const bfrag*)&lds[cb +         ra + f * 512];
                al2[f] = *(const bfrag*)&lds[cb +  4096 + ra + f * 512];
                bh[f]  = *(const bfrag*)&lds[cb +  8192 + rb + f * 512];
                bl2[f] = *(const bfrag*)&lds[cb + 12288 + rb + f * 512];
            }
#pragma unroll
            for (int i = 0; i < 4; i++)
#pragma unroll
                for (int j = 0; j < 4; j++) {
                    acc[i][j] = __builtin_amdgcn_mfma_f32_16x16x32_bf16(ah[i],  bh[j],  acc[i][j], 0, 0, 0);
                    acc[i][j] = __builtin_amdgcn_mfma_f32_16x16x32_bf16(ah[i],  bl2[j], acc[i][j], 0, 0, 0);
                    acc[i][j] = __builtin_amdgcn_mfma_f32_16x16x32_bf16(al2[i], bh[j],  acc[i][j], 0, 0, 0);
                }
            __syncthreads();
            cur ^= 1;
        }
    }
    // ---- tail: 1-term, K=256 over [acat | kcat] ----
    {
        const size_t a2 = (size_t)(bm0 + srow) * 256 + scol;
        const size_t b2 = (size_t)(bn0 + srow) * 256 + scol;
        const size_t rstep2 = (size_t)64 * 256;
        auto stage2 = [&](int b, int kt) {
            unsigned short* d = &lds[b * 16384 + (w << 9)];
            gl16(acat + a2 + kt,          d + 0);
            gl16(acat + a2 + kt + rstep2, d + 2048);
            gl16(kcat + b2 + kt,          d + 8192);
            gl16(kcat + b2 + kt + rstep2, d + 10240);
        };
        stage2(0, 0);
        __syncthreads();
        int cur = 0;
        for (int kt = 0; kt < 256; kt += 32) {
            if (kt + 32 < 256) stage2(cur ^ 1, kt + 32);
            const int cb = cur * 16384;
            bfrag ah[4], bh[4];
#pragma unroll
            for (int f = 0; f < 4; f++) {
                ah[f] = *(const bfrag*)&lds[cb +        ra + f * 512];
                bh[f] = *(const bfrag*)&lds[cb + 8192 + rb + f * 512];
            }
#pragma unroll
            for (int i = 0; i < 4; i++)
#pragma unroll
                for (int j = 0; j < 4; j++)
                    acc[i][j] = __builtin_amdgcn_mfma_f32_16x16x32_bf16(ah[i], bh[j], acc[i][j], 0, 0, 0);
            __syncthreads();
            cur ^= 1;
        }
    }

    const int crow0 = bm0 + wr * 64 + (l >> 4) * 4;
    const int ccol0 = bn0 + wc * 64 + (l & 15);
#pragma unroll
    for (int i = 0; i < 4; i++)
#pragma unroll
        for (int j = 0; j < 4; j++)
#pragma unroll
            for (int r = 0; r < 4; r++)
                out[(size_t)(crow0 + i * 16 + r) * Dq + ccol0 + j * 16] = acc[i][j][r];
}

// Reduce NZ split-K partials + LayerNorm over A=128 -> (hi,lo) bf16.
template<int NZ>
__global__ __launch_bounds__(256)
void rln(const float* __restrict__ p, unsigned short* __restrict__ oh,
         unsigned short* __restrict__ ol, const float* __restrict__ g,
         const float* __restrict__ b, long pstride)
{
    int row  = blockIdx.x * 4 + (threadIdx.x >> 6);
    int lane = threadIdx.x & 63;
    long base = (long)row * Aq;
    float x0 = 0.f, x1 = 0.f;
#pragma unroll
    for (int z = 0; z < NZ; z++) {
        x0 += p[base + z * pstride + lane];
        x1 += p[base + z * pstride + lane + 64];
    }
    float s  = x0 + x1;
    float ss = x0 * x0 + x1 * x1;
#pragma unroll
    for (int off = 32; off > 0; off >>= 1) {
        s  += __shfl_xor(s, off);
        ss += __shfl_xor(ss, off);
    }
    float m  = s * (1.0f / Aq);
    float v  = ss * (1.0f / Aq) - m * m;
    float rs = rsqrtf(v + 1e-5f);
    float y0 = (x0 - m) * rs * g[lane]      + b[lane];
    float y1 = (x1 - m) * rs * g[lane + 64] + b[lane + 64];
    unsigned short h0 = f2bf(y0), h1 = f2bf(y1);
    oh[base + lane]      = h0;
    oh[base + lane + 64] = h1;
    ol[base + lane]      = f2bf(y0 - bf2f(h0));
    ol[base + lane + 64] = f2bf(y1 - bf2f(h1));
}

// Reduce NZ split-K partials [bz][NZ][rowsPerB][A] -> scaled bf16 with
// output row-stride/column-offset (for concatenated tail operands).
template<int NZ>
__global__ __launch_bounds__(256)
void rbf(const float* __restrict__ p, unsigned short* __restrict__ o,
         int rowsPerB, float scale, int total, int ostride, int ocol)
{
    int i = blockIdx.x * 256 + threadIdx.x;
    if (i >= total) return;
    int n = i >> 7, a = i & 127;
    int bz = n / rowsPerB, s = n - bz * rowsPerB;
    long base = ((long)bz * NZ) * rowsPerB * Aq + (long)s * Aq + a;
    float acc = 0.f;
#pragma unroll
    for (int z = 0; z < NZ; z++) acc += p[base + (long)z * rowsPerB * Aq];
    o[(long)n * ostride + ocol + a] = f2bf(acc * scale);
}

// mixed[n,:] = sum_e ew[n,e] * LN_e(h[e,n,:])  -> bf16 into acat col 128.
__global__ __launch_bounds__(256)
void mix_ln(const float* __restrict__ h, const float* __restrict__ ew,
            const float* __restrict__ g, const float* __restrict__ bb,
            unsigned short* __restrict__ acat)
{
    int n    = blockIdx.x * 4 + (threadIdx.x >> 6);
    int lane = threadIdx.x & 63;
    float a0 = 0.0f, a1 = 0.0f;
#pragma unroll
    for (int e = 0; e < Eq; e++) {
        const float* r = h + ((long)e * Nq + n) * Aq;
        float x0 = r[lane], x1 = r[lane + 64];
        float s  = x0 + x1;
        float ss = x0 * x0 + x1 * x1;
#pragma unroll
        for (int off = 32; off > 0; off >>= 1) {
            s  += __shfl_xor(s, off);
            ss += __shfl_xor(ss, off);
        }
        float m  = s * (1.0f / Aq);
        float v  = ss * (1.0f / Aq) - m * m;
        float rs = rsqrtf(v + 1e-5f);
        float wv = ew[(long)n * Eq + e];
        a0 += wv * ((x0 - m) * rs * g[e * Aq + lane]      + bb[e * Aq + lane]);
        a1 += wv * ((x1 - m) * rs * g[e * Aq + lane + 64] + bb[e * Aq + lane + 64]);
    }
    acat[(long)n * 256 + 128 + lane]      = f2bf(a0);
    acat[(long)n * 256 + 128 + lane + 64] = f2bf(a1);
}

extern "C" void kernel_launch(void* const* d_in, const int* in_sizes, int n_in,
                              void* d_out, int out_size, void* d_ws, size_t ws_size,
                              hipStream_t stream)
{
    const float* x             = (const float*)d_in[0];
    const float* ew            = (const float*)d_in[1];
    const float* up_w          = (const float*)d_in[2];
    const float* gate_w        = (const float*)d_in[3];
    const float* down_w        = (const float*)d_in[4];
    const float* pre_w         = (const float*)d_in[5];
    const float* post_w        = (const float*)d_in[6];
    const float* an_g          = (const float*)d_in[7];
    const float* an_b          = (const float*)d_in[8];
    const float* adapt_proj_w  = (const float*)d_in[9];
    const float* adapter_w     = (const float*)d_in[10];
    const float* adapter_g     = (const float*)d_in[11];
    const float* adapter_b     = (const float*)d_in[12];
    const float* expert_proj_w = (const float*)d_in[13];
    const float* output_proj_w = (const float*)d_in[14];
    float* out = (float*)d_out;

    // ---- workspace (KB offsets; peak ~113.3 MB) ----
#define OFF(kb) ((char*)d_ws + (size_t)(kb) * 1024)
    // region 0..32768 KB, time-shared:
    float* wfp  = (float*)OFF(0);        // [16][D][A] 8MB       (phase 1)
    float* kdp  = (float*)OFF(8192);     // [16][D][A] 8MB       (phase 1)
    float* p1   = (float*)OFF(16384);    // [8][N][A] 16MB       (phase 1)
    float* gate = (float*)OFF(0);        // [N,H] fp32 32MB      (phase 2)
    float* p2   = (float*)OFF(0);        // [8][N][A] 16MB       (phase 3)
    unsigned short* wmat = (unsigned short*)OFF(16384);  // [B][S][S] bf16 16MB (phase 3-4)
    float* p3   = (float*)OFF(0);        // [2][8][S][A] 16MB    (phase 4)
    float* h_e  = (float*)OFF(16384);    // [E][N][A] 16MB       (phase 5, after wmat dead)
    // early-only (dead before hh written):
    unsigned short* oph = (unsigned short*)OFF(32768);   // [D][H] 4MB
    unsigned short* apT = (unsigned short*)OFF(36864);   // [A][H] .5MB
    unsigned short* epT = (unsigned short*)OFF(37376);   // [A][H] .5MB
    // long-lived:
    unsigned short* hh   = (unsigned short*)OFF(32768);  // [N,H] 16MB
    unsigned short* hl   = (unsigned short*)OFF(49152);  // [N,H] 16MB
    unsigned short* xh   = (unsigned short*)OFF(65536);  // 8MB
    unsigned short* xl   = (unsigned short*)OFF(73728);  // 8MB
    unsigned short* gwh  = (unsigned short*)OFF(81920);  // 4MB
    unsigned short* gwl  = (unsigned short*)OFF(86016);
    unsigned short* uwh  = (unsigned short*)OFF(90112);
    unsigned short* uwl  = (unsigned short*)OFF(94208);
    unsigned short* dwh  = (unsigned short*)OFF(98304);
    unsigned short* dwl  = (unsigned short*)OFF(102400);
    unsigned short* pwh  = (unsigned short*)OFF(106496); // .25MB
    unsigned short* pwl  = (unsigned short*)OFF(106752);
    unsigned short* powh = (unsigned short*)OFF(107008); // .5MB
    unsigned short* powl = (unsigned short*)OFF(107520);
    unsigned short* ainh = (unsigned short*)OFF(108032); // 1MB
    unsigned short* ainl = (unsigned short*)OFF(109056);
    unsigned short* ainT = (unsigned short*)OFF(110080); // [B][A][S] 1MB
    unsigned short* aouth= (unsigned short*)OFF(111104); // 1MB
    unsigned short* aoutl= (unsigned short*)OFF(112128); // 1MB
    unsigned short* adw  = (unsigned short*)OFF(113152); // [E][A][A] .25MB
    unsigned short* kcat = (unsigned short*)OFF(113408); // [D][256] .5MB
    unsigned short* acat = (unsigned short*)OFF(113920); // [N][256] 2MB -> 115968
#undef OFF

    dim3 blk(256);
    const long NA = (long)Nq * Aq;
    const long SA = (long)Sq * Aq;
    const long SS = (long)Sq * Sq;

    // 1. conversions + transposes
    convert_all<<<dim3(2048), blk, 0, stream>>>(x, gate_w, up_w, down_w, pre_w, post_w,
        output_proj_w, adapter_w, xh, xl, gwh, gwl, uwh, uwl, dwh, dwl,
        pwh, pwl, powh, powl, oph, adw);
    transb<float><<<dim3(4, 64, 1), blk, 0, stream>>>(adapt_proj_w,  apT, Hq, Aq);
    transb<float><<<dim3(4, 64, 1), blk, 0, stream>>>(expert_proj_w, epT, Hq, Aq);

    // 2. weight fusions: kcat = [down@adapt_proj | op@ep]  (1-term, split-K 16)
    mg<1, 0, false><<<dim3(1, 8, 16), blk, 0, stream>>>(oph, nullptr, epT, nullptr,
        nullptr, wfp, nullptr, Aq, Hq, 16, 0, 0, 0, (long)Dq * Aq);
    mg<1, 0, false><<<dim3(1, 8, 16), blk, 0, stream>>>(dwh, nullptr, apT, nullptr,
        nullptr, kdp, nullptr, Aq, Hq, 16, 0, 0, 0, (long)Dq * Aq);
    rbf<16><<<dim3(512), blk, 0, stream>>>(kdp, kcat, Dq, 1.0f, Dq * Aq, 256, 0);
    rbf<16><<<dim3(512), blk, 0, stream>>>(wfp, kcat, Dq, 1.0f, Dq * Aq, 256, 128);

    // 3. ain = LN(x @ pre_w^T)  (3-term, split-K 8)
    mg<3, 0, false><<<dim3(1, 32, 8), blk, 0, stream>>>(xh, xl, pwh, pwl, nullptr,
        p1, nullptr, Aq, Dq, 8, 0, 0, 0, NA);
    rln<8><<<dim3(1024), blk, 0, stream>>>(p1, ainh, ainl, an_g, an_b, NA);
    transb<unsigned short><<<dim3(4, 64, 2), blk, 0, stream>>>(ainh, ainT, Sq, Aq);

    // 4. SwiGLU: gate fp32, then hidden -> (hh,hl) fused in epilogue
    mg<3, 0, true><<<dim3(16, 32, 1), blk, 0, stream>>>(xh, xl, gwh, gwl, nullptr,
        gate, nullptr, Hq, Dq, 1, 0, 0, 0, 0);
    mg<3, 2, true><<<dim3(16, 32, 1), blk, 0, stream>>>(xh, xl, uwh, uwl, gate,
        hh, hl, Hq, Dq, 1, 0, 0, 0, 0);

    // 5. aout = LN(hidden @ post_w^T)  (3-term, split-K 8)
    mg<3, 0, false><<<dim3(1, 32, 8), blk, 0, stream>>>(hh, hl, powh, powl, nullptr,
        p2, nullptr, Aq, Hq, 8, 0, 0, 0, NA);
    rln<8><<<dim3(1024), blk, 0, stream>>>(p2, aouth, aoutl, an_g, an_b, NA);

    // 6. wmat = bf16(silu(clip(ain @ aout^T)))  per batch
    mg<3, 1, false><<<dim3(16, 16, 2), blk, 0, stream>>>(ainh, ainl, aouth, aoutl,
        nullptr, wmat, nullptr, Sq, Aq, 1, SA, SA, SS, 0);

    // 7. acat[:,0:128] = 0.1 * (wmat @ ain)  (1-term, split-K 8, batched)
    mg<1, 0, false><<<dim3(1, 16, 16), blk, 0, stream>>>(wmat, nullptr, ainT, nullptr,
        nullptr, p3, nullptr, Aq, Sq, 8, SS, SA, 8 * SA, SA);
    rbf<8><<<dim3(2048), blk, 0, stream>>>(p3, acat, Sq, 0.1f, Nq * Aq, 256, 0);

    // 8. expert path: h_e, then acat[:,128:256] = mixed
    mg<1, 0, false><<<dim3(1, 32, 8), blk, 0, stream>>>(ainh, nullptr, adw, nullptr,
        nullptr, h_e, nullptr, Aq, Aq, 1, 0, (long)Aq * Aq, NA, 0);
    mix_ln<<<dim3(1024), blk, 0, stream>>>(h_e, ew, adapter_g, adapter_b, acat);

    // 9. out = (hh+hl)@(dwh+dwl)^T + acat@kcat^T
    gfinal<<<dim3(8, 32), blk, 0, stream>>>(hh, hl, dwh, dwl, acat, kcat, out);
}

// Round 7
// 218.244 us; speedup vs baseline: 5.2540x; 1.3847x over previous
//
#include <hip/hip_runtime.h>
#include <hip/hip_bf16.h>
#include <math.h>

// Problem constants (B,S,D,E = 2,2048,1024,8)
#define Bq 2
#define Sq 2048
#define Dq 1024
#define Eq 8
#define Hq 2048            // 2*D
#define Aq 128             // H/16
#define Nq (Bq*Sq)         // 4096 tokens

typedef __attribute__((ext_vector_type(4))) float f32x4;
typedef __attribute__((ext_vector_type(8))) short bfrag;   // 8 bf16 in 4 VGPRs

__device__ __forceinline__ float silu_f(float x) {
    return x / (1.0f + expf(-x));
}
__device__ __forceinline__ unsigned short f2bf(float x) {  // RNE fp32->bf16
    unsigned u = __float_as_uint(x);
    u += 0x7fffu + ((u >> 16) & 1u);
    return (unsigned short)(u >> 16);
}
__device__ __forceinline__ float bf2f(unsigned short h) {
    return __uint_as_float(((unsigned)h) << 16);
}
__device__ __forceinline__ void gl16(const unsigned short* g, unsigned short* l) {
    __builtin_amdgcn_global_load_lds(
        (const __attribute__((address_space(1))) void*)g,
        (__attribute__((address_space(3))) void*)(void*)l, 16, 0, 0);
}

// ---------------------------------------------------------------------------
// One-shot conversion of all inputs: fp32 -> bf16 (hi only; 1-term pipeline).
// Segments (float4 units): x 1048576 | gw 524288 | uw 524288 | dw 524288
//                        | pw 32768 | pow 65536 | opw 524288 | aw 32768
// Total = 3276800.
// ---------------------------------------------------------------------------
__global__ __launch_bounds__(256)
void convert_all(const float* __restrict__ x,  const float* __restrict__ gw,
                 const float* __restrict__ uw, const float* __restrict__ dw,
                 const float* __restrict__ pw, const float* __restrict__ ow,
                 const float* __restrict__ opw, const float* __restrict__ aw,
                 unsigned short* xh,  unsigned short* gwh, unsigned short* uwh,
                 unsigned short* dwh, unsigned short* pwh, unsigned short* powh,
                 unsigned short* oph, unsigned short* adw)
{
    const int T = 3276800;
    for (int i = blockIdx.x * 256 + threadIdx.x; i < T; i += gridDim.x * 256) {
        const float* in; unsigned short* hi; int j = i;
        if (j < 1048576)                 { in = x;   hi = xh;  }
        else if ((j -= 1048576) < 524288){ in = gw;  hi = gwh; }
        else if ((j -= 524288) < 524288) { in = uw;  hi = uwh; }
        else if ((j -= 524288) < 524288) { in = dw;  hi = dwh; }
        else if ((j -= 524288) < 32768)  { in = pw;  hi = pwh; }
        else if ((j -= 32768) < 65536)   { in = ow;  hi = powh; }
        else if ((j -= 65536) < 524288)  { in = opw; hi = oph; }
        else { j -= 524288;                in = aw;  hi = adw; }
        float4 v = ((const float4*)in)[j];
        ((ushort4*)hi)[j] = make_ushort4(f2bf(v.x), f2bf(v.y), f2bf(v.z), f2bf(v.w));
    }
}

// Transpose [R][C] -> bf16 [C][R], batched by blockIdx.z.
template<typename TIN>
__global__ __launch_bounds__(256)
void transb(const TIN* __restrict__ in, unsigned short* __restrict__ out, int R, int C)
{
    __shared__ float t[32][33];
    in  += (size_t)blockIdx.z * R * C;
    out += (size_t)blockIdx.z * R * C;
    int tx = threadIdx.x & 31, ty = threadIdx.x >> 5;
    int r0 = blockIdx.y * 32, c0 = blockIdx.x * 32;
#pragma unroll
    for (int j = 0; j < 4; j++) {
        TIN v = in[(size_t)(r0 + ty + j * 8) * C + c0 + tx];
        float f;
        if (sizeof(TIN) == 2) f = bf2f(*(const unsigned short*)&v);
        else                  f = *(const float*)&v;
        t[ty + j * 8][tx] = f;
    }
    __syncthreads();
#pragma unroll
    for (int j = 0; j < 4; j++)
        out[(size_t)(c0 + ty + j * 8) * R + r0 + tx] = f2bf(t[tx][ty + j * 8]);
}

// ---------------------------------------------------------------------------
// 1-term bf16 MFMA GEMM, double-buffered (stage(t+1) || compute(t)):
//   C[m][n] = sum_k A(m,k)*B(n,k), bf16 row-major K-contig.
// 128x128 tile, BK=32, 4 waves; global_load_lds w=16, XOR-swizzled k-segment.
// z decode: bz = z / kchunks (batch), kz = z % kchunks.
// EPI: 0 = fp32 store to C + bz*zC + kz*pz
//      1 = bf16 store silu(clip(acc,-5,5)) to C + bz*zC
// ---------------------------------------------------------------------------
template<int EPI>
__global__ __launch_bounds__(256)
void mg(const unsigned short* __restrict__ Ah, const unsigned short* __restrict__ Bh,
        void* __restrict__ Cv, int N, int K, int kchunks,
        long zA, long zB, long zC, long pz)
{
    __shared__ __align__(16) unsigned short lds[16384];   // 2 bufs x (A4096|B4096)

    const int tid = threadIdx.x;
    const int l   = tid & 63;
    const int w   = tid >> 6;
    const int wr  = w >> 1, wc = w & 1;
    const int bm0 = blockIdx.y * 128, bn0 = blockIdx.x * 128;
    const int bz  = blockIdx.z / kchunks;
    const int kz  = blockIdx.z - bz * kchunks;
    const int kcnt = K / kchunks;
    const int kbeg = kz * kcnt;
    const int kend = kbeg + kcnt;

    const unsigned short* A0 = Ah + (size_t)bz * zA;
    const unsigned short* B0 = Bh + (size_t)bz * zB;

    const int srow = tid >> 2;
    const int scol = (((tid & 3) ^ (srow & 3)) << 3);
    const size_t aoff0 = (size_t)(bm0 + srow) * K + scol;
    const size_t boff0 = (size_t)(bn0 + srow) * K + scol;
    const size_t rstep = (size_t)64 * K;

    const int cu = (((l >> 4) ^ (l & 3)) << 3);
    const int ra = (wr * 64 + (l & 15)) * 32 + cu;
    const int rb = (wc * 64 + (l & 15)) * 32 + cu;

    auto stage = [&](int b, int kt) {
        unsigned short* d = &lds[b * 8192 + (w << 9)];
        gl16(A0 + aoff0 + kt,         d + 0);
        gl16(A0 + aoff0 + kt + rstep, d + 2048);
        gl16(B0 + boff0 + kt,         d + 4096);
        gl16(B0 + boff0 + kt + rstep, d + 6144);
    };

    f32x4 acc[4][4];
#pragma unroll
    for (int i = 0; i < 4; i++)
#pragma unroll
        for (int j = 0; j < 4; j++) acc[i][j] = (f32x4){0.f, 0.f, 0.f, 0.f};

    stage(0, kbeg);
    __syncthreads();
    int cur = 0;
    for (int kt = kbeg; kt < kend; kt += 32) {
        if (kt + 32 < kend) stage(cur ^ 1, kt + 32);
        const int cb = cur * 8192;
        bfrag ah[4], bh[4];
#pragma unroll
        for (int f = 0; f < 4; f++) {
            ah[f] = *(const bfrag*)&lds[cb + ra + f * 512];
            bh[f] = *(const bfrag*)&lds[cb + 4096 + rb + f * 512];
        }
#pragma unroll
        for (int i = 0; i < 4; i++)
#pragma unroll
            for (int j = 0; j < 4; j++)
                acc[i][j] = __builtin_amdgcn_mfma_f32_16x16x32_bf16(ah[i], bh[j], acc[i][j], 0, 0, 0);
        __syncthreads();
        cur ^= 1;
    }

    // C/D layout: col = lane&15, row = (lane>>4)*4 + reg
    const int crow0 = bm0 + wr * 64 + (l >> 4) * 4;
    const int ccol0 = bn0 + wc * 64 + (l & 15);
#pragma unroll
    for (int i = 0; i < 4; i++)
#pragma unroll
        for (int j = 0; j < 4; j++)
#pragma unroll
            for (int r = 0; r < 4; r++) {
                size_t idx = (size_t)(crow0 + i * 16 + r) * N + (ccol0 + j * 16);
                float v = acc[i][j][r];
                if (EPI == 0)
                    ((float*)Cv + (size_t)bz * zC + (size_t)kz * pz)[idx] = v;
                else
                    ((unsigned short*)Cv + (size_t)bz * zC)[idx] =
                        f2bf(silu_f(fminf(fmaxf(v, -5.f), 5.f)));
            }
}

// ---------------------------------------------------------------------------
// Fused gate+up GEMM: one x-staging, two B-tiles, two accumulator sets.
//   hh[n,h] = bf16( silu(x@gw^T) * (x@uw^T) )      K=1024, tile 128x128.
// ---------------------------------------------------------------------------
__global__ __launch_bounds__(256)
void gup(const unsigned short* __restrict__ xh, const unsigned short* __restrict__ gwh,
         const unsigned short* __restrict__ uwh, unsigned short* __restrict__ hh)
{
    __shared__ __align__(16) unsigned short lds[24576];   // 2 bufs x (A|Bg|Bu = 12288)
    const int tid = threadIdx.x;
    const int l   = tid & 63;
    const int w   = tid >> 6;
    const int wr  = w >> 1, wc = w & 1;

    int nb  = gridDim.x * gridDim.y;                      // 512
    int id  = blockIdx.y * gridDim.x + blockIdx.x;
    int id2 = (id & 7) * (nb >> 3) + (id >> 3);
    int bx  = id2 % gridDim.x, by = id2 / gridDim.x;
    const int bm0 = by * 128, bn0 = bx * 128;

    const int srow = tid >> 2;
    const int scol = (((tid & 3) ^ (srow & 3)) << 3);
    const size_t aoff0 = (size_t)(bm0 + srow) * Dq + scol;
    const size_t boff0 = (size_t)(bn0 + srow) * Dq + scol;
    const size_t rstep = (size_t)64 * Dq;

    const int cu = (((l >> 4) ^ (l & 3)) << 3);
    const int ra = (wr * 64 + (l & 15)) * 32 + cu;
    const int rb = (wc * 64 + (l & 15)) * 32 + cu;

    auto stage = [&](int b, int kt) {
        unsigned short* d = &lds[b * 12288 + (w << 9)];
        gl16(xh  + aoff0 + kt,         d + 0);
        gl16(xh  + aoff0 + kt + rstep, d + 2048);
        gl16(gwh + boff0 + kt,         d + 4096);
        gl16(gwh + boff0 + kt + rstep, d + 6144);
        gl16(uwh + boff0 + kt,         d + 8192);
        gl16(uwh + boff0 + kt + rstep, d + 10240);
    };

    f32x4 accg[4][4], accu[4][4];
#pragma unroll
    for (int i = 0; i < 4; i++)
#pragma unroll
        for (int j = 0; j < 4; j++) {
            accg[i][j] = (f32x4){0.f, 0.f, 0.f, 0.f};
            accu[i][j] = (f32x4){0.f, 0.f, 0.f, 0.f};
        }

    stage(0, 0);
    __syncthreads();
    int cur = 0;
    for (int kt = 0; kt < Dq; kt += 32) {
        if (kt + 32 < Dq) stage(cur ^ 1, kt + 32);
        const int cb = cur * 12288;
        bfrag ah[4], bg[4], bu[4];
#pragma unroll
        for (int f = 0; f < 4; f++) {
            ah[f] = *(const bfrag*)&lds[cb +        ra + f * 512];
            bg[f] = *(const bfrag*)&lds[cb + 4096 + rb + f * 512];
            bu[f] = *(const bfrag*)&lds[cb + 8192 + rb + f * 512];
        }
#pragma unroll
        for (int i = 0; i < 4; i++)
#pragma unroll
            for (int j = 0; j < 4; j++) {
                accg[i][j] = __builtin_amdgcn_mfma_f32_16x16x32_bf16(ah[i], bg[j], accg[i][j], 0, 0, 0);
                accu[i][j] = __builtin_amdgcn_mfma_f32_16x16x32_bf16(ah[i], bu[j], accu[i][j], 0, 0, 0);
            }
        __syncthreads();
        cur ^= 1;
    }

    const int crow0 = bm0 + wr * 64 + (l >> 4) * 4;
    const int ccol0 = bn0 + wc * 64 + (l & 15);
#pragma unroll
    for (int i = 0; i < 4; i++)
#pragma unroll
        for (int j = 0; j < 4; j++)
#pragma unroll
            for (int r = 0; r < 4; r++) {
                size_t idx = (size_t)(crow0 + i * 16 + r) * Hq + (ccol0 + j * 16);
                hh[idx] = f2bf(silu_f(accg[i][j][r]) * accu[i][j][r]);
            }
}

// ---------------------------------------------------------------------------
// Final fused GEMM (1-term):  out[4096][1024] =
//   hh@dwh^T (K=2048)  +  acat@kcat^T (K=256)
// acat=[0.1*adapt | mixed], kcat=[down@adapt_proj | op@ep].
// ---------------------------------------------------------------------------
__global__ __launch_bounds__(256)
void gfinal(const unsigned short* __restrict__ hh, const unsigned short* __restrict__ dwh,
            const unsigned short* __restrict__ acat, const unsigned short* __restrict__ kcat,
            float* __restrict__ out)
{
    __shared__ __align__(16) unsigned short lds[16384];
    const int tid = threadIdx.x;
    const int l   = tid & 63;
    const int w   = tid >> 6;
    const int wr  = w >> 1, wc = w & 1;

    int nb  = gridDim.x * gridDim.y;                      // 256
    int id  = blockIdx.y * gridDim.x + blockIdx.x;
    int id2 = (id & 7) * (nb >> 3) + (id >> 3);
    int bx  = id2 % gridDim.x, by = id2 / gridDim.x;
    const int bm0 = by * 128, bn0 = bx * 128;

    const int srow = tid >> 2;
    const int scol = (((tid & 3) ^ (srow & 3)) << 3);
    const int cu = (((l >> 4) ^ (l & 3)) << 3);
    const int ra = (wr * 64 + (l & 15)) * 32 + cu;
    const int rb = (wc * 64 + (l & 15)) * 32 + cu;

    f32x4 acc[4][4];
#pragma unroll
    for (int i = 0; i < 4; i++)
#pragma unroll
        for (int j = 0; j < 4; j++) acc[i][j] = (f32x4){0.f, 0.f, 0.f, 0.f};

    // ---- main: K=2048 ----
    {
        const size_t aoff0 = (size_t)(bm0 + srow) * Hq + scol;
        const size_t boff0 = (size_t)(bn0 + srow) * Hq + scol;
        const size_t rstep = (size_t)64 * Hq;
        auto stage = [&](int b, int kt) {
            unsigned short* d = &lds[b * 8192 + (w << 9)];
            gl16(hh  + aoff0 + kt,         d + 0);
            gl16(hh  + aoff0 + kt + rstep, d + 2048);
            gl16(dwh + boff0 + kt,         d + 4096);
            gl16(dwh + boff0 + kt + rstep, d + 6144);
        };
        stage(0, 0);
        __syncthreads();
        int cur = 0;
        for (int kt = 0; kt < Hq; kt += 32) {
            if (kt + 32 < Hq) stage(cur ^ 1, kt + 32);
            const int cb = cur * 8192;
            bfrag ah[4], bh[4];
#pragma unroll
            for (int f = 0; f < 4; f++) {
                ah[f] = *(const bfrag*)&lds[cb +        ra + f * 512];
                bh[f] = *(const bfrag*)&lds[cb + 4096 + rb + f * 512];
            }
#pragma unroll
            for (int i = 0; i < 4; i++)
#pragma unroll
                for (int j = 0; j < 4; j++)
                    acc[i][j] = __builtin_amdgcn_mfma_f32_16x16x32_bf16(ah[i], bh[j], acc[i][j], 0, 0, 0);
            __syncthreads();
            cur ^= 1;
        }
    }
    // ---- tail: K=256 over [acat | kcat] ----
    {
        const size_t a2 = (size_t)(bm0 + srow) * 256 + scol;
        const size_t b2 = (size_t)(bn0 + srow) * 256 + scol;
        const size_t rstep2 = (size_t)64 * 256;
        auto stage2 = [&](int b, int kt) {
            unsigned short* d = &lds[b * 8192 + (w << 9)];
            gl16(acat + a2 + kt,          d + 0);
            gl16(acat + a2 + kt + rstep2, d + 2048);
            gl16(kcat + b2 + kt,          d + 4096);
            gl16(kcat + b2 + kt + rstep2, d + 6144);
        };
        stage2(0, 0);
        __syncthreads();
        int cur = 0;
        for (int kt = 0; kt < 256; kt += 32) {
            if (kt + 32 < 256) stage2(cur ^ 1, kt + 32);
            const int cb = cur * 8192;
            bfrag ah[4], bh[4];
#pragma unroll
            for (int f = 0; f < 4; f++) {
                ah[f] = *(const bfrag*)&lds[cb +        ra + f * 512];
                bh[f] = *(const bfrag*)&lds[cb + 4096 + rb + f * 512];
            }
#pragma unroll
            for (int i = 0; i < 4; i++)
#pragma unroll
                for (int j = 0; j < 4; j++)
                    acc[i][j] = __builtin_amdgcn_mfma_f32_16x16x32_bf16(ah[i], bh[j], acc[i][j], 0, 0, 0);
            __syncthreads();
            cur ^= 1;
        }
    }

    const int crow0 = bm0 + wr * 64 + (l >> 4) * 4;
    const int ccol0 = bn0 + wc * 64 + (l & 15);
#pragma unroll
    for (int i = 0; i < 4; i++)
#pragma unroll
        for (int j = 0; j < 4; j++)
#pragma unroll
            for (int r = 0; r < 4; r++)
                out[(size_t)(crow0 + i * 16 + r) * Dq + ccol0 + j * 16] = acc[i][j][r];
}

// Reduce NZ split-K partials + LayerNorm over A=128 -> bf16.
template<int NZ>
__global__ __launch_bounds__(256)
void rln(const float* __restrict__ p, unsigned short* __restrict__ oh,
         const float* __restrict__ g, const float* __restrict__ b, long pstride)
{
    int row  = blockIdx.x * 4 + (threadIdx.x >> 6);
    int lane = threadIdx.x & 63;
    long base = (long)row * Aq;
    float x0 = 0.f, x1 = 0.f;
#pragma unroll
    for (int z = 0; z < NZ; z++) {
        x0 += p[base + z * pstride + lane];
        x1 += p[base + z * pstride + lane + 64];
    }
    float s  = x0 + x1;
    float ss = x0 * x0 + x1 * x1;
#pragma unroll
    for (int off = 32; off > 0; off >>= 1) {
        s  += __shfl_xor(s, off);
        ss += __shfl_xor(ss, off);
    }
    float m  = s * (1.0f / Aq);
    float v  = ss * (1.0f / Aq) - m * m;
    float rs = rsqrtf(v + 1e-5f);
    oh[base + lane]      = f2bf((x0 - m) * rs * g[lane]      + b[lane]);
    oh[base + lane + 64] = f2bf((x1 - m) * rs * g[lane + 64] + b[lane + 64]);
}

// Reduce NZ split-K partials [bz][NZ][rowsPerB][A] -> scaled bf16 with
// output row-stride/column-offset (for concatenated tail operands).
template<int NZ>
__global__ __launch_bounds__(256)
void rbf(const float* __restrict__ p, unsigned short* __restrict__ o,
         int rowsPerB, float scale, int total, int ostride, int ocol)
{
    int i = blockIdx.x * 256 + threadIdx.x;
    if (i >= total) return;
    int n = i >> 7, a = i & 127;
    int bz = n / rowsPerB, s = n - bz * rowsPerB;
    long base = ((long)bz * NZ) * rowsPerB * Aq + (long)s * Aq + a;
    float acc = 0.f;
#pragma unroll
    for (int z = 0; z < NZ; z++) acc += p[base + (long)z * rowsPerB * Aq];
    o[(long)n * ostride + ocol + a] = f2bf(acc * scale);
}

// mixed[n,:] = sum_e ew[n,e] * LN_e(h[e,n,:])  -> bf16 into acat col 128.
__global__ __launch_bounds__(256)
void mix_ln(const float* __restrict__ h, const float* __restrict__ ew,
            const float* __restrict__ g, const float* __restrict__ bb,
            unsigned short* __restrict__ acat)
{
    int n    = blockIdx.x * 4 + (threadIdx.x >> 6);
    int lane = threadIdx.x & 63;
    float a0 = 0.0f, a1 = 0.0f;
#pragma unroll
    for (int e = 0; e < Eq; e++) {
        const float* r = h + ((long)e * Nq + n) * Aq;
        float x0 = r[lane], x1 = r[lane + 64];
        float s  = x0 + x1;
        float ss = x0 * x0 + x1 * x1;
#pragma unroll
        for (int off = 32; off > 0; off >>= 1) {
            s  += __shfl_xor(s, off);
            ss += __shfl_xor(ss, off);
        }
        float m  = s * (1.0f / Aq);
        float v  = ss * (1.0f / Aq) - m * m;
        float rs = rsqrtf(v + 1e-5f);
        float wv = ew[(long)n * Eq + e];
        a0 += wv * ((x0 - m) * rs * g[e * Aq + lane]      + bb[e * Aq + lane]);
        a1 += wv * ((x1 - m) * rs * g[e * Aq + lane + 64] + bb[e * Aq + lane + 64]);
    }
    acat[(long)n * 256 + 128 + lane]      = f2bf(a0);
    acat[(long)n * 256 + 128 + lane + 64] = f2bf(a1);
}

extern "C" void kernel_launch(void* const* d_in, const int* in_sizes, int n_in,
                              void* d_out, int out_size, void* d_ws, size_t ws_size,
                              hipStream_t stream)
{
    const float* x             = (const float*)d_in[0];
    const float* ew            = (const float*)d_in[1];
    const float* up_w          = (const float*)d_in[2];
    const float* gate_w        = (const float*)d_in[3];
    const float* down_w        = (const float*)d_in[4];
    const float* pre_w         = (const float*)d_in[5];
    const float* post_w        = (const float*)d_in[6];
    const float* an_g          = (const float*)d_in[7];
    const float* an_b          = (const float*)d_in[8];
    const float* adapt_proj_w  = (const float*)d_in[9];
    const float* adapter_w     = (const float*)d_in[10];
    const float* adapter_g     = (const float*)d_in[11];
    const float* adapter_b     = (const float*)d_in[12];
    const float* expert_proj_w = (const float*)d_in[13];
    const float* output_proj_w = (const float*)d_in[14];
    float* out = (float*)d_out;

    // ---- workspace (KB offsets; peak ~81 MB) ----
#define OFF(kb) ((char*)d_ws + (size_t)(kb) * 1024)
    // 0..32768 KB time-shared fp32/bf16 region:
    float* wfp  = (float*)OFF(0);        // [16][D][A] 8MB   (phase 1)
    float* kdp  = (float*)OFF(8192);     // 8MB              (phase 1)
    float* p1   = (float*)OFF(16384);    // [8][N][A] 16MB   (phase 1)
    float* p2   = (float*)OFF(0);        // [8][N][A] 16MB   (phase 3)
    unsigned short* wmat = (unsigned short*)OFF(16384);  // [B][S][S] bf16 16MB (ph 3-4)
    float* p3   = (float*)OFF(0);        // [2][8][S][A] 16MB (phase 4)
    float* h_e  = (float*)OFF(0);        // [E][N][A] 16MB    (phase 5, after p3 dead)
    // long-lived:
    unsigned short* hh   = (unsigned short*)OFF(32768);  // [N,H] 16MB
    unsigned short* xh   = (unsigned short*)OFF(49152);  // 8MB
    unsigned short* gwh  = (unsigned short*)OFF(57344);  // 4MB
    unsigned short* uwh  = (unsigned short*)OFF(61440);  // 4MB
    unsigned short* dwh  = (unsigned short*)OFF(65536);  // 4MB
    unsigned short* oph  = (unsigned short*)OFF(69632);  // 4MB
    unsigned short* pwh  = (unsigned short*)OFF(73728);  // .25MB
    unsigned short* powh = (unsigned short*)OFF(73984);  // .5MB
    unsigned short* apT  = (unsigned short*)OFF(74496);  // .5MB
    unsigned short* epT  = (unsigned short*)OFF(75008);  // .5MB
    unsigned short* ainh = (unsigned short*)OFF(75520);  // 1MB
    unsigned short* ainT = (unsigned short*)OFF(76544);  // [B][A][S] 1MB
    unsigned short* aouth= (unsigned short*)OFF(77568);  // 1MB
    unsigned short* adw  = (unsigned short*)OFF(78592);  // .25MB
    unsigned short* kcat = (unsigned short*)OFF(78848);  // [D][256] .5MB
    unsigned short* acat = (unsigned short*)OFF(79360);  // [N][256] 2MB -> 81408
#undef OFF

    dim3 blk(256);
    const long NA = (long)Nq * Aq;
    const long SA = (long)Sq * Aq;
    const long SS = (long)Sq * Sq;

    // 1. conversions + transposes
    convert_all<<<dim3(2048), blk, 0, stream>>>(x, gate_w, up_w, down_w, pre_w, post_w,
        output_proj_w, adapter_w, xh, gwh, uwh, dwh, pwh, powh, oph, adw);
    transb<float><<<dim3(4, 64, 1), blk, 0, stream>>>(adapt_proj_w,  apT, Hq, Aq);
    transb<float><<<dim3(4, 64, 1), blk, 0, stream>>>(expert_proj_w, epT, Hq, Aq);

    // 2. weight fusions: kcat = [down@adapt_proj | op@ep]  (split-K 16)
    mg<0><<<dim3(1, 8, 16), blk, 0, stream>>>(oph, epT, wfp, Aq, Hq, 16,
        0, 0, 0, (long)Dq * Aq);
    mg<0><<<dim3(1, 8, 16), blk, 0, stream>>>(dwh, apT, kdp, Aq, Hq, 16,
        0, 0, 0, (long)Dq * Aq);
    rbf<16><<<dim3(512), blk, 0, stream>>>(kdp, kcat, Dq, 1.0f, Dq * Aq, 256, 0);
    rbf<16><<<dim3(512), blk, 0, stream>>>(wfp, kcat, Dq, 1.0f, Dq * Aq, 256, 128);

    // 3. ain = LN(x @ pre_w^T)  (split-K 8)
    mg<0><<<dim3(1, 32, 8), blk, 0, stream>>>(xh, pwh, p1, Aq, Dq, 8, 0, 0, 0, NA);
    rln<8><<<dim3(1024), blk, 0, stream>>>(p1, ainh, an_g, an_b, NA);
    transb<unsigned short><<<dim3(4, 64, 2), blk, 0, stream>>>(ainh, ainT, Sq, Aq);

    // 4. fused SwiGLU: hh = bf16(silu(x@gw^T) * (x@uw^T))
    gup<<<dim3(16, 32), blk, 0, stream>>>(xh, gwh, uwh, hh);

    // 5. aout = LN(hidden @ post_w^T)  (split-K 8)
    mg<0><<<dim3(1, 32, 8), blk, 0, stream>>>(hh, powh, p2, Aq, Hq, 8, 0, 0, 0, NA);
    rln<8><<<dim3(1024), blk, 0, stream>>>(p2, aouth, an_g, an_b, NA);

    // 6. wmat = bf16(silu(clip(ain @ aout^T)))  per batch
    mg<1><<<dim3(16, 16, 2), blk, 0, stream>>>(ainh, aouth, wmat, Sq, Aq, 1,
        SA, SA, SS, 0);

    // 7. acat[:,0:128] = 0.1 * (wmat @ ain)  (split-K 8, batched)
    mg<0><<<dim3(1, 16, 16), blk, 0, stream>>>(wmat, ainT, p3, Aq, Sq, 8,
        SS, SA, 8 * SA, SA);
    rbf<8><<<dim3(2048), blk, 0, stream>>>(p3, acat, Sq, 0.1f, Nq * Aq, 256, 0);

    // 8. expert path: h_e, then acat[:,128:256] = mixed
    mg<0><<<dim3(1, 32, 8), blk, 0, stream>>>(ainh, adw, h_e, Aq, Aq, 1,
        0, (long)Aq * Aq, NA, 0);
    mix_ln<<<dim3(1024), blk, 0, stream>>>(h_e, ew, adapter_g, adapter_b, acat);

    // 9. out = hh@dwh^T + acat@kcat^T
    gfinal<<<dim3(8, 32), blk, 0, stream>>>(hh, dwh, acat, kcat, out);
}

// Round 8
// 199.449 us; speedup vs baseline: 5.7491x; 1.0942x over previous
//
#include <hip/hip_runtime.h>
#include <hip/hip_bf16.h>
#include <math.h>

// Problem constants (B,S,D,E = 2,2048,1024,8)
#define Bq 2
#define Sq 2048
#define Dq 1024
#define Eq 8
#define Hq 2048            // 2*D
#define Aq 128             // H/16
#define Nq (Bq*Sq)         // 4096 tokens

typedef __attribute__((ext_vector_type(4))) float f32x4;
typedef __attribute__((ext_vector_type(8))) short bfrag;   // 8 bf16 in 4 VGPRs

__device__ __forceinline__ float silu_f(float x) {
    return x / (1.0f + expf(-x));
}
__device__ __forceinline__ unsigned short f2bf(float x) {  // RNE fp32->bf16
    unsigned u = __float_as_uint(x);
    u += 0x7fffu + ((u >> 16) & 1u);
    return (unsigned short)(u >> 16);
}
__device__ __forceinline__ float bf2f(unsigned short h) {
    return __uint_as_float(((unsigned)h) << 16);
}
__device__ __forceinline__ void gl16(const unsigned short* g, unsigned short* l) {
    __builtin_amdgcn_global_load_lds(
        (const __attribute__((address_space(1))) void*)g,
        (__attribute__((address_space(3))) void*)(void*)l, 16, 0, 0);
}

// ---------------------------------------------------------------------------
// BK=64 staging/fragment scheme (shared by mg/gup/gfinal):
//  Panel = [128 rows][64 cols] bf16 = 16 KB, staged in 4 gl16 rounds.
//  LDS(row, q) holds G(row, q ^ (row&7)) (q = 8-col slot) -> pre-swizzled
//  global source, linear LDS dest (gload_lds constraint), conflict-free
//  ds_read_b128 (each bank-group serves exactly 8 lanes).
//  Stage (per thread): srow = tid>>3 (+32/round), slot sq = (tid&7)^(srow&7).
//  Read (lane l), frag i, k-sub ks: row = woff + i*16 + (l&15),
//    slot = ((ks*4 + (l>>4)) ^ (l&7)).
// ---------------------------------------------------------------------------

// ---------------------------------------------------------------------------
// One-shot conversion of all inputs: fp32 -> bf16.
// ---------------------------------------------------------------------------
__global__ __launch_bounds__(256)
void convert_all(const float* __restrict__ x,  const float* __restrict__ gw,
                 const float* __restrict__ uw, const float* __restrict__ dw,
                 const float* __restrict__ pw, const float* __restrict__ ow,
                 const float* __restrict__ opw, const float* __restrict__ aw,
                 unsigned short* xh,  unsigned short* gwh, unsigned short* uwh,
                 unsigned short* dwh, unsigned short* pwh, unsigned short* powh,
                 unsigned short* oph, unsigned short* adw)
{
    const int T = 3276800;
    for (int i = blockIdx.x * 256 + threadIdx.x; i < T; i += gridDim.x * 256) {
        const float* in; unsigned short* hi; int j = i;
        if (j < 1048576)                 { in = x;   hi = xh;  }
        else if ((j -= 1048576) < 524288){ in = gw;  hi = gwh; }
        else if ((j -= 524288) < 524288) { in = uw;  hi = uwh; }
        else if ((j -= 524288) < 524288) { in = dw;  hi = dwh; }
        else if ((j -= 524288) < 32768)  { in = pw;  hi = pwh; }
        else if ((j -= 32768) < 65536)   { in = ow;  hi = powh; }
        else if ((j -= 65536) < 524288)  { in = opw; hi = oph; }
        else { j -= 524288;                in = aw;  hi = adw; }
        float4 v = ((const float4*)in)[j];
        ((ushort4*)hi)[j] = make_ushort4(f2bf(v.x), f2bf(v.y), f2bf(v.z), f2bf(v.w));
    }
}

// Transpose [R][C] -> bf16 [C][R], batched by blockIdx.z.
template<typename TIN>
__global__ __launch_bounds__(256)
void transb(const TIN* __restrict__ in, unsigned short* __restrict__ out, int R, int C)
{
    __shared__ float t[32][33];
    in  += (size_t)blockIdx.z * R * C;
    out += (size_t)blockIdx.z * R * C;
    int tx = threadIdx.x & 31, ty = threadIdx.x >> 5;
    int r0 = blockIdx.y * 32, c0 = blockIdx.x * 32;
#pragma unroll
    for (int j = 0; j < 4; j++) {
        TIN v = in[(size_t)(r0 + ty + j * 8) * C + c0 + tx];
        float f;
        if (sizeof(TIN) == 2) f = bf2f(*(const unsigned short*)&v);
        else                  f = *(const float*)&v;
        t[ty + j * 8][tx] = f;
    }
    __syncthreads();
#pragma unroll
    for (int j = 0; j < 4; j++)
        out[(size_t)(c0 + ty + j * 8) * R + r0 + tx] = f2bf(t[tx][ty + j * 8]);
}

// ---------------------------------------------------------------------------
// 1-term bf16 MFMA GEMM, BK=64, double-buffered:
//   C[m][n] = sum_k A(m,k)*B(n,k), bf16 row-major K-contig.
// 128x128 tile, 4 waves. EPI: 0 = fp32 store (+bz*zC+kz*pz); 1 = bf16 silu-clip.
// ---------------------------------------------------------------------------
template<int EPI>
__global__ __launch_bounds__(256)
void mg(const unsigned short* __restrict__ Ah, const unsigned short* __restrict__ Bh,
        void* __restrict__ Cv, int N, int K, int kchunks,
        long zA, long zB, long zC, long pz)
{
    __shared__ __align__(16) unsigned short lds[32768];  // 2 bufs x (A 8192 | B 8192)

    const int tid = threadIdx.x;
    const int l   = tid & 63;
    const int w   = tid >> 6;
    const int wr  = w >> 1, wc = w & 1;
    const int bm0 = blockIdx.y * 128, bn0 = blockIdx.x * 128;
    const int bz  = blockIdx.z / kchunks;
    const int kz  = blockIdx.z - bz * kchunks;
    const int kcnt = K / kchunks;
    const int kbeg = kz * kcnt;
    const int kend = kbeg + kcnt;

    const unsigned short* A0 = Ah + (size_t)bz * zA;
    const unsigned short* B0 = Bh + (size_t)bz * zB;

    const int srow = tid >> 3;                 // 0..31 (+32 per round)
    const int sq   = (tid & 7) ^ (srow & 7);
    const size_t aoff = (size_t)(bm0 + srow) * K + sq * 8;
    const size_t boff = (size_t)(bn0 + srow) * K + sq * 8;
    const size_t r32  = (size_t)32 * K;

    auto stage = [&](int b, int kt) {
        unsigned short* d = &lds[b * 16384 + (w << 9)];
        gl16(A0 + aoff + kt,           d + 0);
        gl16(A0 + aoff + kt + r32,     d + 2048);
        gl16(A0 + aoff + kt + 2 * r32, d + 4096);
        gl16(A0 + aoff + kt + 3 * r32, d + 6144);
        gl16(B0 + boff + kt,           d + 8192);
        gl16(B0 + boff + kt + r32,     d + 10240);
        gl16(B0 + boff + kt + 2 * r32, d + 12288);
        gl16(B0 + boff + kt + 3 * r32, d + 14336);
    };

    const int rowa = (wr * 64 + (l & 15)) * 64;   // ushort offset of A row
    const int rowb = (wc * 64 + (l & 15)) * 64;
    const int q0 = (((l >> 4)    ) ^ (l & 7)) << 3;   // ks=0 slot*8
    const int q1 = (((l >> 4) + 4) ^ (l & 7)) << 3;   // ks=1 slot*8

    f32x4 acc[4][4];
#pragma unroll
    for (int i = 0; i < 4; i++)
#pragma unroll
        for (int j = 0; j < 4; j++) acc[i][j] = (f32x4){0.f, 0.f, 0.f, 0.f};

    stage(0, kbeg);
    __syncthreads();
    int cur = 0;
    for (int kt = kbeg; kt < kend; kt += 64) {
        if (kt + 64 < kend) stage(cur ^ 1, kt + 64);
        const int cb = cur * 16384;
#pragma unroll
        for (int ks = 0; ks < 2; ks++) {
            const int qo = ks ? q1 : q0;
            bfrag a4[4], b4[4];
#pragma unroll
            for (int f = 0; f < 4; f++) {
                a4[f] = *(const bfrag*)&lds[cb +        rowa + f * 1024 + qo];
                b4[f] = *(const bfrag*)&lds[cb + 8192 + rowb + f * 1024 + qo];
            }
#pragma unroll
            for (int i = 0; i < 4; i++)
#pragma unroll
                for (int j = 0; j < 4; j++)
                    acc[i][j] = __builtin_amdgcn_mfma_f32_16x16x32_bf16(a4[i], b4[j], acc[i][j], 0, 0, 0);
        }
        __syncthreads();
        cur ^= 1;
    }

    // C/D layout: col = lane&15, row = (lane>>4)*4 + reg
    const int crow0 = bm0 + wr * 64 + (l >> 4) * 4;
    const int ccol0 = bn0 + wc * 64 + (l & 15);
#pragma unroll
    for (int i = 0; i < 4; i++)
#pragma unroll
        for (int j = 0; j < 4; j++)
#pragma unroll
            for (int r = 0; r < 4; r++) {
                size_t idx = (size_t)(crow0 + i * 16 + r) * N + (ccol0 + j * 16);
                float v = acc[i][j][r];
                if (EPI == 0)
                    ((float*)Cv + (size_t)bz * zC + (size_t)kz * pz)[idx] = v;
                else
                    ((unsigned short*)Cv + (size_t)bz * zC)[idx] =
                        f2bf(silu_f(fminf(fmaxf(v, -5.f), 5.f)));
            }
}

// ---------------------------------------------------------------------------
// Fused gate+up GEMM, BK=64, SINGLE-buffered (48 KB LDS -> 3 blocks/CU cap;
// inter-block overlap hides staging, m97-style). 2D XCD chunk: each XCD owns
// 8 bx x 8 by tiles (weights ~4MB + x ~2MB working set).
//   hh[n,h] = bf16( silu(x@gw^T) * (x@uw^T) )      K=1024.
// ---------------------------------------------------------------------------
__global__ __launch_bounds__(256)
void gup(const unsigned short* __restrict__ xh, const unsigned short* __restrict__ gwh,
         const unsigned short* __restrict__ uwh, unsigned short* __restrict__ hh)
{
    __shared__ __align__(16) unsigned short lds[24576];  // x | gw | uw (8192 each)
    const int tid = threadIdx.x;
    const int l   = tid & 63;
    const int w   = tid >> 6;
    const int wr  = w >> 1, wc = w & 1;

    // 2D XCD chunking over grid (16,32): xcd = id&7 owns bx in [ (xcd&1)*8, +8 ),
    // by in [ (xcd>>1)*8, +8 ).  j = id>>3 indexes within the chunk.
    int id  = blockIdx.y * gridDim.x + blockIdx.x;
    int xcd = id & 7, j = id >> 3;
    int bx  = (xcd & 1) * 8 + (j & 7);
    int by  = (xcd >> 1) * 8 + (j >> 3);
    const int bm0 = by * 128, bn0 = bx * 128;

    const int srow = tid >> 3;
    const int sq   = (tid & 7) ^ (srow & 7);
    const size_t aoff = (size_t)(bm0 + srow) * Dq + sq * 8;
    const size_t boff = (size_t)(bn0 + srow) * Dq + sq * 8;
    const size_t r32  = (size_t)32 * Dq;

    const int rowa = (wr * 64 + (l & 15)) * 64;
    const int rowb = (wc * 64 + (l & 15)) * 64;
    const int q0 = (((l >> 4)    ) ^ (l & 7)) << 3;
    const int q1 = (((l >> 4) + 4) ^ (l & 7)) << 3;

    f32x4 accg[4][4], accu[4][4];
#pragma unroll
    for (int i = 0; i < 4; i++)
#pragma unroll
        for (int jj = 0; jj < 4; jj++) {
            accg[i][jj] = (f32x4){0.f, 0.f, 0.f, 0.f};
            accu[i][jj] = (f32x4){0.f, 0.f, 0.f, 0.f};
        }

    for (int kt = 0; kt < Dq; kt += 64) {
        unsigned short* d = &lds[w << 9];
        gl16(xh  + aoff + kt,           d + 0);
        gl16(xh  + aoff + kt + r32,     d + 2048);
        gl16(xh  + aoff + kt + 2 * r32, d + 4096);
        gl16(xh  + aoff + kt + 3 * r32, d + 6144);
        gl16(gwh + boff + kt,           d + 8192);
        gl16(gwh + boff + kt + r32,     d + 10240);
        gl16(gwh + boff + kt + 2 * r32, d + 12288);
        gl16(gwh + boff + kt + 3 * r32, d + 14336);
        gl16(uwh + boff + kt,           d + 16384);
        gl16(uwh + boff + kt + r32,     d + 18432);
        gl16(uwh + boff + kt + 2 * r32, d + 20480);
        gl16(uwh + boff + kt + 3 * r32, d + 22528);
        __syncthreads();                     // drains vmcnt; buffer ready
#pragma unroll
        for (int ks = 0; ks < 2; ks++) {
            const int qo = ks ? q1 : q0;
            bfrag a4[4], g4[4], u4[4];
#pragma unroll
            for (int f = 0; f < 4; f++) {
                a4[f] = *(const bfrag*)&lds[        rowa + f * 1024 + qo];
                g4[f] = *(const bfrag*)&lds[ 8192 + rowb + f * 1024 + qo];
                u4[f] = *(const bfrag*)&lds[16384 + rowb + f * 1024 + qo];
            }
#pragma unroll
            for (int i = 0; i < 4; i++)
#pragma unroll
                for (int jj = 0; jj < 4; jj++) {
                    accg[i][jj] = __builtin_amdgcn_mfma_f32_16x16x32_bf16(a4[i], g4[jj], accg[i][jj], 0, 0, 0);
                    accu[i][jj] = __builtin_amdgcn_mfma_f32_16x16x32_bf16(a4[i], u4[jj], accu[i][jj], 0, 0, 0);
                }
        }
        __syncthreads();                     // all reads done before restage
    }

    const int crow0 = bm0 + wr * 64 + (l >> 4) * 4;
    const int ccol0 = bn0 + wc * 64 + (l & 15);
#pragma unroll
    for (int i = 0; i < 4; i++)
#pragma unroll
        for (int jj = 0; jj < 4; jj++)
#pragma unroll
            for (int r = 0; r < 4; r++) {
                size_t idx = (size_t)(crow0 + i * 16 + r) * Hq + (ccol0 + jj * 16);
                hh[idx] = f2bf(silu_f(accg[i][jj][r]) * accu[i][jj][r]);
            }
}

// ---------------------------------------------------------------------------
// Final fused GEMM, BK=64, double-buffered:  out[4096][1024] =
//   hh@dwh^T (K=2048)  +  acat@kcat^T (K=256)
// XCD swizzle: each XCD owns 4 by-rows x all 8 bx (proven 52MB fetch, r6).
// ---------------------------------------------------------------------------
__global__ __launch_bounds__(256)
void gfinal(const unsigned short* __restrict__ hh, const unsigned short* __restrict__ dwh,
            const unsigned short* __restrict__ acat, const unsigned short* __restrict__ kcat,
            float* __restrict__ out)
{
    __shared__ __align__(16) unsigned short lds[32768];
    const int tid = threadIdx.x;
    const int l   = tid & 63;
    const int w   = tid >> 6;
    const int wr  = w >> 1, wc = w & 1;

    int nb  = gridDim.x * gridDim.y;                      // 256
    int id  = blockIdx.y * gridDim.x + blockIdx.x;
    int id2 = (id & 7) * (nb >> 3) + (id >> 3);
    int bx  = id2 % gridDim.x, by = id2 / gridDim.x;
    const int bm0 = by * 128, bn0 = bx * 128;

    const int srow = tid >> 3;
    const int sq   = (tid & 7) ^ (srow & 7);
    const int rowa = (wr * 64 + (l & 15)) * 64;
    const int rowb = (wc * 64 + (l & 15)) * 64;
    const int q0 = (((l >> 4)    ) ^ (l & 7)) << 3;
    const int q1 = (((l >> 4) + 4) ^ (l & 7)) << 3;

    f32x4 acc[4][4];
#pragma unroll
    for (int i = 0; i < 4; i++)
#pragma unroll
        for (int j = 0; j < 4; j++) acc[i][j] = (f32x4){0.f, 0.f, 0.f, 0.f};

    // ---- main: K=2048 ----
    {
        const size_t aoff = (size_t)(bm0 + srow) * Hq + sq * 8;
        const size_t boff = (size_t)(bn0 + srow) * Hq + sq * 8;
        const size_t r32  = (size_t)32 * Hq;
        auto stage = [&](int b, int kt) {
            unsigned short* d = &lds[b * 16384 + (w << 9)];
            gl16(hh  + aoff + kt,           d + 0);
            gl16(hh  + aoff + kt + r32,     d + 2048);
            gl16(hh  + aoff + kt + 2 * r32, d + 4096);
            gl16(hh  + aoff + kt + 3 * r32, d + 6144);
            gl16(dwh + boff + kt,           d + 8192);
            gl16(dwh + boff + kt + r32,     d + 10240);
            gl16(dwh + boff + kt + 2 * r32, d + 12288);
            gl16(dwh + boff + kt + 3 * r32, d + 14336);
        };
        stage(0, 0);
        __syncthreads();
        int cur = 0;
        for (int kt = 0; kt < Hq; kt += 64) {
            if (kt + 64 < Hq) stage(cur ^ 1, kt + 64);
            const int cb = cur * 16384;
#pragma unroll
            for (int ks = 0; ks < 2; ks++) {
                const int qo = ks ? q1 : q0;
                bfrag a4[4], b4[4];
#pragma unroll
                for (int f = 0; f < 4; f++) {
                    a4[f] = *(const bfrag*)&lds[cb +        rowa + f * 1024 + qo];
                    b4[f] = *(const bfrag*)&lds[cb + 8192 + rowb + f * 1024 + qo];
                }
#pragma unroll
                for (int i = 0; i < 4; i++)
#pragma unroll
                    for (int j = 0; j < 4; j++)
                        acc[i][j] = __builtin_amdgcn_mfma_f32_16x16x32_bf16(a4[i], b4[j], acc[i][j], 0, 0, 0);
            }
            __syncthreads();
            cur ^= 1;
        }
    }
    // ---- tail: K=256 over [acat | kcat] ----
    {
        const size_t aoff = (size_t)(bm0 + srow) * 256 + sq * 8;
        const size_t boff = (size_t)(bn0 + srow) * 256 + sq * 8;
        const size_t r32  = (size_t)32 * 256;
        auto stage2 = [&](int b, int kt) {
            unsigned short* d = &lds[b * 16384 + (w << 9)];
            gl16(acat + aoff + kt,           d + 0);
            gl16(acat + aoff + kt + r32,     d + 2048);
            gl16(acat + aoff + kt + 2 * r32, d + 4096);
            gl16(acat + aoff + kt + 3 * r32, d + 6144);
            gl16(kcat + boff + kt,           d + 8192);
            gl16(kcat + boff + kt + r32,     d + 10240);
            gl16(kcat + boff + kt + 2 * r32, d + 12288);
            gl16(kcat + boff + kt + 3 * r32, d + 14336);
        };
        stage2(0, 0);
        __syncthreads();
        int cur = 0;
        for (int kt = 0; kt < 256; kt += 64) {
            if (kt + 64 < 256) stage2(cur ^ 1, kt + 64);
            const int cb = cur * 16384;
#pragma unroll
            for (int ks = 0; ks < 2; ks++) {
                const int qo = ks ? q1 : q0;
                bfrag a4[4], b4[4];
#pragma unroll
                for (int f = 0; f < 4; f++) {
                    a4[f] = *(const bfrag*)&lds[cb +        rowa + f * 1024 + qo];
                    b4[f] = *(const bfrag*)&lds[cb + 8192 + rowb + f * 1024 + qo];
                }
#pragma unroll
                for (int i = 0; i < 4; i++)
#pragma unroll
                    for (int j = 0; j < 4; j++)
                        acc[i][j] = __builtin_amdgcn_mfma_f32_16x16x32_bf16(a4[i], b4[j], acc[i][j], 0, 0, 0);
            }
            __syncthreads();
            cur ^= 1;
        }
    }

    const int crow0 = bm0 + wr * 64 + (l >> 4) * 4;
    const int ccol0 = bn0 + wc * 64 + (l & 15);
#pragma unroll
    for (int i = 0; i < 4; i++)
#pragma unroll
        for (int j = 0; j < 4; j++)
#pragma unroll
            for (int r = 0; r < 4; r++)
                out[(size_t)(crow0 + i * 16 + r) * Dq + ccol0 + j * 16] = acc[i][j][r];
}

// Reduce NZ split-K partials + LayerNorm over A=128 -> bf16.
template<int NZ>
__global__ __launch_bounds__(256)
void rln(const float* __restrict__ p, unsigned short* __restrict__ oh,
         const float* __restrict__ g, const float* __restrict__ b, long pstride)
{
    int row  = blockIdx.x * 4 + (threadIdx.x >> 6);
    int lane = threadIdx.x & 63;
    long base = (long)row * Aq;
    float x0 = 0.f, x1 = 0.f;
#pragma unroll
    for (int z = 0; z < NZ; z++) {
        x0 += p[base + z * pstride + lane];
        x1 += p[base + z * pstride + lane + 64];
    }
    float s  = x0 + x1;
    float ss = x0 * x0 + x1 * x1;
#pragma unroll
    for (int off = 32; off > 0; off >>= 1) {
        s  += __shfl_xor(s, off);
        ss += __shfl_xor(ss, off);
    }
    float m  = s * (1.0f / Aq);
    float v  = ss * (1.0f / Aq) - m * m;
    float rs = rsqrtf(v + 1e-5f);
    oh[base + lane]      = f2bf((x0 - m) * rs * g[lane]      + b[lane]);
    oh[base + lane + 64] = f2bf((x1 - m) * rs * g[lane + 64] + b[lane + 64]);
}

// Reduce NZ split-K partials [bz][NZ][rowsPerB][A] -> scaled bf16 with
// output row-stride/column-offset (for concatenated tail operands).
template<int NZ>
__global__ __launch_bounds__(256)
void rbf(const float* __restrict__ p, unsigned short* __restrict__ o,
         int rowsPerB, float scale, int total, int ostride, int ocol)
{
    int i = blockIdx.x * 256 + threadIdx.x;
    if (i >= total) return;
    int n = i >> 7, a = i & 127;
    int bz = n / rowsPerB, s = n - bz * rowsPerB;
    long base = ((long)bz * NZ) * rowsPerB * Aq + (long)s * Aq + a;
    float acc = 0.f;
#pragma unroll
    for (int z = 0; z < NZ; z++) acc += p[base + (long)z * rowsPerB * Aq];
    o[(long)n * ostride + ocol + a] = f2bf(acc * scale);
}

// mixed[n,:] = sum_e ew[n,e] * LN_e(h[e,n,:])  -> bf16 into acat col 128.
__global__ __launch_bounds__(256)
void mix_ln(const float* __restrict__ h, const float* __restrict__ ew,
            const float* __restrict__ g, const float* __restrict__ bb,
            unsigned short* __restrict__ acat)
{
    int n    = blockIdx.x * 4 + (threadIdx.x >> 6);
    int lane = threadIdx.x & 63;
    float a0 = 0.0f, a1 = 0.0f;
#pragma unroll
    for (int e = 0; e < Eq; e++) {
        const float* r = h + ((long)e * Nq + n) * Aq;
        float x0 = r[lane], x1 = r[lane + 64];
        float s  = x0 + x1;
        float ss = x0 * x0 + x1 * x1;
#pragma unroll
        for (int off = 32; off > 0; off >>= 1) {
            s  += __shfl_xor(s, off);
            ss += __shfl_xor(ss, off);
        }
        float m  = s * (1.0f / Aq);
        float v  = ss * (1.0f / Aq) - m * m;
        float rs = rsqrtf(v + 1e-5f);
        float wv = ew[(long)n * Eq + e];
        a0 += wv * ((x0 - m) * rs * g[e * Aq + lane]      + bb[e * Aq + lane]);
        a1 += wv * ((x1 - m) * rs * g[e * Aq + lane + 64] + bb[e * Aq + lane + 64]);
    }
    acat[(long)n * 256 + 128 + lane]      = f2bf(a0);
    acat[(long)n * 256 + 128 + lane + 64] = f2bf(a1);
}

extern "C" void kernel_launch(void* const* d_in, const int* in_sizes, int n_in,
                              void* d_out, int out_size, void* d_ws, size_t ws_size,
                              hipStream_t stream)
{
    const float* x             = (const float*)d_in[0];
    const float* ew            = (const float*)d_in[1];
    const float* up_w          = (const float*)d_in[2];
    const float* gate_w        = (const float*)d_in[3];
    const float* down_w        = (const float*)d_in[4];
    const float* pre_w         = (const float*)d_in[5];
    const float* post_w        = (const float*)d_in[6];
    const float* an_g          = (const float*)d_in[7];
    const float* an_b          = (const float*)d_in[8];
    const float* adapt_proj_w  = (const float*)d_in[9];
    const float* adapter_w     = (const float*)d_in[10];
    const float* adapter_g     = (const float*)d_in[11];
    const float* adapter_b     = (const float*)d_in[12];
    const float* expert_proj_w = (const float*)d_in[13];
    const float* output_proj_w = (const float*)d_in[14];
    float* out = (float*)d_out;

    // ---- workspace (KB offsets; peak ~81 MB) ----
#define OFF(kb) ((char*)d_ws + (size_t)(kb) * 1024)
    float* wfp  = (float*)OFF(0);        // [16][D][A] 8MB   (phase 1)
    float* kdp  = (float*)OFF(8192);     // 8MB              (phase 1)
    float* p1   = (float*)OFF(16384);    // [8][N][A] 16MB   (phase 1)
    float* p2   = (float*)OFF(0);        // [8][N][A] 16MB   (phase 3)
    unsigned short* wmat = (unsigned short*)OFF(16384);  // [B][S][S] bf16 16MB (ph 3-4)
    float* p3   = (float*)OFF(0);        // [2][8][S][A] 16MB (phase 4)
    float* h_e  = (float*)OFF(0);        // [E][N][A] 16MB    (phase 5, after p3 dead)
    unsigned short* hh   = (unsigned short*)OFF(32768);  // [N,H] 16MB
    unsigned short* xh   = (unsigned short*)OFF(49152);  // 8MB
    unsigned short* gwh  = (unsigned short*)OFF(57344);  // 4MB
    unsigned short* uwh  = (unsigned short*)OFF(61440);  // 4MB
    unsigned short* dwh  = (unsigned short*)OFF(65536);  // 4MB
    unsigned short* oph  = (unsigned short*)OFF(69632);  // 4MB
    unsigned short* pwh  = (unsigned short*)OFF(73728);  // .25MB
    unsigned short* powh = (unsigned short*)OFF(73984);  // .5MB
    unsigned short* apT  = (unsigned short*)OFF(74496);  // .5MB
    unsigned short* epT  = (unsigned short*)OFF(75008);  // .5MB
    unsigned short* ainh = (unsigned short*)OFF(75520);  // 1MB
    unsigned short* ainT = (unsigned short*)OFF(76544);  // [B][A][S] 1MB
    unsigned short* aouth= (unsigned short*)OFF(77568);  // 1MB
    unsigned short* adw  = (unsigned short*)OFF(78592);  // .25MB
    unsigned short* kcat = (unsigned short*)OFF(78848);  // [D][256] .5MB
    unsigned short* acat = (unsigned short*)OFF(79360);  // [N][256] 2MB -> 81408
#undef OFF

    dim3 blk(256);
    const long NA = (long)Nq * Aq;
    const long SA = (long)Sq * Aq;
    const long SS = (long)Sq * Sq;

    // 1. conversions + transposes
    convert_all<<<dim3(2048), blk, 0, stream>>>(x, gate_w, up_w, down_w, pre_w, post_w,
        output_proj_w, adapter_w, xh, gwh, uwh, dwh, pwh, powh, oph, adw);
    transb<float><<<dim3(4, 64, 1), blk, 0, stream>>>(adapt_proj_w,  apT, Hq, Aq);
    transb<float><<<dim3(4, 64, 1), blk, 0, stream>>>(expert_proj_w, epT, Hq, Aq);

    // 2. weight fusions: kcat = [down@adapt_proj | op@ep]  (split-K 16)
    mg<0><<<dim3(1, 8, 16), blk, 0, stream>>>(oph, epT, wfp, Aq, Hq, 16,
        0, 0, 0, (long)Dq * Aq);
    mg<0><<<dim3(1, 8, 16), blk, 0, stream>>>(dwh, apT, kdp, Aq, Hq, 16,
        0, 0, 0, (long)Dq * Aq);
    rbf<16><<<dim3(512), blk, 0, stream>>>(kdp, kcat, Dq, 1.0f, Dq * Aq, 256, 0);
    rbf<16><<<dim3(512), blk, 0, stream>>>(wfp, kcat, Dq, 1.0f, Dq * Aq, 256, 128);

    // 3. ain = LN(x @ pre_w^T)  (split-K 8)
    mg<0><<<dim3(1, 32, 8), blk, 0, stream>>>(xh, pwh, p1, Aq, Dq, 8, 0, 0, 0, NA);
    rln<8><<<dim3(1024), blk, 0, stream>>>(p1, ainh, an_g, an_b, NA);
    transb<unsigned short><<<dim3(4, 64, 2), blk, 0, stream>>>(ainh, ainT, Sq, Aq);

    // 4. fused SwiGLU: hh = bf16(silu(x@gw^T) * (x@uw^T))
    gup<<<dim3(16, 32), blk, 0, stream>>>(xh, gwh, uwh, hh);

    // 5. aout = LN(hidden @ post_w^T)  (split-K 8)
    mg<0><<<dim3(1, 32, 8), blk, 0, stream>>>(hh, powh, p2, Aq, Hq, 8, 0, 0, 0, NA);
    rln<8><<<dim3(1024), blk, 0, stream>>>(p2, aouth, an_g, an_b, NA);

    // 6. wmat = bf16(silu(clip(ain @ aout^T)))  per batch
    mg<1><<<dim3(16, 16, 2), blk, 0, stream>>>(ainh, aouth, wmat, Sq, Aq, 1,
        SA, SA, SS, 0);

    // 7. acat[:,0:128] = 0.1 * (wmat @ ain)  (split-K 8, batched)
    mg<0><<<dim3(1, 16, 16), blk, 0, stream>>>(wmat, ainT, p3, Aq, Sq, 8,
        SS, SA, 8 * SA, SA);
    rbf<8><<<dim3(2048), blk, 0, stream>>>(p3, acat, Sq, 0.1f, Nq * Aq, 256, 0);

    // 8. expert path: h_e, then acat[:,128:256] = mixed
    mg<0><<<dim3(1, 32, 8), blk, 0, stream>>>(ainh, adw, h_e, Aq, Aq, 1,
        0, (long)Aq * Aq, NA, 0);
    mix_ln<<<dim3(1024), blk, 0, stream>>>(h_e, ew, adapter_g, adapter_b, acat);

    // 9. out = hh@dwh^T + acat@kcat^T
    gfinal<<<dim3(8, 32), blk, 0, stream>>>(hh, dwh, acat, kcat, out);
}

// Round 9
// 177.963 us; speedup vs baseline: 6.4432x; 1.1207x over previous
//
#include <hip/hip_runtime.h>
#include <hip/hip_bf16.h>
#include <math.h>

// Problem constants (B,S,D,E = 2,2048,1024,8)
#define Bq 2
#define Sq 2048
#define Dq 1024
#define Eq 8
#define Hq 2048            // 2*D
#define Aq 128             // H/16
#define Nq (Bq*Sq)         // 4096 tokens

typedef __attribute__((ext_vector_type(4))) float f32x4;
typedef __attribute__((ext_vector_type(8))) short bfrag;   // 8 bf16 in 4 VGPRs

__device__ __forceinline__ float silu_f(float x) {
    return x / (1.0f + expf(-x));
}
__device__ __forceinline__ unsigned short f2bf(float x) {  // RNE fp32->bf16
    unsigned u = __float_as_uint(x);
    u += 0x7fffu + ((u >> 16) & 1u);
    return (unsigned short)(u >> 16);
}
__device__ __forceinline__ float bf2f(unsigned short h) {
    return __uint_as_float(((unsigned)h) << 16);
}
__device__ __forceinline__ void gl16(const unsigned short* g, unsigned short* l) {
    __builtin_amdgcn_global_load_lds(
        (const __attribute__((address_space(1))) void*)g,
        (__attribute__((address_space(3))) void*)(void*)l, 16, 0, 0);
}

// ---------------------------------------------------------------------------
// BK=64 staging/fragment scheme (shared by mg/gup/gfinal):
//  Panel = [128 rows][64 cols] bf16 = 16 KB, staged in 4 gl16 rounds.
//  LDS(row, q) holds G(row, q ^ (row&7)) -> pre-swizzled global source,
//  linear LDS dest, conflict-free ds_read_b128 (verified: bank conflicts = 0).
// ---------------------------------------------------------------------------

__global__ __launch_bounds__(256)
void convert_all(const float* __restrict__ x,  const float* __restrict__ gw,
                 const float* __restrict__ uw, const float* __restrict__ dw,
                 const float* __restrict__ pw, const float* __restrict__ ow,
                 const float* __restrict__ opw, const float* __restrict__ aw,
                 unsigned short* xh,  unsigned short* gwh, unsigned short* uwh,
                 unsigned short* dwh, unsigned short* pwh, unsigned short* powh,
                 unsigned short* oph, unsigned short* adw)
{
    const int T = 3276800;
    for (int i = blockIdx.x * 256 + threadIdx.x; i < T; i += gridDim.x * 256) {
        const float* in; unsigned short* hi; int j = i;
        if (j < 1048576)                 { in = x;   hi = xh;  }
        else if ((j -= 1048576) < 524288){ in = gw;  hi = gwh; }
        else if ((j -= 524288) < 524288) { in = uw;  hi = uwh; }
        else if ((j -= 524288) < 524288) { in = dw;  hi = dwh; }
        else if ((j -= 524288) < 32768)  { in = pw;  hi = pwh; }
        else if ((j -= 32768) < 65536)   { in = ow;  hi = powh; }
        else if ((j -= 65536) < 524288)  { in = opw; hi = oph; }
        else { j -= 524288;                in = aw;  hi = adw; }
        float4 v = ((const float4*)in)[j];
        ((ushort4*)hi)[j] = make_ushort4(f2bf(v.x), f2bf(v.y), f2bf(v.z), f2bf(v.w));
    }
}

// Transpose [R][C] -> bf16 [C][R], batched by blockIdx.z.
template<typename TIN>
__global__ __launch_bounds__(256)
void transb(const TIN* __restrict__ in, unsigned short* __restrict__ out, int R, int C)
{
    __shared__ float t[32][33];
    in  += (size_t)blockIdx.z * R * C;
    out += (size_t)blockIdx.z * R * C;
    int tx = threadIdx.x & 31, ty = threadIdx.x >> 5;
    int r0 = blockIdx.y * 32, c0 = blockIdx.x * 32;
#pragma unroll
    for (int j = 0; j < 4; j++) {
        TIN v = in[(size_t)(r0 + ty + j * 8) * C + c0 + tx];
        float f;
        if (sizeof(TIN) == 2) f = bf2f(*(const unsigned short*)&v);
        else                  f = *(const float*)&v;
        t[ty + j * 8][tx] = f;
    }
    __syncthreads();
#pragma unroll
    for (int j = 0; j < 4; j++)
        out[(size_t)(c0 + ty + j * 8) * R + r0 + tx] = f2bf(t[tx][ty + j * 8]);
}

// ---------------------------------------------------------------------------
// 1-term bf16 MFMA GEMM, BK=64, double-buffered. 128x128 tile, 4 waves.
// EPI: 0 = fp32 store (+bz*zC+kz*pz); 1 = bf16 silu-clip store (+bz*zC).
// ---------------------------------------------------------------------------
template<int EPI>
__global__ __launch_bounds__(256)
void mg(const unsigned short* __restrict__ Ah, const unsigned short* __restrict__ Bh,
        void* __restrict__ Cv, int N, int K, int kchunks,
        long zA, long zB, long zC, long pz)
{
    __shared__ __align__(16) unsigned short lds[32768];  // 2 bufs x (A 8192 | B 8192)

    const int tid = threadIdx.x;
    const int l   = tid & 63;
    const int w   = tid >> 6;
    const int wr  = w >> 1, wc = w & 1;
    const int bm0 = blockIdx.y * 128, bn0 = blockIdx.x * 128;
    const int bz  = blockIdx.z / kchunks;
    const int kz  = blockIdx.z - bz * kchunks;
    const int kcnt = K / kchunks;
    const int kbeg = kz * kcnt;
    const int kend = kbeg + kcnt;

    const unsigned short* A0 = Ah + (size_t)bz * zA;
    const unsigned short* B0 = Bh + (size_t)bz * zB;

    const int srow = tid >> 3;                 // 0..31 (+32 per round)
    const int sq   = (tid & 7) ^ (srow & 7);
    const size_t aoff = (size_t)(bm0 + srow) * K + sq * 8;
    const size_t boff = (size_t)(bn0 + srow) * K + sq * 8;
    const size_t r32  = (size_t)32 * K;

    auto stage = [&](int b, int kt) {
        unsigned short* d = &lds[b * 16384 + (w << 9)];
        gl16(A0 + aoff + kt,           d + 0);
        gl16(A0 + aoff + kt + r32,     d + 2048);
        gl16(A0 + aoff + kt + 2 * r32, d + 4096);
        gl16(A0 + aoff + kt + 3 * r32, d + 6144);
        gl16(B0 + boff + kt,           d + 8192);
        gl16(B0 + boff + kt + r32,     d + 10240);
        gl16(B0 + boff + kt + 2 * r32, d + 12288);
        gl16(B0 + boff + kt + 3 * r32, d + 14336);
    };

    const int rowa = (wr * 64 + (l & 15)) * 64;   // ushort offset of A row
    const int rowb = (wc * 64 + (l & 15)) * 64;
    const int q0 = (((l >> 4)    ) ^ (l & 7)) << 3;   // ks=0 slot*8
    const int q1 = (((l >> 4) + 4) ^ (l & 7)) << 3;   // ks=1 slot*8

    f32x4 acc[4][4];
#pragma unroll
    for (int i = 0; i < 4; i++)
#pragma unroll
        for (int j = 0; j < 4; j++) acc[i][j] = (f32x4){0.f, 0.f, 0.f, 0.f};

    stage(0, kbeg);
    __syncthreads();
    int cur = 0;
    for (int kt = kbeg; kt < kend; kt += 64) {
        if (kt + 64 < kend) stage(cur ^ 1, kt + 64);
        const int cb = cur * 16384;
#pragma unroll
        for (int ks = 0; ks < 2; ks++) {
            const int qo = ks ? q1 : q0;
            bfrag a4[4], b4[4];
#pragma unroll
            for (int f = 0; f < 4; f++) {
                a4[f] = *(const bfrag*)&lds[cb +        rowa + f * 1024 + qo];
                b4[f] = *(const bfrag*)&lds[cb + 8192 + rowb + f * 1024 + qo];
            }
#pragma unroll
            for (int i = 0; i < 4; i++)
#pragma unroll
                for (int j = 0; j < 4; j++)
                    acc[i][j] = __builtin_amdgcn_mfma_f32_16x16x32_bf16(a4[i], b4[j], acc[i][j], 0, 0, 0);
        }
        __syncthreads();
        cur ^= 1;
    }

    const int crow0 = bm0 + wr * 64 + (l >> 4) * 4;
    const int ccol0 = bn0 + wc * 64 + (l & 15);
#pragma unroll
    for (int i = 0; i < 4; i++)
#pragma unroll
        for (int j = 0; j < 4; j++)
#pragma unroll
            for (int r = 0; r < 4; r++) {
                size_t idx = (size_t)(crow0 + i * 16 + r) * N + (ccol0 + j * 16);
                float v = acc[i][j][r];
                if (EPI == 0)
                    ((float*)Cv + (size_t)bz * zC + (size_t)kz * pz)[idx] = v;
                else
                    ((unsigned short*)Cv + (size_t)bz * zC)[idx] =
                        f2bf(silu_f(fminf(fmaxf(v, -5.f), 5.f)));
            }
}

// ---------------------------------------------------------------------------
// Fused gate+up GEMM, BK=64, DOUBLE-buffered (96 KB LDS, 1 block/CU — in-block
// pipeline is the only latency cover at this occupancy; round-8 single-buf at
// 2/CU left ~80% stall). 2D XCD chunk (proven: FETCH 70->41 MB).
//   hh[n,h] = bf16( silu(x@gw^T) * (x@uw^T) )      K=1024.
// ---------------------------------------------------------------------------
__global__ __launch_bounds__(256)
void gup(const unsigned short* __restrict__ xh, const unsigned short* __restrict__ gwh,
         const unsigned short* __restrict__ uwh, unsigned short* __restrict__ hh)
{
    __shared__ __align__(16) unsigned short lds[49152];  // 2 bufs x (x|gw|uw 24576)
    const int tid = threadIdx.x;
    const int l   = tid & 63;
    const int w   = tid >> 6;
    const int wr  = w >> 1, wc = w & 1;

    int id  = blockIdx.y * gridDim.x + blockIdx.x;
    int xcd = id & 7, j = id >> 3;
    int bx  = (xcd & 1) * 8 + (j & 7);
    int by  = (xcd >> 1) * 8 + (j >> 3);
    const int bm0 = by * 128, bn0 = bx * 128;

    const int srow = tid >> 3;
    const int sq   = (tid & 7) ^ (srow & 7);
    const size_t aoff = (size_t)(bm0 + srow) * Dq + sq * 8;
    const size_t boff = (size_t)(bn0 + srow) * Dq + sq * 8;
    const size_t r32  = (size_t)32 * Dq;

    const int rowa = (wr * 64 + (l & 15)) * 64;
    const int rowb = (wc * 64 + (l & 15)) * 64;
    const int q0 = (((l >> 4)    ) ^ (l & 7)) << 3;
    const int q1 = (((l >> 4) + 4) ^ (l & 7)) << 3;

    auto stage = [&](int b, int kt) {
        unsigned short* d = &lds[b * 24576 + (w << 9)];
        gl16(xh  + aoff + kt,           d + 0);
        gl16(xh  + aoff + kt + r32,     d + 2048);
        gl16(xh  + aoff + kt + 2 * r32, d + 4096);
        gl16(xh  + aoff + kt + 3 * r32, d + 6144);
        gl16(gwh + boff + kt,           d + 8192);
        gl16(gwh + boff + kt + r32,     d + 10240);
        gl16(gwh + boff + kt + 2 * r32, d + 12288);
        gl16(gwh + boff + kt + 3 * r32, d + 14336);
        gl16(uwh + boff + kt,           d + 16384);
        gl16(uwh + boff + kt + r32,     d + 18432);
        gl16(uwh + boff + kt + 2 * r32, d + 20480);
        gl16(uwh + boff + kt + 3 * r32, d + 22528);
    };

    f32x4 accg[4][4], accu[4][4];
#pragma unroll
    for (int i = 0; i < 4; i++)
#pragma unroll
        for (int jj = 0; jj < 4; jj++) {
            accg[i][jj] = (f32x4){0.f, 0.f, 0.f, 0.f};
            accu[i][jj] = (f32x4){0.f, 0.f, 0.f, 0.f};
        }

    stage(0, 0);
    __syncthreads();
    int cur = 0;
    for (int kt = 0; kt < Dq; kt += 64) {
        if (kt + 64 < Dq) stage(cur ^ 1, kt + 64);   // next tile flies over compute
        const int cb = cur * 24576;
#pragma unroll
        for (int ks = 0; ks < 2; ks++) {
            const int qo = ks ? q1 : q0;
            bfrag a4[4], g4[4], u4[4];
#pragma unroll
            for (int f = 0; f < 4; f++) {
                a4[f] = *(const bfrag*)&lds[cb +         rowa + f * 1024 + qo];
                g4[f] = *(const bfrag*)&lds[cb +  8192 + rowb + f * 1024 + qo];
                u4[f] = *(const bfrag*)&lds[cb + 16384 + rowb + f * 1024 + qo];
            }
#pragma unroll
            for (int i = 0; i < 4; i++)
#pragma unroll
                for (int jj = 0; jj < 4; jj++) {
                    accg[i][jj] = __builtin_amdgcn_mfma_f32_16x16x32_bf16(a4[i], g4[jj], accg[i][jj], 0, 0, 0);
                    accu[i][jj] = __builtin_amdgcn_mfma_f32_16x16x32_bf16(a4[i], u4[jj], accu[i][jj], 0, 0, 0);
                }
        }
        __syncthreads();
        cur ^= 1;
    }

    const int crow0 = bm0 + wr * 64 + (l >> 4) * 4;
    const int ccol0 = bn0 + wc * 64 + (l & 15);
#pragma unroll
    for (int i = 0; i < 4; i++)
#pragma unroll
        for (int jj = 0; jj < 4; jj++)
#pragma unroll
            for (int r = 0; r < 4; r++) {
                size_t idx = (size_t)(crow0 + i * 16 + r) * Hq + (ccol0 + jj * 16);
                hh[idx] = f2bf(silu_f(accg[i][jj][r]) * accu[i][jj][r]);
            }
}

// ---------------------------------------------------------------------------
// Final fused GEMM, BK=64, double-buffered:  out[4096][1024] =
//   hh@dwh^T (K=2048)  +  acat@kcat^T (K=256)
// ---------------------------------------------------------------------------
__global__ __launch_bounds__(256)
void gfinal(const unsigned short* __restrict__ hh, const unsigned short* __restrict__ dwh,
            const unsigned short* __restrict__ acat, const unsigned short* __restrict__ kcat,
            float* __restrict__ out)
{
    __shared__ __align__(16) unsigned short lds[32768];
    const int tid = threadIdx.x;
    const int l   = tid & 63;
    const int w   = tid >> 6;
    const int wr  = w >> 1, wc = w & 1;

    int nb  = gridDim.x * gridDim.y;                      // 256
    int id  = blockIdx.y * gridDim.x + blockIdx.x;
    int id2 = (id & 7) * (nb >> 3) + (id >> 3);
    int bx  = id2 % gridDim.x, by = id2 / gridDim.x;
    const int bm0 = by * 128, bn0 = bx * 128;

    const int srow = tid >> 3;
    const int sq   = (tid & 7) ^ (srow & 7);
    const int rowa = (wr * 64 + (l & 15)) * 64;
    const int rowb = (wc * 64 + (l & 15)) * 64;
    const int q0 = (((l >> 4)    ) ^ (l & 7)) << 3;
    const int q1 = (((l >> 4) + 4) ^ (l & 7)) << 3;

    f32x4 acc[4][4];
#pragma unroll
    for (int i = 0; i < 4; i++)
#pragma unroll
        for (int j = 0; j < 4; j++) acc[i][j] = (f32x4){0.f, 0.f, 0.f, 0.f};

    // ---- main: K=2048 ----
    {
        const size_t aoff = (size_t)(bm0 + srow) * Hq + sq * 8;
        const size_t boff = (size_t)(bn0 + srow) * Hq + sq * 8;
        const size_t r32  = (size_t)32 * Hq;
        auto stage = [&](int b, int kt) {
            unsigned short* d = &lds[b * 16384 + (w << 9)];
            gl16(hh  + aoff + kt,           d + 0);
            gl16(hh  + aoff + kt + r32,     d + 2048);
            gl16(hh  + aoff + kt + 2 * r32, d + 4096);
            gl16(hh  + aoff + kt + 3 * r32, d + 6144);
            gl16(dwh + boff + kt,           d + 8192);
            gl16(dwh + boff + kt + r32,     d + 10240);
            gl16(dwh + boff + kt + 2 * r32, d + 12288);
            gl16(dwh + boff + kt + 3 * r32, d + 14336);
        };
        stage(0, 0);
        __syncthreads();
        int cur = 0;
        for (int kt = 0; kt < Hq; kt += 64) {
            if (kt + 64 < Hq) stage(cur ^ 1, kt + 64);
            const int cb = cur * 16384;
#pragma unroll
            for (int ks = 0; ks < 2; ks++) {
                const int qo = ks ? q1 : q0;
                bfrag a4[4], b4[4];
#pragma unroll
                for (int f = 0; f < 4; f++) {
                    a4[f] = *(const bfrag*)&lds[cb +        rowa + f * 1024 + qo];
                    b4[f] = *(const bfrag*)&lds[cb + 8192 + rowb + f * 1024 + qo];
                }
#pragma unroll
                for (int i = 0; i < 4; i++)
#pragma unroll
                    for (int j = 0; j < 4; j++)
                        acc[i][j] = __builtin_amdgcn_mfma_f32_16x16x32_bf16(a4[i], b4[j], acc[i][j], 0, 0, 0);
            }
            __syncthreads();
            cur ^= 1;
        }
    }
    // ---- tail: K=256 over [acat | kcat] ----
    {
        const size_t aoff = (size_t)(bm0 + srow) * 256 + sq * 8;
        const size_t boff = (size_t)(bn0 + srow) * 256 + sq * 8;
        const size_t r32  = (size_t)32 * 256;
        auto stage2 = [&](int b, int kt) {
            unsigned short* d = &lds[b * 16384 + (w << 9)];
            gl16(acat + aoff + kt,           d + 0);
            gl16(acat + aoff + kt + r32,     d + 2048);
            gl16(acat + aoff + kt + 2 * r32, d + 4096);
            gl16(acat + aoff + kt + 3 * r32, d + 6144);
            gl16(kcat + boff + kt,           d + 8192);
            gl16(kcat + boff + kt + r32,     d + 10240);
            gl16(kcat + boff + kt + 2 * r32, d + 12288);
            gl16(kcat + boff + kt + 3 * r32, d + 14336);
        };
        stage2(0, 0);
        __syncthreads();
        int cur = 0;
        for (int kt = 0; kt < 256; kt += 64) {
            if (kt + 64 < 256) stage2(cur ^ 1, kt + 64);
            const int cb = cur * 16384;
#pragma unroll
            for (int ks = 0; ks < 2; ks++) {
                const int qo = ks ? q1 : q0;
                bfrag a4[4], b4[4];
#pragma unroll
                for (int f = 0; f < 4; f++) {
                    a4[f] = *(const bfrag*)&lds[cb +        rowa + f * 1024 + qo];
                    b4[f] = *(const bfrag*)&lds[cb + 8192 + rowb + f * 1024 + qo];
                }
#pragma unroll
                for (int i = 0; i < 4; i++)
#pragma unroll
                    for (int j = 0; j < 4; j++)
                        acc[i][j] = __builtin_amdgcn_mfma_f32_16x16x32_bf16(a4[i], b4[j], acc[i][j], 0, 0, 0);
            }
            __syncthreads();
            cur ^= 1;
        }
    }

    const int crow0 = bm0 + wr * 64 + (l >> 4) * 4;
    const int ccol0 = bn0 + wc * 64 + (l & 15);
#pragma unroll
    for (int i = 0; i < 4; i++)
#pragma unroll
        for (int j = 0; j < 4; j++)
#pragma unroll
            for (int r = 0; r < 4; r++)
                out[(size_t)(crow0 + i * 16 + r) * Dq + ccol0 + j * 16] = acc[i][j][r];
}

// Reduce NZ split-K partials + LayerNorm over A=128 -> bf16.
template<int NZ>
__global__ __launch_bounds__(256)
void rln(const float* __restrict__ p, unsigned short* __restrict__ oh,
         const float* __restrict__ g, const float* __restrict__ b, long pstride)
{
    int row  = blockIdx.x * 4 + (threadIdx.x >> 6);
    int lane = threadIdx.x & 63;
    long base = (long)row * Aq;
    float x0 = 0.f, x1 = 0.f;
#pragma unroll
    for (int z = 0; z < NZ; z++) {
        x0 += p[base + z * pstride + lane];
        x1 += p[base + z * pstride + lane + 64];
    }
    float s  = x0 + x1;
    float ss = x0 * x0 + x1 * x1;
#pragma unroll
    for (int off = 32; off > 0; off >>= 1) {
        s  += __shfl_xor(s, off);
        ss += __shfl_xor(ss, off);
    }
    float m  = s * (1.0f / Aq);
    float v  = ss * (1.0f / Aq) - m * m;
    float rs = rsqrtf(v + 1e-5f);
    oh[base + lane]      = f2bf((x0 - m) * rs * g[lane]      + b[lane]);
    oh[base + lane + 64] = f2bf((x1 - m) * rs * g[lane + 64] + b[lane + 64]);
}

// Reduce NZ split-K partials [bz][NZ][rowsPerB][A] -> scaled bf16.
// Output col = ocol + bz*ocolStep (lets one launch fill both kcat halves).
template<int NZ>
__global__ __launch_bounds__(256)
void rbf(const float* __restrict__ p, unsigned short* __restrict__ o,
         int rowsPerB, float scale, int total, int ostride, int ocol, int ocolStep)
{
    int i = blockIdx.x * 256 + threadIdx.x;
    if (i >= total) return;
    int n = i >> 7, a = i & 127;
    int bz = n / rowsPerB, s = n - bz * rowsPerB;
    long base = ((long)bz * NZ) * rowsPerB * Aq + (long)s * Aq + a;
    float acc = 0.f;
#pragma unroll
    for (int z = 0; z < NZ; z++) acc += p[base + (long)z * rowsPerB * Aq];
    o[(long)s * ostride + (ocol + bz * ocolStep) + a +
      (ocolStep ? 0 : (long)bz * rowsPerB * ostride)] = f2bf(acc * scale);
}

// mixed[n,:] = sum_e ew[n,e] * LN_e(h[e,n,:])  -> bf16 into acat col 128.
__global__ __launch_bounds__(256)
void mix_ln(const float* __restrict__ h, const float* __restrict__ ew,
            const float* __restrict__ g, const float* __restrict__ bb,
            unsigned short* __restrict__ acat)
{
    int n    = blockIdx.x * 4 + (threadIdx.x >> 6);
    int lane = threadIdx.x & 63;
    float a0 = 0.0f, a1 = 0.0f;
#pragma unroll
    for (int e = 0; e < Eq; e++) {
        const float* r = h + ((long)e * Nq + n) * Aq;
        float x0 = r[lane], x1 = r[lane + 64];
        float s  = x0 + x1;
        float ss = x0 * x0 + x1 * x1;
#pragma unroll
        for (int off = 32; off > 0; off >>= 1) {
            s  += __shfl_xor(s, off);
            ss += __shfl_xor(ss, off);
        }
        float m  = s * (1.0f / Aq);
        float v  = ss * (1.0f / Aq) - m * m;
        float rs = rsqrtf(v + 1e-5f);
        float wv = ew[(long)n * Eq + e];
        a0 += wv * ((x0 - m) * rs * g[e * Aq + lane]      + bb[e * Aq + lane]);
        a1 += wv * ((x1 - m) * rs * g[e * Aq + lane + 64] + bb[e * Aq + lane + 64]);
    }
    acat[(long)n * 256 + 128 + lane]      = f2bf(a0);
    acat[(long)n * 256 + 128 + lane + 64] = f2bf(a1);
}

extern "C" void kernel_launch(void* const* d_in, const int* in_sizes, int n_in,
                              void* d_out, int out_size, void* d_ws, size_t ws_size,
                              hipStream_t stream)
{
    const float* x             = (const float*)d_in[0];
    const float* ew            = (const float*)d_in[1];
    const float* up_w          = (const float*)d_in[2];
    const float* gate_w        = (const float*)d_in[3];
    const float* down_w        = (const float*)d_in[4];
    const float* pre_w         = (const float*)d_in[5];
    const float* post_w        = (const float*)d_in[6];
    const float* an_g          = (const float*)d_in[7];
    const float* an_b          = (const float*)d_in[8];
    const float* adapt_proj_w  = (const float*)d_in[9];
    const float* adapter_w     = (const float*)d_in[10];
    const float* adapter_g     = (const float*)d_in[11];
    const float* adapter_b     = (const float*)d_in[12];
    const float* expert_proj_w = (const float*)d_in[13];
    const float* output_proj_w = (const float*)d_in[14];
    float* out = (float*)d_out;

    // ---- workspace (KB offsets; peak ~81 MB) ----
#define OFF(kb) ((char*)d_ws + (size_t)(kb) * 1024)
    float* kdp  = (float*)OFF(0);        // [16][D][A] 8MB   (phase 1, bz=0)
    float* wfp  = (float*)OFF(8192);     // 8MB              (phase 1, bz=1)
    float* p1   = (float*)OFF(16384);    // [8][N][A] 16MB   (phase 1)
    float* p2   = (float*)OFF(0);        // [8][N][A] 16MB   (phase 3)
    unsigned short* wmat = (unsigned short*)OFF(16384);  // [B][S][S] bf16 16MB (ph 3-4)
    float* p3   = (float*)OFF(0);        // [2][8][S][A] 16MB (phase 4)
    float* h_e  = (float*)OFF(0);        // [E][N][A] 16MB    (phase 5, after p3 dead)
    unsigned short* hh   = (unsigned short*)OFF(32768);  // [N,H] 16MB
    unsigned short* xh   = (unsigned short*)OFF(49152);  // 8MB
    unsigned short* gwh  = (unsigned short*)OFF(57344);  // 4MB
    unsigned short* uwh  = (unsigned short*)OFF(61440);  // 4MB
    unsigned short* dwh  = (unsigned short*)OFF(65536);  // 4MB   } contiguous pair
    unsigned short* oph  = (unsigned short*)OFF(69632);  // 4MB   } for batched kcat
    unsigned short* pwh  = (unsigned short*)OFF(73728);  // .25MB
    unsigned short* powh = (unsigned short*)OFF(73984);  // .5MB
    unsigned short* apT  = (unsigned short*)OFF(74496);  // .5MB  } contiguous pair
    unsigned short* epT  = (unsigned short*)OFF(75008);  // .5MB  }
    unsigned short* ainh = (unsigned short*)OFF(75520);  // 1MB
    unsigned short* ainT = (unsigned short*)OFF(76544);  // [B][A][S] 1MB
    unsigned short* aouth= (unsigned short*)OFF(77568);  // 1MB
    unsigned short* adw  = (unsigned short*)OFF(78592);  // .25MB
    unsigned short* kcat = (unsigned short*)OFF(78848);  // [D][256] .5MB
    unsigned short* acat = (unsigned short*)OFF(79360);  // [N][256] 2MB -> 81408
#undef OFF

    dim3 blk(256);
    const long NA = (long)Nq * Aq;
    const long SA = (long)Sq * Aq;
    const long SS = (long)Sq * Sq;

    // 1. conversions + transposes
    convert_all<<<dim3(2048), blk, 0, stream>>>(x, gate_w, up_w, down_w, pre_w, post_w,
        output_proj_w, adapter_w, xh, gwh, uwh, dwh, pwh, powh, oph, adw);
    transb<float><<<dim3(4, 64, 1), blk, 0, stream>>>(adapt_proj_w,  apT, Hq, Aq);
    transb<float><<<dim3(4, 64, 1), blk, 0, stream>>>(expert_proj_w, epT, Hq, Aq);

    // 2. weight fusions (batched bz=2): bz0 = dwh@apT -> kdp, bz1 = oph@epT -> wfp
    mg<0><<<dim3(1, 8, 32), blk, 0, stream>>>(dwh, apT, kdp, Aq, Hq, 16,
        (long)Dq * Hq, (long)Aq * Hq, (long)16 * Dq * Aq, (long)Dq * Aq);
    // merged reduce: bz0 -> kcat cols 0..127, bz1 -> cols 128..255
    rbf<16><<<dim3(1024), blk, 0, stream>>>(kdp, kcat, Dq, 1.0f, 2 * Dq * Aq, 256, 0, 128);

    // 3. ain = LN(x @ pre_w^T)  (split-K 8)
    mg<0><<<dim3(1, 32, 8), blk, 0, stream>>>(xh, pwh, p1, Aq, Dq, 8, 0, 0, 0, NA);
    rln<8><<<dim3(1024), blk, 0, stream>>>(p1, ainh, an_g, an_b, NA);
    transb<unsigned short><<<dim3(4, 64, 2), blk, 0, stream>>>(ainh, ainT, Sq, Aq);

    // 4. fused SwiGLU: hh = bf16(silu(x@gw^T) * (x@uw^T))
    gup<<<dim3(16, 32), blk, 0, stream>>>(xh, gwh, uwh, hh);

    // 5. aout = LN(hidden @ post_w^T)  (split-K 8)
    mg<0><<<dim3(1, 32, 8), blk, 0, stream>>>(hh, powh, p2, Aq, Hq, 8, 0, 0, 0, NA);
    rln<8><<<dim3(1024), blk, 0, stream>>>(p2, aouth, an_g, an_b, NA);

    // 6. wmat = bf16(silu(clip(ain @ aout^T)))  per batch
    mg<1><<<dim3(16, 16, 2), blk, 0, stream>>>(ainh, aouth, wmat, Sq, Aq, 1,
        SA, SA, SS, 0);

    // 7. acat[:,0:128] = 0.1 * (wmat @ ain)  (split-K 8, batched)
    mg<0><<<dim3(1, 16, 16), blk, 0, stream>>>(wmat, ainT, p3, Aq, Sq, 8,
        SS, SA, 8 * SA, SA);
    rbf<8><<<dim3(2048), blk, 0, stream>>>(p3, acat, Sq, 0.1f, Nq * Aq, 256, 0, 0);

    // 8. expert path: h_e, then acat[:,128:256] = mixed
    mg<0><<<dim3(1, 32, 8), blk, 0, stream>>>(ainh, adw, h_e, Aq, Aq, 1,
        0, (long)Aq * Aq, NA, 0);
    mix_ln<<<dim3(1024), blk, 0, stream>>>(h_e, ew, adapter_g, adapter_b, acat);

    // 9. out = hh@dwh^T + acat@kcat^T
    gfinal<<<dim3(8, 32), blk, 0, stream>>>(hh, dwh, acat, kcat, out);
}

// Round 10
// 168.489 us; speedup vs baseline: 6.8055x; 1.0562x over previous
//
#include <hip/hip_runtime.h>
#include <hip/hip_bf16.h>
#include <math.h>

// Problem constants (B,S,D,E = 2,2048,1024,8)
#define Bq 2
#define Sq 2048
#define Dq 1024
#define Eq 8
#define Hq 2048            // 2*D
#define Aq 128             // H/16
#define Nq (Bq*Sq)         // 4096 tokens

typedef __attribute__((ext_vector_type(4))) float f32x4;
typedef __attribute__((ext_vector_type(8))) short bfrag;   // 8 bf16 in 4 VGPRs

__device__ __forceinline__ float silu_f(float x) {
    return x / (1.0f + expf(-x));
}
__device__ __forceinline__ unsigned short f2bf(float x) {  // RNE fp32->bf16
    unsigned u = __float_as_uint(x);
    u += 0x7fffu + ((u >> 16) & 1u);
    return (unsigned short)(u >> 16);
}
__device__ __forceinline__ float bf2f(unsigned short h) {
    return __uint_as_float(((unsigned)h) << 16);
}
__device__ __forceinline__ void gl16(const unsigned short* g, unsigned short* l) {
    __builtin_amdgcn_global_load_lds(
        (const __attribute__((address_space(1))) void*)g,
        (__attribute__((address_space(3))) void*)(void*)l, 16, 0, 0);
}

// Counted-vmcnt wait-then-barrier (T4): each wave waits for ITS loads, then
// all waves rendezvous -> collective completion; next tile's N loads stay in
// flight across the barrier. Raw s_barrier has no fence semantics -> explicit
// memory-clobber fences pin LDS reads after the wait.
#define WAITV_BAR(N)                                            \
    asm volatile("s_waitcnt vmcnt(" #N ")" ::: "memory");       \
    __builtin_amdgcn_s_barrier();                               \
    asm volatile("" ::: "memory")
#define END_BAR()                                               \
    asm volatile("" ::: "memory");                              \
    __builtin_amdgcn_s_barrier();                               \
    asm volatile("" ::: "memory")

// ---------------------------------------------------------------------------
// BK=64 staging/fragment scheme (shared by mg/gup/gfinal):
//  Panel = [128 rows][64 cols] bf16 = 16 KB, staged in 4 gl16 rounds.
//  LDS(row, q) holds G(row, q ^ (row&7)) -> pre-swizzled global source,
//  linear LDS dest, conflict-free ds_read_b128 (verified: bank conflicts = 0).
// ---------------------------------------------------------------------------

__global__ __launch_bounds__(256)
void convert_all(const float* __restrict__ x,  const float* __restrict__ gw,
                 const float* __restrict__ uw, const float* __restrict__ dw,
                 const float* __restrict__ pw, const float* __restrict__ ow,
                 const float* __restrict__ opw, const float* __restrict__ aw,
                 unsigned short* xh,  unsigned short* gwh, unsigned short* uwh,
                 unsigned short* dwh, unsigned short* pwh, unsigned short* powh,
                 unsigned short* oph, unsigned short* adw)
{
    const int T = 3276800;
    for (int i = blockIdx.x * 256 + threadIdx.x; i < T; i += gridDim.x * 256) {
        const float* in; unsigned short* hi; int j = i;
        if (j < 1048576)                 { in = x;   hi = xh;  }
        else if ((j -= 1048576) < 524288){ in = gw;  hi = gwh; }
        else if ((j -= 524288) < 524288) { in = uw;  hi = uwh; }
        else if ((j -= 524288) < 524288) { in = dw;  hi = dwh; }
        else if ((j -= 524288) < 32768)  { in = pw;  hi = pwh; }
        else if ((j -= 32768) < 65536)   { in = ow;  hi = powh; }
        else if ((j -= 65536) < 524288)  { in = opw; hi = oph; }
        else { j -= 524288;                in = aw;  hi = adw; }
        float4 v = ((const float4*)in)[j];
        ((ushort4*)hi)[j] = make_ushort4(f2bf(v.x), f2bf(v.y), f2bf(v.z), f2bf(v.w));
    }
}

// Transpose [R][C] -> bf16 [C][R], batched by blockIdx.z.
template<typename TIN>
__global__ __launch_bounds__(256)
void transb(const TIN* __restrict__ in, unsigned short* __restrict__ out, int R, int C)
{
    __shared__ float t[32][33];
    in  += (size_t)blockIdx.z * R * C;
    out += (size_t)blockIdx.z * R * C;
    int tx = threadIdx.x & 31, ty = threadIdx.x >> 5;
    int r0 = blockIdx.y * 32, c0 = blockIdx.x * 32;
#pragma unroll
    for (int j = 0; j < 4; j++) {
        TIN v = in[(size_t)(r0 + ty + j * 8) * C + c0 + tx];
        float f;
        if (sizeof(TIN) == 2) f = bf2f(*(const unsigned short*)&v);
        else                  f = *(const float*)&v;
        t[ty + j * 8][tx] = f;
    }
    __syncthreads();
#pragma unroll
    for (int j = 0; j < 4; j++)
        out[(size_t)(c0 + ty + j * 8) * R + r0 + tx] = f2bf(t[tx][ty + j * 8]);
}

// ---------------------------------------------------------------------------
// 1-term bf16 MFMA GEMM, BK=64, double-buffered + counted-vmcnt pipeline.
// 128x128 tile, 4 waves. EPI: 0 = fp32 store (+bz*zC+kz*pz); 1 = bf16 silu-clip.
// ---------------------------------------------------------------------------
template<int EPI>
__global__ __launch_bounds__(256)
void mg(const unsigned short* __restrict__ Ah, const unsigned short* __restrict__ Bh,
        void* __restrict__ Cv, int N, int K, int kchunks,
        long zA, long zB, long zC, long pz)
{
    __shared__ __align__(16) unsigned short lds[32768];  // 2 bufs x (A 8192 | B 8192)

    const int tid = threadIdx.x;
    const int l   = tid & 63;
    const int w   = tid >> 6;
    const int wr  = w >> 1, wc = w & 1;
    const int bm0 = blockIdx.y * 128, bn0 = blockIdx.x * 128;
    const int bz  = blockIdx.z / kchunks;
    const int kz  = blockIdx.z - bz * kchunks;
    const int kcnt = K / kchunks;
    const int kbeg = kz * kcnt;
    const int kend = kbeg + kcnt;

    const unsigned short* A0 = Ah + (size_t)bz * zA;
    const unsigned short* B0 = Bh + (size_t)bz * zB;

    const int srow = tid >> 3;                 // 0..31 (+32 per round)
    const int sq   = (tid & 7) ^ (srow & 7);
    const size_t aoff = (size_t)(bm0 + srow) * K + sq * 8;
    const size_t boff = (size_t)(bn0 + srow) * K + sq * 8;
    const size_t r32  = (size_t)32 * K;

    auto stage = [&](int b, int kt) {
        unsigned short* d = &lds[b * 16384 + (w << 9)];
        gl16(A0 + aoff + kt,           d + 0);
        gl16(A0 + aoff + kt + r32,     d + 2048);
        gl16(A0 + aoff + kt + 2 * r32, d + 4096);
        gl16(A0 + aoff + kt + 3 * r32, d + 6144);
        gl16(B0 + boff + kt,           d + 8192);
        gl16(B0 + boff + kt + r32,     d + 10240);
        gl16(B0 + boff + kt + 2 * r32, d + 12288);
        gl16(B0 + boff + kt + 3 * r32, d + 14336);
    };

    const int rowa = (wr * 64 + (l & 15)) * 64;   // ushort offset of A row
    const int rowb = (wc * 64 + (l & 15)) * 64;
    const int q0 = (((l >> 4)    ) ^ (l & 7)) << 3;   // ks=0 slot*8
    const int q1 = (((l >> 4) + 4) ^ (l & 7)) << 3;   // ks=1 slot*8

    f32x4 acc[4][4];
#pragma unroll
    for (int i = 0; i < 4; i++)
#pragma unroll
        for (int j = 0; j < 4; j++) acc[i][j] = (f32x4){0.f, 0.f, 0.f, 0.f};

    stage(0, kbeg);
    int cur = 0;
    for (int kt = kbeg; kt < kend; kt += 64) {
        if (kt + 64 < kend) {
            stage(cur ^ 1, kt + 64);       // next tile's 8 loads stay in flight
            WAITV_BAR(8);                  // wait only for CUR's loads
        } else {
            WAITV_BAR(0);
        }
        const int cb = cur * 16384;
#pragma unroll
        for (int ks = 0; ks < 2; ks++) {
            const int qo = ks ? q1 : q0;
            bfrag a4[4], b4[4];
#pragma unroll
            for (int f = 0; f < 4; f++) {
                a4[f] = *(const bfrag*)&lds[cb +        rowa + f * 1024 + qo];
                b4[f] = *(const bfrag*)&lds[cb + 8192 + rowb + f * 1024 + qo];
            }
#pragma unroll
            for (int i = 0; i < 4; i++)
#pragma unroll
                for (int j = 0; j < 4; j++)
                    acc[i][j] = __builtin_amdgcn_mfma_f32_16x16x32_bf16(a4[i], b4[j], acc[i][j], 0, 0, 0);
        }
        END_BAR();                         // readers done before next overwrite
        cur ^= 1;
    }

    const int crow0 = bm0 + wr * 64 + (l >> 4) * 4;
    const int ccol0 = bn0 + wc * 64 + (l & 15);
#pragma unroll
    for (int i = 0; i < 4; i++)
#pragma unroll
        for (int j = 0; j < 4; j++)
#pragma unroll
            for (int r = 0; r < 4; r++) {
                size_t idx = (size_t)(crow0 + i * 16 + r) * N + (ccol0 + j * 16);
                float v = acc[i][j][r];
                if (EPI == 0)
                    ((float*)Cv + (size_t)bz * zC + (size_t)kz * pz)[idx] = v;
                else
                    ((unsigned short*)Cv + (size_t)bz * zC)[idx] =
                        f2bf(silu_f(fminf(fmaxf(v, -5.f), 5.f)));
            }
}

// ---------------------------------------------------------------------------
// Fused gate+up GEMM, BK=64, double-buffered + counted-vmcnt (12 loads/stage).
// 2D XCD chunk (proven: FETCH 70->41 MB).
//   hh[n,h] = bf16( silu(x@gw^T) * (x@uw^T) )      K=1024.
// ---------------------------------------------------------------------------
__global__ __launch_bounds__(256)
void gup(const unsigned short* __restrict__ xh, const unsigned short* __restrict__ gwh,
         const unsigned short* __restrict__ uwh, unsigned short* __restrict__ hh)
{
    __shared__ __align__(16) unsigned short lds[49152];  // 2 bufs x (x|gw|uw 24576)
    const int tid = threadIdx.x;
    const int l   = tid & 63;
    const int w   = tid >> 6;
    const int wr  = w >> 1, wc = w & 1;

    int id  = blockIdx.y * gridDim.x + blockIdx.x;
    int xcd = id & 7, j = id >> 3;
    int bx  = (xcd & 1) * 8 + (j & 7);
    int by  = (xcd >> 1) * 8 + (j >> 3);
    const int bm0 = by * 128, bn0 = bx * 128;

    const int srow = tid >> 3;
    const int sq   = (tid & 7) ^ (srow & 7);
    const size_t aoff = (size_t)(bm0 + srow) * Dq + sq * 8;
    const size_t boff = (size_t)(bn0 + srow) * Dq + sq * 8;
    const size_t r32  = (size_t)32 * Dq;

    const int rowa = (wr * 64 + (l & 15)) * 64;
    const int rowb = (wc * 64 + (l & 15)) * 64;
    const int q0 = (((l >> 4)    ) ^ (l & 7)) << 3;
    const int q1 = (((l >> 4) + 4) ^ (l & 7)) << 3;

    auto stage = [&](int b, int kt) {
        unsigned short* d = &lds[b * 24576 + (w << 9)];
        gl16(xh  + aoff + kt,           d + 0);
        gl16(xh  + aoff + kt + r32,     d + 2048);
        gl16(xh  + aoff + kt + 2 * r32, d + 4096);
        gl16(xh  + aoff + kt + 3 * r32, d + 6144);
        gl16(gwh + boff + kt,           d + 8192);
        gl16(gwh + boff + kt + r32,     d + 10240);
        gl16(gwh + boff + kt + 2 * r32, d + 12288);
        gl16(gwh + boff + kt + 3 * r32, d + 14336);
        gl16(uwh + boff + kt,           d + 16384);
        gl16(uwh + boff + kt + r32,     d + 18432);
        gl16(uwh + boff + kt + 2 * r32, d + 20480);
        gl16(uwh + boff + kt + 3 * r32, d + 22528);
    };

    f32x4 accg[4][4], accu[4][4];
#pragma unroll
    for (int i = 0; i < 4; i++)
#pragma unroll
        for (int jj = 0; jj < 4; jj++) {
            accg[i][jj] = (f32x4){0.f, 0.f, 0.f, 0.f};
            accu[i][jj] = (f32x4){0.f, 0.f, 0.f, 0.f};
        }

    stage(0, 0);
    int cur = 0;
    for (int kt = 0; kt < Dq; kt += 64) {
        if (kt + 64 < Dq) {
            stage(cur ^ 1, kt + 64);
            WAITV_BAR(12);
        } else {
            WAITV_BAR(0);
        }
        const int cb = cur * 24576;
#pragma unroll
        for (int ks = 0; ks < 2; ks++) {
            const int qo = ks ? q1 : q0;
            bfrag a4[4], g4[4], u4[4];
#pragma unroll
            for (int f = 0; f < 4; f++) {
                a4[f] = *(const bfrag*)&lds[cb +         rowa + f * 1024 + qo];
                g4[f] = *(const bfrag*)&lds[cb +  8192 + rowb + f * 1024 + qo];
                u4[f] = *(const bfrag*)&lds[cb + 16384 + rowb + f * 1024 + qo];
            }
#pragma unroll
            for (int i = 0; i < 4; i++)
#pragma unroll
                for (int jj = 0; jj < 4; jj++) {
                    accg[i][jj] = __builtin_amdgcn_mfma_f32_16x16x32_bf16(a4[i], g4[jj], accg[i][jj], 0, 0, 0);
                    accu[i][jj] = __builtin_amdgcn_mfma_f32_16x16x32_bf16(a4[i], u4[jj], accu[i][jj], 0, 0, 0);
                }
        }
        END_BAR();
        cur ^= 1;
    }

    const int crow0 = bm0 + wr * 64 + (l >> 4) * 4;
    const int ccol0 = bn0 + wc * 64 + (l & 15);
#pragma unroll
    for (int i = 0; i < 4; i++)
#pragma unroll
        for (int jj = 0; jj < 4; jj++)
#pragma unroll
            for (int r = 0; r < 4; r++) {
                size_t idx = (size_t)(crow0 + i * 16 + r) * Hq + (ccol0 + jj * 16);
                hh[idx] = f2bf(silu_f(accg[i][jj][r]) * accu[i][jj][r]);
            }
}

// ---------------------------------------------------------------------------
// Final fused GEMM, BK=64, double-buffered + counted-vmcnt:  out[4096][1024] =
//   hh@dwh^T (K=2048)  +  acat@kcat^T (K=256)
// ---------------------------------------------------------------------------
__global__ __launch_bounds__(256)
void gfinal(const unsigned short* __restrict__ hh, const unsigned short* __restrict__ dwh,
            const unsigned short* __restrict__ acat, const unsigned short* __restrict__ kcat,
            float* __restrict__ out)
{
    __shared__ __align__(16) unsigned short lds[32768];
    const int tid = threadIdx.x;
    const int l   = tid & 63;
    const int w   = tid >> 6;
    const int wr  = w >> 1, wc = w & 1;

    int nb  = gridDim.x * gridDim.y;                      // 256
    int id  = blockIdx.y * gridDim.x + blockIdx.x;
    int id2 = (id & 7) * (nb >> 3) + (id >> 3);
    int bx  = id2 % gridDim.x, by = id2 / gridDim.x;
    const int bm0 = by * 128, bn0 = bx * 128;

    const int srow = tid >> 3;
    const int sq   = (tid & 7) ^ (srow & 7);
    const int rowa = (wr * 64 + (l & 15)) * 64;
    const int rowb = (wc * 64 + (l & 15)) * 64;
    const int q0 = (((l >> 4)    ) ^ (l & 7)) << 3;
    const int q1 = (((l >> 4) + 4) ^ (l & 7)) << 3;

    f32x4 acc[4][4];
#pragma unroll
    for (int i = 0; i < 4; i++)
#pragma unroll
        for (int j = 0; j < 4; j++) acc[i][j] = (f32x4){0.f, 0.f, 0.f, 0.f};

    // ---- main: K=2048 ----
    {
        const size_t aoff = (size_t)(bm0 + srow) * Hq + sq * 8;
        const size_t boff = (size_t)(bn0 + srow) * Hq + sq * 8;
        const size_t r32  = (size_t)32 * Hq;
        auto stage = [&](int b, int kt) {
            unsigned short* d = &lds[b * 16384 + (w << 9)];
            gl16(hh  + aoff + kt,           d + 0);
            gl16(hh  + aoff + kt + r32,     d + 2048);
            gl16(hh  + aoff + kt + 2 * r32, d + 4096);
            gl16(hh  + aoff + kt + 3 * r32, d + 6144);
            gl16(dwh + boff + kt,           d + 8192);
            gl16(dwh + boff + kt + r32,     d + 10240);
            gl16(dwh + boff + kt + 2 * r32, d + 12288);
            gl16(dwh + boff + kt + 3 * r32, d + 14336);
        };
        stage(0, 0);
        int cur = 0;
        for (int kt = 0; kt < Hq; kt += 64) {
            if (kt + 64 < Hq) {
                stage(cur ^ 1, kt + 64);
                WAITV_BAR(8);
            } else {
                WAITV_BAR(0);
            }
            const int cb = cur * 16384;
#pragma unroll
            for (int ks = 0; ks < 2; ks++) {
                const int qo = ks ? q1 : q0;
                bfrag a4[4], b4[4];
#pragma unroll
                for (int f = 0; f < 4; f++) {
                    a4[f] = *(const bfrag*)&lds[cb +        rowa + f * 1024 + qo];
                    b4[f] = *(const bfrag*)&lds[cb + 8192 + rowb + f * 1024 + qo];
                }
#pragma unroll
                for (int i = 0; i < 4; i++)
#pragma unroll
                    for (int j = 0; j < 4; j++)
                        acc[i][j] = __builtin_amdgcn_mfma_f32_16x16x32_bf16(a4[i], b4[j], acc[i][j], 0, 0, 0);
            }
            END_BAR();
            cur ^= 1;
        }
    }
    // ---- tail: K=256 over [acat | kcat] ----
    {
        const size_t aoff = (size_t)(bm0 + srow) * 256 + sq * 8;
        const size_t boff = (size_t)(bn0 + srow) * 256 + sq * 8;
        const size_t r32  = (size_t)32 * 256;
        auto stage2 = [&](int b, int kt) {
            unsigned short* d = &lds[b * 16384 + (w << 9)];
            gl16(acat + aoff + kt,           d + 0);
            gl16(acat + aoff + kt + r32,     d + 2048);
            gl16(acat + aoff + kt + 2 * r32, d + 4096);
            gl16(acat + aoff + kt + 3 * r32, d + 6144);
            gl16(kcat + boff + kt,           d + 8192);
            gl16(kcat + boff + kt + r32,     d + 10240);
            gl16(kcat + boff + kt + 2 * r32, d + 12288);
            gl16(kcat + boff + kt + 3 * r32, d + 14336);
        };
        stage2(0, 0);
        int cur = 0;
        for (int kt = 0; kt < 256; kt += 64) {
            if (kt + 64 < 256) {
                stage2(cur ^ 1, kt + 64);
                WAITV_BAR(8);
            } else {
                WAITV_BAR(0);
            }
            const int cb = cur * 16384;
#pragma unroll
            for (int ks = 0; ks < 2; ks++) {
                const int qo = ks ? q1 : q0;
                bfrag a4[4], b4[4];
#pragma unroll
                for (int f = 0; f < 4; f++) {
                    a4[f] = *(const bfrag*)&lds[cb +        rowa + f * 1024 + qo];
                    b4[f] = *(const bfrag*)&lds[cb + 8192 + rowb + f * 1024 + qo];
                }
#pragma unroll
                for (int i = 0; i < 4; i++)
#pragma unroll
                    for (int j = 0; j < 4; j++)
                        acc[i][j] = __builtin_amdgcn_mfma_f32_16x16x32_bf16(a4[i], b4[j], acc[i][j], 0, 0, 0);
            }
            END_BAR();
            cur ^= 1;
        }
    }

    const int crow0 = bm0 + wr * 64 + (l >> 4) * 4;
    const int ccol0 = bn0 + wc * 64 + (l & 15);
#pragma unroll
    for (int i = 0; i < 4; i++)
#pragma unroll
        for (int j = 0; j < 4; j++)
#pragma unroll
            for (int r = 0; r < 4; r++)
                out[(size_t)(crow0 + i * 16 + r) * Dq + ccol0 + j * 16] = acc[i][j][r];
}

// Reduce NZ split-K partials + LayerNorm over A=128 -> bf16.
template<int NZ>
__global__ __launch_bounds__(256)
void rln(const float* __restrict__ p, unsigned short* __restrict__ oh,
         const float* __restrict__ g, const float* __restrict__ b, long pstride)
{
    int row  = blockIdx.x * 4 + (threadIdx.x >> 6);
    int lane = threadIdx.x & 63;
    long base = (long)row * Aq;
    float x0 = 0.f, x1 = 0.f;
#pragma unroll
    for (int z = 0; z < NZ; z++) {
        x0 += p[base + z * pstride + lane];
        x1 += p[base + z * pstride + lane + 64];
    }
    float s  = x0 + x1;
    float ss = x0 * x0 + x1 * x1;
#pragma unroll
    for (int off = 32; off > 0; off >>= 1) {
        s  += __shfl_xor(s, off);
        ss += __shfl_xor(ss, off);
    }
    float m  = s * (1.0f / Aq);
    float v  = ss * (1.0f / Aq) - m * m;
    float rs = rsqrtf(v + 1e-5f);
    oh[base + lane]      = f2bf((x0 - m) * rs * g[lane]      + b[lane]);
    oh[base + lane + 64] = f2bf((x1 - m) * rs * g[lane + 64] + b[lane + 64]);
}

// Reduce NZ split-K partials [bz][NZ][rowsPerB][A] -> scaled bf16.
// Output col = ocol + bz*ocolStep (lets one launch fill both kcat halves).
template<int NZ>
__global__ __launch_bounds__(256)
void rbf(const float* __restrict__ p, unsigned short* __restrict__ o,
         int rowsPerB, float scale, int total, int ostride, int ocol, int ocolStep)
{
    int i = blockIdx.x * 256 + threadIdx.x;
    if (i >= total) return;
    int n = i >> 7, a = i & 127;
    int bz = n / rowsPerB, s = n - bz * rowsPerB;
    long base = ((long)bz * NZ) * rowsPerB * Aq + (long)s * Aq + a;
    float acc = 0.f;
#pragma unroll
    for (int z = 0; z < NZ; z++) acc += p[base + (long)z * rowsPerB * Aq];
    o[(long)s * ostride + (ocol + bz * ocolStep) + a +
      (ocolStep ? 0 : (long)bz * rowsPerB * ostride)] = f2bf(acc * scale);
}

// mixed[n,:] = sum_e ew[n,e] * LN_e(h[e,n,:])  -> bf16 into acat col 128.
__global__ __launch_bounds__(256)
void mix_ln(const float* __restrict__ h, const float* __restrict__ ew,
            const float* __restrict__ g, const float* __restrict__ bb,
            unsigned short* __restrict__ acat)
{
    int n    = blockIdx.x * 4 + (threadIdx.x >> 6);
    int lane = threadIdx.x & 63;
    float a0 = 0.0f, a1 = 0.0f;
#pragma unroll
    for (int e = 0; e < Eq; e++) {
        const float* r = h + ((long)e * Nq + n) * Aq;
        float x0 = r[lane], x1 = r[lane + 64];
        float s  = x0 + x1;
        float ss = x0 * x0 + x1 * x1;
#pragma unroll
        for (int off = 32; off > 0; off >>= 1) {
            s  += __shfl_xor(s, off);
            ss += __shfl_xor(ss, off);
        }
        float m  = s * (1.0f / Aq);
        float v  = ss * (1.0f / Aq) - m * m;
        float rs = rsqrtf(v + 1e-5f);
        float wv = ew[(long)n * Eq + e];
        a0 += wv * ((x0 - m) * rs * g[e * Aq + lane]      + bb[e * Aq + lane]);
        a1 += wv * ((x1 - m) * rs * g[e * Aq + lane + 64] + bb[e * Aq + lane + 64]);
    }
    acat[(long)n * 256 + 128 + lane]      = f2bf(a0);
    acat[(long)n * 256 + 128 + lane + 64] = f2bf(a1);
}

extern "C" void kernel_launch(void* const* d_in, const int* in_sizes, int n_in,
                              void* d_out, int out_size, void* d_ws, size_t ws_size,
                              hipStream_t stream)
{
    const float* x             = (const float*)d_in[0];
    const float* ew            = (const float*)d_in[1];
    const float* up_w          = (const float*)d_in[2];
    const float* gate_w        = (const float*)d_in[3];
    const float* down_w        = (const float*)d_in[4];
    const float* pre_w         = (const float*)d_in[5];
    const float* post_w        = (const float*)d_in[6];
    const float* an_g          = (const float*)d_in[7];
    const float* an_b          = (const float*)d_in[8];
    const float* adapt_proj_w  = (const float*)d_in[9];
    const float* adapter_w     = (const float*)d_in[10];
    const float* adapter_g     = (const float*)d_in[11];
    const float* adapter_b     = (const float*)d_in[12];
    const float* expert_proj_w = (const float*)d_in[13];
    const float* output_proj_w = (const float*)d_in[14];
    float* out = (float*)d_out;

    // ---- workspace (KB offsets; peak ~81 MB) ----
#define OFF(kb) ((char*)d_ws + (size_t)(kb) * 1024)
    float* kdp  = (float*)OFF(0);        // [16][D][A] 8MB   (phase 1, bz=0)
    float* wfp  = (float*)OFF(8192);     // 8MB              (phase 1, bz=1)
    float* p1   = (float*)OFF(16384);    // [8][N][A] 16MB   (phase 1)
    float* p2   = (float*)OFF(0);        // [8][N][A] 16MB   (phase 3)
    unsigned short* wmat = (unsigned short*)OFF(16384);  // [B][S][S] bf16 16MB (ph 3-4)
    float* p3   = (float*)OFF(0);        // [2][8][S][A] 16MB (phase 4)
    float* h_e  = (float*)OFF(0);        // [E][N][A] 16MB    (phase 5, after p3 dead)
    unsigned short* hh   = (unsigned short*)OFF(32768);  // [N,H] 16MB
    unsigned short* xh   = (unsigned short*)OFF(49152);  // 8MB
    unsigned short* gwh  = (unsigned short*)OFF(57344);  // 4MB
    unsigned short* uwh  = (unsigned short*)OFF(61440);  // 4MB
    unsigned short* dwh  = (unsigned short*)OFF(65536);  // 4MB   } contiguous pair
    unsigned short* oph  = (unsigned short*)OFF(69632);  // 4MB   } for batched kcat
    unsigned short* pwh  = (unsigned short*)OFF(73728);  // .25MB
    unsigned short* powh = (unsigned short*)OFF(73984);  // .5MB
    unsigned short* apT  = (unsigned short*)OFF(74496);  // .5MB  } contiguous pair
    unsigned short* epT  = (unsigned short*)OFF(75008);  // .5MB  }
    unsigned short* ainh = (unsigned short*)OFF(75520);  // 1MB
    unsigned short* ainT = (unsigned short*)OFF(76544);  // [B][A][S] 1MB
    unsigned short* aouth= (unsigned short*)OFF(77568);  // 1MB
    unsigned short* adw  = (unsigned short*)OFF(78592);  // .25MB
    unsigned short* kcat = (unsigned short*)OFF(78848);  // [D][256] .5MB
    unsigned short* acat = (unsigned short*)OFF(79360);  // [N][256] 2MB -> 81408
#undef OFF

    dim3 blk(256);
    const long NA = (long)Nq * Aq;
    const long SA = (long)Sq * Aq;
    const long SS = (long)Sq * Sq;

    // 1. conversions + transposes
    convert_all<<<dim3(2048), blk, 0, stream>>>(x, gate_w, up_w, down_w, pre_w, post_w,
        output_proj_w, adapter_w, xh, gwh, uwh, dwh, pwh, powh, oph, adw);
    transb<float><<<dim3(4, 64, 1), blk, 0, stream>>>(adapt_proj_w,  apT, Hq, Aq);
    transb<float><<<dim3(4, 64, 1), blk, 0, stream>>>(expert_proj_w, epT, Hq, Aq);

    // 2. weight fusions (batched bz=2): bz0 = dwh@apT -> kdp, bz1 = oph@epT -> wfp
    mg<0><<<dim3(1, 8, 32), blk, 0, stream>>>(dwh, apT, kdp, Aq, Hq, 16,
        (long)Dq * Hq, (long)Aq * Hq, (long)16 * Dq * Aq, (long)Dq * Aq);
    rbf<16><<<dim3(1024), blk, 0, stream>>>(kdp, kcat, Dq, 1.0f, 2 * Dq * Aq, 256, 0, 128);

    // 3. ain = LN(x @ pre_w^T)  (split-K 8)
    mg<0><<<dim3(1, 32, 8), blk, 0, stream>>>(xh, pwh, p1, Aq, Dq, 8, 0, 0, 0, NA);
    rln<8><<<dim3(1024), blk, 0, stream>>>(p1, ainh, an_g, an_b, NA);
    transb<unsigned short><<<dim3(4, 64, 2), blk, 0, stream>>>(ainh, ainT, Sq, Aq);

    // 4. fused SwiGLU: hh = bf16(silu(x@gw^T) * (x@uw^T))
    gup<<<dim3(16, 32), blk, 0, stream>>>(xh, gwh, uwh, hh);

    // 5. aout = LN(hidden @ post_w^T)  (split-K 8)
    mg<0><<<dim3(1, 32, 8), blk, 0, stream>>>(hh, powh, p2, Aq, Hq, 8, 0, 0, 0, NA);
    rln<8><<<dim3(1024), blk, 0, stream>>>(p2, aouth, an_g, an_b, NA);

    // 6. wmat = bf16(silu(clip(ain @ aout^T)))  per batch
    mg<1><<<dim3(16, 16, 2), blk, 0, stream>>>(ainh, aouth, wmat, Sq, Aq, 1,
        SA, SA, SS, 0);

    // 7. acat[:,0:128] = 0.1 * (wmat @ ain)  (split-K 8, batched)
    mg<0><<<dim3(1, 16, 16), blk, 0, stream>>>(wmat, ainT, p3, Aq, Sq, 8,
        SS, SA, 8 * SA, SA);
    rbf<8><<<dim3(2048), blk, 0, stream>>>(p3, acat, Sq, 0.1f, Nq * Aq, 256, 0, 0);

    // 8. expert path: h_e, then acat[:,128:256] = mixed
    mg<0><<<dim3(1, 32, 8), blk, 0, stream>>>(ainh, adw, h_e, Aq, Aq, 1,
        0, (long)Aq * Aq, NA, 0);
    mix_ln<<<dim3(1024), blk, 0, stream>>>(h_e, ew, adapter_g, adapter_b, acat);

    // 9. out = hh@dwh^T + acat@kcat^T
    gfinal<<<dim3(8, 32), blk, 0, stream>>>(hh, dwh, acat, kcat, out);
}